// Round 1
// baseline (4166.420 us; speedup 1.0000x reference)
//
#include <hip/hip_runtime.h>
#include <cmath>

#define NB 32
#define C1N 64
#define DIM 256
#define NHEAD 8
#define SEQL 784
#define NA 1605632      /* NB*SEQL*C1N */
#define SEQN 6422528    /* NB*SEQL*DIM */
#define KSEL 803u
#define SCALE 0.17677669529663687f   /* 1/sqrt(32) */
#define PECOEF (-0.03597789207803197f) /* -ln(10000)/256 */

// ---------------- zero ----------------
__global__ void k_zero(unsigned* __restrict__ p, int n) {
  int i = blockIdx.x * 256 + threadIdx.x;
  if (i < n) p[i] = 0u;
}

// ---------------- conv + relu + hist(high16) ----------------
__global__ __launch_bounds__(256) void k_conv(const float* __restrict__ x,
                                              const float* __restrict__ cw,
                                              float* __restrict__ vbuf,
                                              unsigned* __restrict__ hist) {
  int idx = blockIdx.x * 256 + threadIdx.x;   // ((b*28+h)*28+w)*64 + c
  int c = idx & 63;
  int p = idx >> 6;
  int wc = p % 28;
  int t2 = p / 28;
  int hr = t2 % 28;
  int b = t2 / 28;
  const float* xb = x + b * 784;
  const float* wp = cw + c * 81;
  float s = 0.0f;
  #pragma unroll
  for (int dy = 0; dy < 9; ++dy) {
    int iy = hr + dy - 4;
    if (iy < 0 || iy >= 28) continue;
    #pragma unroll
    for (int dx = 0; dx < 9; ++dx) {
      int ix = wc + dx - 4;
      if (ix < 0 || ix >= 28) continue;
      s = fmaf(xb[iy * 28 + ix], wp[dy * 9 + dx], s);
    }
  }
  s = fmaxf(s, 0.0f);
  vbuf[idx] = s;
  if (s > 0.0f) atomicAdd(&hist[__float_as_uint(s) >> 16], 1u);
}

// ---------------- radix-select pass 1 scan ----------------
__global__ __launch_bounds__(1024) void k_scan_hi(unsigned* __restrict__ hist,
                                                  unsigned* __restrict__ sel) {
  __shared__ unsigned ss[1024];
  int t = threadIdx.x;
  unsigned sum = 0;
  for (int i = 0; i < 64; ++i) sum += hist[t * 64 + i];
  ss[t] = sum;
  __syncthreads();
  for (int off = 1; off < 1024; off <<= 1) {
    unsigned v = (t + off < 1024) ? ss[t + off] : 0u;
    __syncthreads();
    ss[t] += v;
    __syncthreads();
  }
  unsigned S = ss[t];
  unsigned above = (t < 1023) ? ss[t + 1] : 0u;
  if (t == 0 && ss[0] < KSEL) {   // fewer than k positives -> threshold 0
    sel[0] = 0xFFFFFFFFu; sel[1] = 0u; sel[2] = 1u; sel[3] = 0u;
  }
  if (S >= KSEL && above < KSEL) {
    unsigned cum = above;
    for (int bb = t * 64 + 63; bb >= t * 64; --bb) {
      unsigned hb = hist[bb];
      cum += hb;
      if (cum >= KSEL) { sel[0] = (unsigned)bb; sel[1] = KSEL - (cum - hb); break; }
    }
  }
  __syncthreads();
  for (int i = t; i < 65536; i += 1024) hist[i] = 0u;  // clear for pass 2
}

// ---------------- radix-select pass 2 hist(low16) ----------------
__global__ __launch_bounds__(256) void k_hist_lo(const float* __restrict__ vbuf,
                                                 const unsigned* __restrict__ sel,
                                                 unsigned* __restrict__ hist) {
  int i = blockIdx.x * 256 + threadIdx.x;
  float a = vbuf[i];
  if (a > 0.0f) {
    unsigned bits = __float_as_uint(a);
    if ((bits >> 16) == sel[0]) atomicAdd(&hist[bits & 0xFFFFu], 1u);
  }
}

// ---------------- radix-select pass 2 scan ----------------
__global__ __launch_bounds__(1024) void k_scan_lo(const unsigned* __restrict__ hist,
                                                  unsigned* __restrict__ sel) {
  if (sel[2]) return;  // uniform
  __shared__ unsigned ss[1024];
  int t = threadIdx.x;
  unsigned rem = sel[1];
  unsigned sum = 0;
  for (int i = 0; i < 64; ++i) sum += hist[t * 64 + i];
  ss[t] = sum;
  __syncthreads();
  for (int off = 1; off < 1024; off <<= 1) {
    unsigned v = (t + off < 1024) ? ss[t + off] : 0u;
    __syncthreads();
    ss[t] += v;
    __syncthreads();
  }
  unsigned S = ss[t];
  unsigned above = (t < 1023) ? ss[t + 1] : 0u;
  if (S >= rem && above < rem) {
    unsigned cum = above;
    for (int bb = t * 64 + 63; bb >= t * 64; --bb) {
      unsigned hb = hist[bb];
      cum += hb;
      if (cum >= rem) { sel[3] = (sel[0] << 16) | (unsigned)bb; break; }
    }
  }
}

// ---------------- top-2 select + sparse softmax + embed + pos-enc ----------------
__global__ __launch_bounds__(256) void k_select(const float* __restrict__ vbuf,
                                                const unsigned* __restrict__ sel,
                                                const float* __restrict__ ce,
                                                float* __restrict__ seq,
                                                float* __restrict__ out_sw,
                                                float* __restrict__ out_idx) {
  int wid = threadIdx.x >> 6;
  int lane = threadIdx.x & 63;
  int pos = blockIdx.x * 4 + wid;   // 0..25087 = b*784 + h*28 + w
  int hw = pos % 784;
  int hr = hw / 28;
  int wc = hw % 28;
  float thr = __uint_as_float(sel[3]);
  float a = vbuf[(size_t)pos * 64 + lane];
  float val = (a >= thr) ? a : 0.0f;
  unsigned long long nzm = __ballot(val > 0.0f);
  int count = __popcll(nzm);
  // top-1 (stable: lowest index wins ties)
  float v1 = val; int i1 = lane;
  #pragma unroll
  for (int off = 32; off > 0; off >>= 1) {
    float ov = __shfl_xor(v1, off);
    int oi = __shfl_xor(i1, off);
    if (ov > v1 || (ov == v1 && oi < i1)) { v1 = ov; i1 = oi; }
  }
  // top-2: exclude i1, reduce again
  float vx = (lane == i1) ? -INFINITY : val;
  float v2 = vx; int i2 = lane;
  #pragma unroll
  for (int off = 32; off > 0; off >>= 1) {
    float ov = __shfl_xor(v2, off);
    int oi = __shfl_xor(i2, off);
    if (ov > v2 || (ov == v2 && oi < i2)) { v2 = ov; i2 = oi; }
  }
  float w1 = 0.0f, w2 = 0.0f;
  if (count >= 2) {
    float e = __expf(v2 - v1);
    float invd = 1.0f / (1.0f + e);
    w1 = invd; w2 = e * invd;
  } else if (count == 1) {
    w1 = 1.0f;
  }
  float wt = (lane == i1) ? w1 : ((lane == i2) ? w2 : 0.0f);
  out_sw[(size_t)pos * 64 + lane] = wt;
  if (lane < 2) out_idx[pos * 2 + lane] = (float)(lane == 0 ? i1 : i2);
  // loc_emb: 4 consecutive dims per lane
  int d0 = lane * 4;
  float4 c1v = *(const float4*)(ce + (size_t)i1 * 256 + d0);
  float4 c2v = *(const float4*)(ce + (size_t)i2 * 256 + d0);
  float dv0 = __expf((float)d0 * PECOEF);
  float dv2 = __expf((float)(d0 + 2) * PECOEF);
  float4 o;
  o.x = w1 * c1v.x + w2 * c2v.x + sinf((float)hr * dv0);
  o.y = w1 * c1v.y + w2 * c2v.y + cosf((float)wc * dv0);
  o.z = w1 * c1v.z + w2 * c2v.z + sinf((float)hr * dv2);
  o.w = w1 * c1v.w + w2 * c2v.w + cosf((float)wc * dv2);
  *(float4*)(seq + (size_t)pos * 256 + d0) = o;
}

// ---------------- tiled f32 GEMM: C[M][N] = A[M][K] @ Bm[N][K]^T + bias ----------------
__global__ __launch_bounds__(256) void k_gemm_bt(const float* __restrict__ A,
                                                 const float* __restrict__ Bm,
                                                 const float* __restrict__ bias,
                                                 float* __restrict__ C,
                                                 int M, int N, int K) {
  __shared__ float As[16][68];
  __shared__ float Bs[16][68];
  int tid = threadIdx.x;
  int tx = tid & 15, ty = tid >> 4;
  int m0 = blockIdx.y * 64, n0 = blockIdx.x * 64;
  int lr = tid >> 2;           // 0..63
  int lc4 = (tid & 3) * 4;     // 0,4,8,12
  float acc[4][4] = {{0.f}};
  for (int k0 = 0; k0 < K; k0 += 16) {
    float4 av = *(const float4*)(A + (size_t)(m0 + lr) * K + k0 + lc4);
    float4 bv = *(const float4*)(Bm + (size_t)(n0 + lr) * K + k0 + lc4);
    As[lc4 + 0][lr] = av.x; As[lc4 + 1][lr] = av.y;
    As[lc4 + 2][lr] = av.z; As[lc4 + 3][lr] = av.w;
    Bs[lc4 + 0][lr] = bv.x; Bs[lc4 + 1][lr] = bv.y;
    Bs[lc4 + 2][lr] = bv.z; Bs[lc4 + 3][lr] = bv.w;
    __syncthreads();
    #pragma unroll
    for (int kk = 0; kk < 16; ++kk) {
      float4 a4 = *(const float4*)&As[kk][ty * 4];
      float4 b4 = *(const float4*)&Bs[kk][tx * 4];
      float avr[4] = {a4.x, a4.y, a4.z, a4.w};
      float bvr[4] = {b4.x, b4.y, b4.z, b4.w};
      #pragma unroll
      for (int i = 0; i < 4; ++i)
        #pragma unroll
        for (int j = 0; j < 4; ++j)
          acc[i][j] = fmaf(avr[i], bvr[j], acc[i][j]);
    }
    __syncthreads();
  }
  float4 b4 = *(const float4*)(bias + n0 + tx * 4);
  #pragma unroll
  for (int i = 0; i < 4; ++i) {
    float4 o;
    o.x = acc[i][0] + b4.x; o.y = acc[i][1] + b4.y;
    o.z = acc[i][2] + b4.z; o.w = acc[i][3] + b4.w;
    *(float4*)(C + (size_t)(m0 + ty * 4 + i) * N + n0 + tx * 4) = o;
  }
}

// ---------------- flash attention (f32), one block = (b, head, 16 q-rows) ----------------
__global__ __launch_bounds__(512) void k_attn(const float* __restrict__ qkvbuf,
                                              float* __restrict__ ctx) {
  int qb = blockIdx.x;   // 0..48
  int nh = blockIdx.y;   // 0..7
  int b = blockIdx.z;    // 0..31
  int wid = threadIdx.x >> 6;
  int lane = threadIdx.x & 63;
  __shared__ float4 Ks[64][8];
  __shared__ float4 Vs[64][8];
  int r0 = qb * 16 + wid * 2;
  float qreg[2][32];
  float mx[2] = {-INFINITY, -INFINITY};
  float lsum[2] = {0.f, 0.f};
  float acc[2][32];
  #pragma unroll
  for (int r = 0; r < 2; ++r)
    #pragma unroll
    for (int i = 0; i < 32; ++i) acc[r][i] = 0.f;
  #pragma unroll
  for (int r = 0; r < 2; ++r) {
    const float* qp = qkvbuf + (size_t)(b * 784 + r0 + r) * 768 + nh * 32;
    #pragma unroll
    for (int i = 0; i < 8; ++i) {
      float4 qv = *(const float4*)(qp + i * 4);
      qreg[r][i * 4 + 0] = qv.x; qreg[r][i * 4 + 1] = qv.y;
      qreg[r][i * 4 + 2] = qv.z; qreg[r][i * 4 + 3] = qv.w;
    }
  }
  const float* kvbase = qkvbuf + (size_t)b * 784 * 768 + 256 + nh * 32;
  int lrow = threadIdx.x >> 3;   // 0..63
  int g = threadIdx.x & 7;
  int pc = g ^ (lrow & 7);       // XOR swizzle
  for (int kt = 0; kt < 13; ++kt) {
    int k0 = kt * 64;
    if (k0 + lrow < 784) {
      const float* kp = kvbase + (size_t)(k0 + lrow) * 768 + g * 4;
      Ks[lrow][pc] = *(const float4*)kp;
      Vs[lrow][pc] = *(const float4*)(kp + 256);
    } else {
      Ks[lrow][pc] = make_float4(0.f, 0.f, 0.f, 0.f);
      Vs[lrow][pc] = make_float4(0.f, 0.f, 0.f, 0.f);
    }
    __syncthreads();
    int kk = k0 + lane;
    if (kk < 784) {
      float s[2] = {0.f, 0.f};
      #pragma unroll
      for (int i = 0; i < 8; ++i) {
        float4 kv = Ks[lane][i ^ (lane & 7)];
        #pragma unroll
        for (int r = 0; r < 2; ++r) {
          s[r] = fmaf(qreg[r][i * 4 + 0], kv.x, s[r]);
          s[r] = fmaf(qreg[r][i * 4 + 1], kv.y, s[r]);
          s[r] = fmaf(qreg[r][i * 4 + 2], kv.z, s[r]);
          s[r] = fmaf(qreg[r][i * 4 + 3], kv.w, s[r]);
        }
      }
      float p[2], sc[2];
      #pragma unroll
      for (int r = 0; r < 2; ++r) {
        s[r] *= SCALE;
        float nm = fmaxf(mx[r], s[r]);
        p[r] = __expf(s[r] - nm);
        sc[r] = __expf(mx[r] - nm);
        lsum[r] = lsum[r] * sc[r] + p[r];
        mx[r] = nm;
      }
      #pragma unroll
      for (int i = 0; i < 8; ++i) {
        float4 vv = Vs[lane][i ^ (lane & 7)];
        #pragma unroll
        for (int r = 0; r < 2; ++r) {
          acc[r][i * 4 + 0] = fmaf(p[r], vv.x, acc[r][i * 4 + 0] * sc[r]);
          acc[r][i * 4 + 1] = fmaf(p[r], vv.y, acc[r][i * 4 + 1] * sc[r]);
          acc[r][i * 4 + 2] = fmaf(p[r], vv.z, acc[r][i * 4 + 2] * sc[r]);
          acc[r][i * 4 + 3] = fmaf(p[r], vv.w, acc[r][i * 4 + 3] * sc[r]);
        }
      }
    }
    __syncthreads();
  }
  // merge 64 lane-local online-softmax states per row
  #pragma unroll
  for (int off = 32; off > 0; off >>= 1) {
    #pragma unroll
    for (int r = 0; r < 2; ++r) {
      float om = __shfl_xor(mx[r], off);
      float ol = __shfl_xor(lsum[r], off);
      float nm = fmaxf(mx[r], om);
      float sa = __expf(mx[r] - nm);
      float sb = __expf(om - nm);
      lsum[r] = lsum[r] * sa + ol * sb;
      mx[r] = nm;
      #pragma unroll
      for (int i = 0; i < 32; ++i) {
        float oa = __shfl_xor(acc[r][i], off);
        acc[r][i] = acc[r][i] * sa + oa * sb;
      }
    }
  }
  float inv0 = 1.0f / lsum[0];
  float inv1 = 1.0f / lsum[1];
  float* bounce = (float*)&Ks[0][0];
  #pragma unroll
  for (int j = 0; j < 32; ++j) {
    if (lane == j)      bounce[wid * 64 + j]      = acc[0][j] * inv0;
    if (lane == j + 32) bounce[wid * 64 + j + 32] = acc[1][j] * inv1;
  }
  float ov = bounce[wid * 64 + lane];
  int rr = r0 + (lane >> 5);
  ctx[(size_t)(b * 784 + rr) * 256 + nh * 32 + (lane & 31)] = ov;
}

// ---------------- mean pool over sequence ----------------
__global__ __launch_bounds__(1024) void k_pool(const float* __restrict__ ao,
                                               float* __restrict__ out) {
  int b = blockIdx.x;
  int d = threadIdx.x & 255;
  int sg = threadIdx.x >> 8;   // 0..3
  float s = 0.f;
  for (int t = sg; t < 784; t += 4) s += ao[((size_t)b * 784 + t) * 256 + d];
  __shared__ float red[4][256];
  red[sg][d] = s;
  __syncthreads();
  if (sg == 0) {
    float tot = red[0][d] + red[1][d] + red[2][d] + red[3][d];
    out[b * 256 + d] = tot * (1.0f / 784.0f);
  }
}

extern "C" void kernel_launch(void* const* d_in, const int* in_sizes, int n_in,
                              void* d_out, int out_size, void* d_ws, size_t ws_size,
                              hipStream_t stream) {
  (void)in_sizes; (void)n_in; (void)out_size; (void)ws_size;
  const float* x   = (const float*)d_in[0];
  const float* cw  = (const float*)d_in[1];
  const float* ce  = (const float*)d_in[2];
  const float* ipw = (const float*)d_in[3];
  const float* ipb = (const float*)d_in[4];
  const float* opw = (const float*)d_in[5];
  const float* opb = (const float*)d_in[6];

  float* out = (float*)d_out;
  float* pooled  = out;                    // 8192
  float* out_sw  = out + 8192;             // 1605632
  float* out_idx = out + 8192 + NA;        // 50176

  float* ws = (float*)d_ws;
  float* vbuf = ws;                                  // NA floats
  unsigned* hist = (unsigned*)(ws + NA);             // 65536
  unsigned* sel  = hist + 65536;                     // 16
  float* seq  = ws + NA + 65536 + 16;                // SEQN floats
  float* qkv  = seq + SEQN;                          // 3*SEQN floats
  float* ctx  = seq;                                 // reuse (seq dead after QKV gemm)
  float* aout = qkv;                                 // reuse (qkv dead after attention)

  k_zero<<<(65552 + 255) / 256, 256, 0, stream>>>(hist, 65536 + 16);
  k_conv<<<NA / 256, 256, 0, stream>>>(x, cw, vbuf, hist);
  k_scan_hi<<<1, 1024, 0, stream>>>(hist, sel);
  k_hist_lo<<<NA / 256, 256, 0, stream>>>(vbuf, sel, hist);
  k_scan_lo<<<1, 1024, 0, stream>>>(hist, sel);
  k_select<<<25088 / 4, 256, 0, stream>>>(vbuf, sel, ce, seq, out_sw, out_idx);
  {
    dim3 g(768 / 64, 25088 / 64);
    k_gemm_bt<<<g, 256, 0, stream>>>(seq, ipw, ipb, qkv, 25088, 768, 256);
  }
  {
    dim3 g(49, NHEAD, NB);
    k_attn<<<g, 512, 0, stream>>>(qkv, ctx);
  }
  {
    dim3 g(256 / 64, 25088 / 64);
    k_gemm_bt<<<g, 256, 0, stream>>>(ctx, opw, opb, aout, 25088, 256, 256);
  }
  k_pool<<<NB, 1024, 0, stream>>>(aout, pooled);
}

// Round 2
// 720.335 us; speedup vs baseline: 5.7840x; 5.7840x over previous
//
#include <hip/hip_runtime.h>
#include <cmath>

#define NB 32
#define C1N 64
#define DIM 256
#define NHEAD 8
#define SEQL 784
#define NA 1605632      /* NB*SEQL*C1N */
#define SEQN 6422528    /* NB*SEQL*DIM */
#define KSEL 803u
#define SCALE 0.17677669529663687f   /* 1/sqrt(32) */
#define PECOEF (-0.03597789207803197f) /* -ln(10000)/256 */

typedef __attribute__((ext_vector_type(8))) short bf16x8;
typedef __attribute__((ext_vector_type(4))) float f32x4;

__device__ __forceinline__ unsigned short f2b(float f) {
  unsigned u = __float_as_uint(f);
  unsigned r = u + 0x7fffu + ((u >> 16) & 1u);
  return (unsigned short)(r >> 16);
}

// ---------------- zero ----------------
__global__ void k_zero(unsigned* __restrict__ p, int n) {
  int i = blockIdx.x * 256 + threadIdx.x;
  if (i < n) p[i] = 0u;
}

// ---------------- weights f32 -> bf16 ----------------
__global__ __launch_bounds__(256) void k_cast(const float* __restrict__ ipw,
                                              const float* __restrict__ opw,
                                              unsigned short* __restrict__ wb) {
  int i = blockIdx.x * 256 + threadIdx.x;
  float v = (i < 196608) ? ipw[i] : opw[i - 196608];
  wb[i] = f2b(v);
}

// ---------------- conv + relu + hist(high16) ----------------
__global__ __launch_bounds__(256) void k_conv(const float* __restrict__ x,
                                              const float* __restrict__ cw,
                                              float* __restrict__ vbuf,
                                              unsigned* __restrict__ hist) {
  int idx = blockIdx.x * 256 + threadIdx.x;
  int c = idx & 63;
  int p = idx >> 6;
  int wc = p % 28;
  int t2 = p / 28;
  int hr = t2 % 28;
  int b = t2 / 28;
  const float* xb = x + b * 784;
  const float* wp = cw + c * 81;
  float s = 0.0f;
  #pragma unroll
  for (int dy = 0; dy < 9; ++dy) {
    int iy = hr + dy - 4;
    if (iy < 0 || iy >= 28) continue;
    #pragma unroll
    for (int dx = 0; dx < 9; ++dx) {
      int ix = wc + dx - 4;
      if (ix < 0 || ix >= 28) continue;
      s = fmaf(xb[iy * 28 + ix], wp[dy * 9 + dx], s);
    }
  }
  s = fmaxf(s, 0.0f);
  vbuf[idx] = s;
  if (s > 0.0f) atomicAdd(&hist[__float_as_uint(s) >> 16], 1u);
}

// ---------------- radix-select pass 1 scan ----------------
__global__ __launch_bounds__(1024) void k_scan_hi(unsigned* __restrict__ hist,
                                                  unsigned* __restrict__ sel) {
  __shared__ unsigned ss[1024];
  int t = threadIdx.x;
  unsigned sum = 0;
  for (int i = 0; i < 64; ++i) sum += hist[t * 64 + i];
  ss[t] = sum;
  __syncthreads();
  for (int off = 1; off < 1024; off <<= 1) {
    unsigned v = (t + off < 1024) ? ss[t + off] : 0u;
    __syncthreads();
    ss[t] += v;
    __syncthreads();
  }
  unsigned S = ss[t];
  unsigned above = (t < 1023) ? ss[t + 1] : 0u;
  if (t == 0 && ss[0] < KSEL) {
    sel[0] = 0xFFFFFFFFu; sel[1] = 0u; sel[2] = 1u; sel[3] = 0u;
  }
  if (S >= KSEL && above < KSEL) {
    unsigned cum = above;
    for (int bb = t * 64 + 63; bb >= t * 64; --bb) {
      unsigned hb = hist[bb];
      cum += hb;
      if (cum >= KSEL) { sel[0] = (unsigned)bb; sel[1] = KSEL - (cum - hb); break; }
    }
  }
  __syncthreads();
  for (int i = t; i < 65536; i += 1024) hist[i] = 0u;
}

// ---------------- radix-select pass 2 hist(low16) ----------------
__global__ __launch_bounds__(256) void k_hist_lo(const float* __restrict__ vbuf,
                                                 const unsigned* __restrict__ sel,
                                                 unsigned* __restrict__ hist) {
  int i = blockIdx.x * 256 + threadIdx.x;
  float a = vbuf[i];
  if (a > 0.0f) {
    unsigned bits = __float_as_uint(a);
    if ((bits >> 16) == sel[0]) atomicAdd(&hist[bits & 0xFFFFu], 1u);
  }
}

// ---------------- radix-select pass 2 scan ----------------
__global__ __launch_bounds__(1024) void k_scan_lo(const unsigned* __restrict__ hist,
                                                  unsigned* __restrict__ sel) {
  if (sel[2]) return;
  __shared__ unsigned ss[1024];
  int t = threadIdx.x;
  unsigned rem = sel[1];
  unsigned sum = 0;
  for (int i = 0; i < 64; ++i) sum += hist[t * 64 + i];
  ss[t] = sum;
  __syncthreads();
  for (int off = 1; off < 1024; off <<= 1) {
    unsigned v = (t + off < 1024) ? ss[t + off] : 0u;
    __syncthreads();
    ss[t] += v;
    __syncthreads();
  }
  unsigned S = ss[t];
  unsigned above = (t < 1023) ? ss[t + 1] : 0u;
  if (S >= rem && above < rem) {
    unsigned cum = above;
    for (int bb = t * 64 + 63; bb >= t * 64; --bb) {
      unsigned hb = hist[bb];
      cum += hb;
      if (cum >= rem) { sel[3] = (sel[0] << 16) | (unsigned)bb; break; }
    }
  }
}

// ---------------- top-2 select + sparse softmax + embed + pos-enc (seq in bf16) ----
__global__ __launch_bounds__(256) void k_select(const float* __restrict__ vbuf,
                                                const unsigned* __restrict__ sel,
                                                const float* __restrict__ ce,
                                                unsigned short* __restrict__ seqb,
                                                float* __restrict__ out_sw,
                                                float* __restrict__ out_idx) {
  int wid = threadIdx.x >> 6;
  int lane = threadIdx.x & 63;
  int pos = blockIdx.x * 4 + wid;
  int hw = pos % 784;
  int hr = hw / 28;
  int wc = hw % 28;
  float thr = __uint_as_float(sel[3]);
  float a = vbuf[(size_t)pos * 64 + lane];
  float val = (a >= thr) ? a : 0.0f;
  unsigned long long nzm = __ballot(val > 0.0f);
  int count = __popcll(nzm);
  float v1 = val; int i1 = lane;
  #pragma unroll
  for (int off = 32; off > 0; off >>= 1) {
    float ov = __shfl_xor(v1, off);
    int oi = __shfl_xor(i1, off);
    if (ov > v1 || (ov == v1 && oi < i1)) { v1 = ov; i1 = oi; }
  }
  float vx = (lane == i1) ? -INFINITY : val;
  float v2 = vx; int i2 = lane;
  #pragma unroll
  for (int off = 32; off > 0; off >>= 1) {
    float ov = __shfl_xor(v2, off);
    int oi = __shfl_xor(i2, off);
    if (ov > v2 || (ov == v2 && oi < i2)) { v2 = ov; i2 = oi; }
  }
  float w1 = 0.0f, w2 = 0.0f;
  if (count >= 2) {
    float e = __expf(v2 - v1);
    float invd = 1.0f / (1.0f + e);
    w1 = invd; w2 = e * invd;
  } else if (count == 1) {
    w1 = 1.0f;
  }
  float wt = (lane == i1) ? w1 : ((lane == i2) ? w2 : 0.0f);
  out_sw[(size_t)pos * 64 + lane] = wt;
  if (lane < 2) out_idx[pos * 2 + lane] = (float)(lane == 0 ? i1 : i2);
  int d0 = lane * 4;
  float4 c1v = *(const float4*)(ce + (size_t)i1 * 256 + d0);
  float4 c2v = *(const float4*)(ce + (size_t)i2 * 256 + d0);
  float dv0 = __expf((float)d0 * PECOEF);
  float dv2 = __expf((float)(d0 + 2) * PECOEF);
  float ox = w1 * c1v.x + w2 * c2v.x + sinf((float)hr * dv0);
  float oy = w1 * c1v.y + w2 * c2v.y + cosf((float)wc * dv0);
  float oz = w1 * c1v.z + w2 * c2v.z + sinf((float)hr * dv2);
  float ow = w1 * c1v.w + w2 * c2v.w + cosf((float)wc * dv2);
  ushort4 ob = make_ushort4(f2b(ox), f2b(oy), f2b(oz), f2b(ow));
  *(ushort4*)(seqb + (size_t)pos * 256 + d0) = ob;
}

// ---------------- MFMA bf16 GEMM: C[M][N] = A[M][K] @ W[N][K]^T + bias ----------------
template<int OUTBF16>
__global__ __launch_bounds__(256) void k_gemm_mfma(const unsigned short* __restrict__ A,
                                                   const unsigned short* __restrict__ W,
                                                   const float* __restrict__ bias,
                                                   void* __restrict__ Cv,
                                                   int M, int N, int K) {
  int tid = threadIdx.x;
  int lane = tid & 63, wid = tid >> 6;
  int q = lane & 15, g = lane >> 4;
  int m0 = blockIdx.y * 128 + (wid >> 1) * 64;
  int n0 = blockIdx.x * 128 + (wid & 1) * 64;
  f32x4 acc[4][4];
  #pragma unroll
  for (int i = 0; i < 4; ++i)
    #pragma unroll
    for (int j = 0; j < 4; ++j) acc[i][j] = (f32x4){0.f, 0.f, 0.f, 0.f};
  for (int k0 = 0; k0 < K; k0 += 32) {
    bf16x8 af[4], bf[4];
    #pragma unroll
    for (int i = 0; i < 4; ++i)
      af[i] = *(const bf16x8*)(A + (size_t)(m0 + i * 16 + q) * K + k0 + g * 8);
    #pragma unroll
    for (int j = 0; j < 4; ++j)
      bf[j] = *(const bf16x8*)(W + (size_t)(n0 + j * 16 + q) * K + k0 + g * 8);
    #pragma unroll
    for (int i = 0; i < 4; ++i)
      #pragma unroll
      for (int j = 0; j < 4; ++j)
        acc[i][j] = __builtin_amdgcn_mfma_f32_16x16x32_bf16(af[i], bf[j], acc[i][j], 0, 0, 0);
  }
  float bj[4];
  #pragma unroll
  for (int j = 0; j < 4; ++j) bj[j] = bias[n0 + j * 16 + q];
  #pragma unroll
  for (int i = 0; i < 4; ++i) {
    #pragma unroll
    for (int j = 0; j < 4; ++j) {
      #pragma unroll
      for (int r = 0; r < 4; ++r) {
        int row = m0 + i * 16 + g * 4 + r;
        int col = n0 + j * 16 + q;
        float v = acc[i][j][r] + bj[j];
        if (OUTBF16) ((unsigned short*)Cv)[(size_t)row * N + col] = f2b(v);
        else ((float*)Cv)[(size_t)row * N + col] = v;
      }
    }
  }
}

// ---------------- V transpose: qkv V-part -> Vt[(b*8+nh)*32+d][800] ----------------
__global__ __launch_bounds__(256) void k_vt(const unsigned short* __restrict__ qkv,
                                            unsigned short* __restrict__ Vt) {
  int bh = blockIdx.x;
  int b = bh >> 3, nh = bh & 7;
  int d = threadIdx.x & 31;
  int g = threadIdx.x >> 5;
  const unsigned short* src = qkv + (size_t)b * 784 * 768 + 512 + nh * 32 + d;
  unsigned short* dst = Vt + ((size_t)bh * 32 + d) * 800;
  int r0 = g * 100;
  for (int r = 0; r < 100; r += 4) {
    int rr = r0 + r;
    ushort4 o;
    o.x = (rr + 0 < 784) ? src[(size_t)(rr + 0) * 768] : (unsigned short)0;
    o.y = (rr + 1 < 784) ? src[(size_t)(rr + 1) * 768] : (unsigned short)0;
    o.z = (rr + 2 < 784) ? src[(size_t)(rr + 2) * 768] : (unsigned short)0;
    o.w = (rr + 3 < 784) ? src[(size_t)(rr + 3) * 768] : (unsigned short)0;
    *(ushort4*)(dst + rr) = o;
  }
}

// ---------------- MFMA flash attention: 1 wave = (b, head, 16 q-rows) ----------------
__global__ __launch_bounds__(64) void k_attn(const unsigned short* __restrict__ qkv,
                                             const unsigned short* __restrict__ Vt,
                                             unsigned short* __restrict__ ctx) {
  int qb = blockIdx.x;   // 0..48
  int nh = blockIdx.y;
  int b = blockIdx.z;
  int lane = threadIdx.x;
  int q = lane & 15, g = lane >> 4;
  const f32x4 zero4 = {0.f, 0.f, 0.f, 0.f};

  // Q fragment (B operand): col=lane&15 -> q row, k = g*8+e over head dims
  bf16x8 qf = *(const bf16x8*)(qkv + (size_t)(b * 784 + qb * 16 + q) * 768 + nh * 32 + g * 8);
  const unsigned short* kbase = qkv + (size_t)b * 784 * 768 + 256 + nh * 32;
  const unsigned short* vtb = Vt + (size_t)(b * 8 + nh) * 32 * 800;

  f32x4 acc0 = zero4, acc1 = zero4;
  float m = -INFINITY, l = 0.f;

  for (int c = 0; c < 25; ++c) {
    int k0 = c * 32;
    // S^T tiles: lane holds S[key=k0(+16)+g*4+r][q]
    bf16x8 kfA = *(const bf16x8*)(kbase + (size_t)(k0 + q) * 768 + g * 8);
    f32x4 s0 = __builtin_amdgcn_mfma_f32_16x16x32_bf16(kfA, qf, zero4, 0, 0, 0);
    bool hasB = (k0 + 16) < 784;
    f32x4 s1;
    if (hasB) {
      bf16x8 kfB = *(const bf16x8*)(kbase + (size_t)(k0 + 16 + q) * 768 + g * 8);
      s1 = __builtin_amdgcn_mfma_f32_16x16x32_bf16(kfB, qf, zero4, 0, 0, 0);
    } else {
      s1 = (f32x4){-1e30f, -1e30f, -1e30f, -1e30f};
    }
    float t0[4], t1[4];
    float smax = -1e30f;
    #pragma unroll
    for (int r = 0; r < 4; ++r) {
      t0[r] = s0[r] * SCALE;
      t1[r] = hasB ? s1[r] * SCALE : -1e30f;
      smax = fmaxf(smax, fmaxf(t0[r], t1[r]));
    }
    smax = fmaxf(smax, __shfl_xor(smax, 16));
    smax = fmaxf(smax, __shfl_xor(smax, 32));
    float mnew = fmaxf(m, smax);
    float sc = __expf(m - mnew);
    float p0[4], p1[4];
    float ls = 0.f;
    #pragma unroll
    for (int r = 0; r < 4; ++r) {
      p0[r] = __expf(t0[r] - mnew);
      p1[r] = __expf(t1[r] - mnew);
      ls += p0[r] + p1[r];
    }
    ls += __shfl_xor(ls, 16);
    ls += __shfl_xor(ls, 32);
    l = l * sc + ls;
    m = mnew;
    acc0 = acc0 * sc;
    acc1 = acc1 * sc;
    // pack p0/p1 as bf16 pair in u32; redistribute to PV B-operand layout
    unsigned w0 = (unsigned)f2b(p0[0]) | ((unsigned)f2b(p1[0]) << 16);
    unsigned w1 = (unsigned)f2b(p0[1]) | ((unsigned)f2b(p1[1]) << 16);
    unsigned w2 = (unsigned)f2b(p0[2]) | ((unsigned)f2b(p1[2]) << 16);
    unsigned w3 = (unsigned)f2b(p0[3]) | ((unsigned)f2b(p1[3]) << 16);
    int src0 = (g & 1) * 32 + q;
    int src1 = src0 + 16;
    unsigned e0 = (unsigned)__shfl((int)w0, src0);
    unsigned e1 = (unsigned)__shfl((int)w1, src0);
    unsigned e2 = (unsigned)__shfl((int)w2, src0);
    unsigned e3 = (unsigned)__shfl((int)w3, src0);
    unsigned e4 = (unsigned)__shfl((int)w0, src1);
    unsigned e5 = (unsigned)__shfl((int)w1, src1);
    unsigned e6 = (unsigned)__shfl((int)w2, src1);
    unsigned e7 = (unsigned)__shfl((int)w3, src1);
    bool lo = (g < 2);
    unsigned h0 = lo ? (e0 & 0xffffu) : (e0 >> 16);
    unsigned h1 = lo ? (e1 & 0xffffu) : (e1 >> 16);
    unsigned h2 = lo ? (e2 & 0xffffu) : (e2 >> 16);
    unsigned h3 = lo ? (e3 & 0xffffu) : (e3 >> 16);
    unsigned h4 = lo ? (e4 & 0xffffu) : (e4 >> 16);
    unsigned h5 = lo ? (e5 & 0xffffu) : (e5 >> 16);
    unsigned h6 = lo ? (e6 & 0xffffu) : (e6 >> 16);
    unsigned h7 = lo ? (e7 & 0xffffu) : (e7 >> 16);
    union { unsigned u[4]; bf16x8 v; } pu;
    pu.u[0] = h0 | (h1 << 16);
    pu.u[1] = h2 | (h3 << 16);
    pu.u[2] = h4 | (h5 << 16);
    pu.u[3] = h6 | (h7 << 16);
    // PV: ctx^T[d][q] += Vt_frag x P_frag
    bf16x8 v0 = *(const bf16x8*)(vtb + (size_t)q * 800 + k0 + g * 8);
    bf16x8 v1 = *(const bf16x8*)(vtb + (size_t)(16 + q) * 800 + k0 + g * 8);
    acc0 = __builtin_amdgcn_mfma_f32_16x16x32_bf16(v0, pu.v, acc0, 0, 0, 0);
    acc1 = __builtin_amdgcn_mfma_f32_16x16x32_bf16(v1, pu.v, acc1, 0, 0, 0);
  }
  float linv = 1.f / l;
  unsigned short* cp = ctx + (size_t)(b * 784 + qb * 16 + q) * 256 + nh * 32;
  ushort4 oA = make_ushort4(f2b(acc0[0] * linv), f2b(acc0[1] * linv),
                            f2b(acc0[2] * linv), f2b(acc0[3] * linv));
  ushort4 oB = make_ushort4(f2b(acc1[0] * linv), f2b(acc1[1] * linv),
                            f2b(acc1[2] * linv), f2b(acc1[3] * linv));
  *(ushort4*)(cp + g * 4) = oA;
  *(ushort4*)(cp + 16 + g * 4) = oB;
}

// ---------------- mean pool over sequence ----------------
__global__ __launch_bounds__(1024) void k_pool(const float* __restrict__ ao,
                                               float* __restrict__ out) {
  int b = blockIdx.x;
  int d = threadIdx.x & 255;
  int sg = threadIdx.x >> 8;
  float s = 0.f;
  for (int t = sg; t < 784; t += 4) s += ao[((size_t)b * 784 + t) * 256 + d];
  __shared__ float red[4][256];
  red[sg][d] = s;
  __syncthreads();
  if (sg == 0) {
    float tot = red[0][d] + red[1][d] + red[2][d] + red[3][d];
    out[b * 256 + d] = tot * (1.0f / 784.0f);
  }
}

extern "C" void kernel_launch(void* const* d_in, const int* in_sizes, int n_in,
                              void* d_out, int out_size, void* d_ws, size_t ws_size,
                              hipStream_t stream) {
  (void)in_sizes; (void)n_in; (void)out_size; (void)ws_size;
  const float* x   = (const float*)d_in[0];
  const float* cw  = (const float*)d_in[1];
  const float* ce  = (const float*)d_in[2];
  const float* ipw = (const float*)d_in[3];
  const float* ipb = (const float*)d_in[4];
  const float* opw = (const float*)d_in[5];
  const float* opb = (const float*)d_in[6];

  float* out = (float*)d_out;
  float* pooled  = out;
  float* out_sw  = out + 8192;
  float* out_idx = out + 8192 + NA;

  float* ws = (float*)d_ws;
  float* vbuf = ws;                                   // NA f32
  unsigned* hist = (unsigned*)(ws + NA);              // 65536
  unsigned* sel  = hist + 65536;                      // 16
  unsigned short* seqb = (unsigned short*)(ws + NA + 65552);      // SEQN bf16 (later: ctx)
  unsigned short* qkvb = seqb + SEQN;                 // 3*SEQN bf16 (later: aout f32)
  unsigned short* Vt   = qkvb + 3 * (size_t)SEQN;     // 256*32*800 bf16
  unsigned short* wb   = Vt + 256 * 32 * 800;         // 262144 bf16
  float* aout = (float*)qkvb;

  k_zero<<<(65552 + 255) / 256, 256, 0, stream>>>(hist, 65536 + 16);
  k_cast<<<262144 / 256, 256, 0, stream>>>(ipw, opw, wb);
  k_conv<<<NA / 256, 256, 0, stream>>>(x, cw, vbuf, hist);
  k_scan_hi<<<1, 1024, 0, stream>>>(hist, sel);
  k_hist_lo<<<NA / 256, 256, 0, stream>>>(vbuf, sel, hist);
  k_scan_lo<<<1, 1024, 0, stream>>>(hist, sel);
  k_select<<<25088 / 4, 256, 0, stream>>>(vbuf, sel, ce, seqb, out_sw, out_idx);
  {
    dim3 gq(768 / 128, 25088 / 128);
    k_gemm_mfma<1><<<gq, 256, 0, stream>>>(seqb, wb, ipb, qkvb, 25088, 768, 256);
  }
  k_vt<<<256, 256, 0, stream>>>(qkvb, Vt);
  {
    dim3 ga(49, NHEAD, NB);
    k_attn<<<ga, 64, 0, stream>>>(qkvb, Vt, seqb /* ctx */);
  }
  {
    dim3 go(256 / 128, 25088 / 128);
    k_gemm_mfma<0><<<go, 256, 0, stream>>>(seqb, wb + 196608, opb, aout, 25088, 256, 256);
  }
  k_pool<<<NB, 1024, 0, stream>>>(aout, pooled);
}

// Round 3
// 446.965 us; speedup vs baseline: 9.3216x; 1.6116x over previous
//
#include <hip/hip_runtime.h>
#include <cmath>

#define NB 32
#define C1N 64
#define DIM 256
#define NHEAD 8
#define SEQL 784
#define NA 1605632      /* NB*SEQL*C1N */
#define SEQN 6422528    /* NB*SEQL*DIM */
#define KSEL 803u
#define SCALE 0.17677669529663687f   /* 1/sqrt(32) */
#define PECOEF (-0.03597789207803197f) /* -ln(10000)/256 */

typedef __attribute__((ext_vector_type(8))) short bf16x8;
typedef __attribute__((ext_vector_type(4))) float f32x4;

__device__ __forceinline__ unsigned short f2b(float f) {
  unsigned u = __float_as_uint(f);
  unsigned r = u + 0x7fffu + ((u >> 16) & 1u);
  return (unsigned short)(r >> 16);
}

// ---------------- zero ----------------
__global__ void k_zero(unsigned* __restrict__ p, int n) {
  int i = blockIdx.x * 256 + threadIdx.x;
  if (i < n) p[i] = 0u;
}

// ---------------- weights f32 -> bf16 ----------------
__global__ __launch_bounds__(256) void k_cast(const float* __restrict__ ipw,
                                              const float* __restrict__ opw,
                                              unsigned short* __restrict__ wb) {
  int i = blockIdx.x * 256 + threadIdx.x;
  float v = (i < 196608) ? ipw[i] : opw[i - 196608];
  wb[i] = f2b(v);
}

// ---------------- conv + relu (pure) ----------------
__global__ __launch_bounds__(256) void k_conv(const float* __restrict__ x,
                                              const float* __restrict__ cw,
                                              float* __restrict__ vbuf) {
  int idx = blockIdx.x * 256 + threadIdx.x;
  int c = idx & 63;
  int p = idx >> 6;
  int wc = p % 28;
  int t2 = p / 28;
  int hr = t2 % 28;
  int b = t2 / 28;
  const float* xb = x + b * 784;
  const float* wp = cw + c * 81;
  float s = 0.0f;
  #pragma unroll
  for (int dy = 0; dy < 9; ++dy) {
    int iy = hr + dy - 4;
    if (iy < 0 || iy >= 28) continue;
    #pragma unroll
    for (int dx = 0; dx < 9; ++dx) {
      int ix = wc + dx - 4;
      if (ix < 0 || ix >= 28) continue;
      s = fmaf(xb[iy * 28 + ix], wp[dy * 9 + dx], s);
    }
  }
  vbuf[idx] = fmaxf(s, 0.0f);
}

// ---------------- radix stage A: hist of byte (bits>>24), LDS-privatized --------
__global__ __launch_bounds__(256) void k_h8(const float* __restrict__ vbuf,
                                            const unsigned* __restrict__ sel,
                                            unsigned* __restrict__ hist8,
                                            int stage) {
  __shared__ unsigned lh[256];
  int tid = threadIdx.x;
  lh[tid] = 0u;
  __syncthreads();
  if (stage == 0 || sel[2] == 0u) {
    unsigned key = (stage == 1) ? sel[0] : 0u;
    const float4* v4 = (const float4*)vbuf;
    int n4 = NA / 4;
    for (int i = blockIdx.x * 256 + tid; i < n4; i += gridDim.x * 256) {
      float4 v = v4[i];
      float vv[4] = {v.x, v.y, v.z, v.w};
      #pragma unroll
      for (int j = 0; j < 4; ++j) {
        if (vv[j] > 0.0f) {
          unsigned bits = __float_as_uint(vv[j]);
          if (stage == 0) atomicAdd(&lh[bits >> 24], 1u);
          else if ((bits >> 24) == key) atomicAdd(&lh[(bits >> 16) & 0xFFu], 1u);
        }
      }
    }
  }
  __syncthreads();
  if (lh[tid] > 0u) atomicAdd(&hist8[tid], lh[tid]);
}

// ---------------- radix stage A/B scan (256 buckets) ----------------
__global__ __launch_bounds__(256) void k_scan8(const unsigned* __restrict__ hist8,
                                               unsigned* __restrict__ sel,
                                               int stage) {
  if (stage == 1 && sel[2]) return;
  __shared__ unsigned ss[256];
  int t = threadIdx.x;
  ss[t] = hist8[t];
  __syncthreads();
  for (int off = 1; off < 256; off <<= 1) {
    unsigned v = (t + off < 256) ? ss[t + off] : 0u;
    __syncthreads();
    ss[t] += v;
    __syncthreads();
  }
  unsigned rem = (stage == 0) ? KSEL : sel[1];
  if (stage == 0 && t == 0 && ss[0] < KSEL) {
    sel[2] = 1u; sel[3] = 0u;
  }
  unsigned S = ss[t];
  unsigned above = (t < 255) ? ss[t + 1] : 0u;
  if (S >= rem && above < rem) {
    if (stage == 0) { sel[0] = (unsigned)t; sel[1] = rem - above; }
    else            { sel[4] = (unsigned)t; sel[5] = rem - above; }
  }
}

// ---------------- radix stage C: hist of low 16 bits within slice ----------------
__global__ __launch_bounds__(256) void k_h16(const float* __restrict__ vbuf,
                                             const unsigned* __restrict__ sel,
                                             unsigned* __restrict__ hist16) {
  if (sel[2]) return;
  unsigned key16 = (sel[0] << 8) | sel[4];
  const float4* v4 = (const float4*)vbuf;
  int n4 = NA / 4;
  for (int i = blockIdx.x * 256 + threadIdx.x; i < n4; i += gridDim.x * 256) {
    float4 v = v4[i];
    float vv[4] = {v.x, v.y, v.z, v.w};
    #pragma unroll
    for (int j = 0; j < 4; ++j) {
      if (vv[j] > 0.0f) {
        unsigned bits = __float_as_uint(vv[j]);
        if ((bits >> 16) == key16) atomicAdd(&hist16[bits & 0xFFFFu], 1u);
      }
    }
  }
}

// ---------------- radix stage C scan (65536 buckets) ----------------
__global__ __launch_bounds__(1024) void k_scan16(const unsigned* __restrict__ hist16,
                                                 unsigned* __restrict__ sel) {
  if (sel[2]) return;
  __shared__ unsigned ss[1024];
  int t = threadIdx.x;
  unsigned rem = sel[5];
  unsigned sum = 0;
  for (int i = 0; i < 64; ++i) sum += hist16[t * 64 + i];
  ss[t] = sum;
  __syncthreads();
  for (int off = 1; off < 1024; off <<= 1) {
    unsigned v = (t + off < 1024) ? ss[t + off] : 0u;
    __syncthreads();
    ss[t] += v;
    __syncthreads();
  }
  unsigned S = ss[t];
  unsigned above = (t < 1023) ? ss[t + 1] : 0u;
  if (S >= rem && above < rem) {
    unsigned cum = above;
    for (int bb = t * 64 + 63; bb >= t * 64; --bb) {
      unsigned hb = hist16[bb];
      cum += hb;
      if (cum >= rem) {
        sel[3] = (((sel[0] << 8) | sel[4]) << 16) | (unsigned)bb;
        break;
      }
    }
  }
}

// ---------------- top-2 select + sparse softmax + embed + pos-enc (seq in bf16) ----
__global__ __launch_bounds__(256) void k_select(const float* __restrict__ vbuf,
                                                const unsigned* __restrict__ sel,
                                                const float* __restrict__ ce,
                                                unsigned short* __restrict__ seqb,
                                                float* __restrict__ out_sw,
                                                float* __restrict__ out_idx) {
  int wid = threadIdx.x >> 6;
  int lane = threadIdx.x & 63;
  int pos = blockIdx.x * 4 + wid;
  int hw = pos % 784;
  int hr = hw / 28;
  int wc = hw % 28;
  float thr = __uint_as_float(sel[3]);
  float a = vbuf[(size_t)pos * 64 + lane];
  float val = (a >= thr) ? a : 0.0f;
  unsigned long long nzm = __ballot(val > 0.0f);
  int count = __popcll(nzm);
  float v1 = val; int i1 = lane;
  #pragma unroll
  for (int off = 32; off > 0; off >>= 1) {
    float ov = __shfl_xor(v1, off);
    int oi = __shfl_xor(i1, off);
    if (ov > v1 || (ov == v1 && oi < i1)) { v1 = ov; i1 = oi; }
  }
  float vx = (lane == i1) ? -INFINITY : val;
  float v2 = vx; int i2 = lane;
  #pragma unroll
  for (int off = 32; off > 0; off >>= 1) {
    float ov = __shfl_xor(v2, off);
    int oi = __shfl_xor(i2, off);
    if (ov > v2 || (ov == v2 && oi < i2)) { v2 = ov; i2 = oi; }
  }
  float w1 = 0.0f, w2 = 0.0f;
  if (count >= 2) {
    float e = __expf(v2 - v1);
    float invd = 1.0f / (1.0f + e);
    w1 = invd; w2 = e * invd;
  } else if (count == 1) {
    w1 = 1.0f;
  }
  float wt = (lane == i1) ? w1 : ((lane == i2) ? w2 : 0.0f);
  out_sw[(size_t)pos * 64 + lane] = wt;
  if (lane < 2) out_idx[pos * 2 + lane] = (float)(lane == 0 ? i1 : i2);
  int d0 = lane * 4;
  float4 c1v = *(const float4*)(ce + (size_t)i1 * 256 + d0);
  float4 c2v = *(const float4*)(ce + (size_t)i2 * 256 + d0);
  float dv0 = __expf((float)d0 * PECOEF);
  float dv2 = __expf((float)(d0 + 2) * PECOEF);
  float ox = w1 * c1v.x + w2 * c2v.x + sinf((float)hr * dv0);
  float oy = w1 * c1v.y + w2 * c2v.y + cosf((float)wc * dv0);
  float oz = w1 * c1v.z + w2 * c2v.z + sinf((float)hr * dv2);
  float ow = w1 * c1v.w + w2 * c2v.w + cosf((float)wc * dv2);
  ushort4 ob = make_ushort4(f2b(ox), f2b(oy), f2b(oz), f2b(ow));
  *(ushort4*)(seqb + (size_t)pos * 256 + d0) = ob;
}

// ---------------- MFMA bf16 GEMM: C[M][N] = A[M][K] @ W[N][K]^T + bias ----------------
template<int OUTBF16>
__global__ __launch_bounds__(256) void k_gemm_mfma(const unsigned short* __restrict__ A,
                                                   const unsigned short* __restrict__ W,
                                                   const float* __restrict__ bias,
                                                   void* __restrict__ Cv,
                                                   int M, int N, int K) {
  int tid = threadIdx.x;
  int lane = tid & 63, wid = tid >> 6;
  int q = lane & 15, g = lane >> 4;
  int m0 = blockIdx.y * 128 + (wid >> 1) * 64;
  int n0 = blockIdx.x * 128 + (wid & 1) * 64;
  f32x4 acc[4][4];
  #pragma unroll
  for (int i = 0; i < 4; ++i)
    #pragma unroll
    for (int j = 0; j < 4; ++j) acc[i][j] = (f32x4){0.f, 0.f, 0.f, 0.f};
  for (int k0 = 0; k0 < K; k0 += 32) {
    bf16x8 af[4], bf[4];
    #pragma unroll
    for (int i = 0; i < 4; ++i)
      af[i] = *(const bf16x8*)(A + (size_t)(m0 + i * 16 + q) * K + k0 + g * 8);
    #pragma unroll
    for (int j = 0; j < 4; ++j)
      bf[j] = *(const bf16x8*)(W + (size_t)(n0 + j * 16 + q) * K + k0 + g * 8);
    #pragma unroll
    for (int i = 0; i < 4; ++i)
      #pragma unroll
      for (int j = 0; j < 4; ++j)
        acc[i][j] = __builtin_amdgcn_mfma_f32_16x16x32_bf16(af[i], bf[j], acc[i][j], 0, 0, 0);
  }
  float bj[4];
  #pragma unroll
  for (int j = 0; j < 4; ++j) bj[j] = bias[n0 + j * 16 + q];
  #pragma unroll
  for (int i = 0; i < 4; ++i) {
    #pragma unroll
    for (int j = 0; j < 4; ++j) {
      #pragma unroll
      for (int r = 0; r < 4; ++r) {
        int row = m0 + i * 16 + g * 4 + r;
        int col = n0 + j * 16 + q;
        float v = acc[i][j][r] + bj[j];
        if (OUTBF16) ((unsigned short*)Cv)[(size_t)row * N + col] = f2b(v);
        else ((float*)Cv)[(size_t)row * N + col] = v;
      }
    }
  }
}

// ---------------- V transpose via LDS tiles: qkv V-part -> Vt[(bh)*32+d][800] -------
__global__ __launch_bounds__(256) void k_vt(const unsigned short* __restrict__ qkv,
                                            unsigned short* __restrict__ Vt) {
  __shared__ unsigned short lds[32][72];
  int k0 = blockIdx.x * 64;
  int bh = blockIdx.y;
  int b = bh >> 3, nh = bh & 7;
  int tid = threadIdx.x;
  int key = tid >> 2;
  int c8 = (tid & 3) * 8;
  int kk = k0 + key;
  ushort4 a = make_ushort4(0, 0, 0, 0), bq = a;
  if (kk < 784) {
    const unsigned short* src = qkv + (size_t)(b * 784 + kk) * 768 + 512 + nh * 32 + c8;
    a  = *(const ushort4*)src;
    bq = *(const ushort4*)(src + 4);
  }
  lds[c8 + 0][key] = a.x;  lds[c8 + 1][key] = a.y;
  lds[c8 + 2][key] = a.z;  lds[c8 + 3][key] = a.w;
  lds[c8 + 4][key] = bq.x; lds[c8 + 5][key] = bq.y;
  lds[c8 + 6][key] = bq.z; lds[c8 + 7][key] = bq.w;
  __syncthreads();
  int d = tid >> 3;
  int kc = (tid & 7) * 8;
  if (k0 + kc < 800) {
    ushort4 o0 = make_ushort4(lds[d][kc + 0], lds[d][kc + 1], lds[d][kc + 2], lds[d][kc + 3]);
    ushort4 o1 = make_ushort4(lds[d][kc + 4], lds[d][kc + 5], lds[d][kc + 6], lds[d][kc + 7]);
    unsigned short* dst = Vt + ((size_t)bh * 32 + d) * 800 + k0 + kc;
    *(ushort4*)dst = o0;
    *(ushort4*)(dst + 4) = o1;
  }
}

// ---------------- MFMA flash attention: 1 wave = (b, head, 16 q-rows) ----------------
__global__ __launch_bounds__(64) void k_attn(const unsigned short* __restrict__ qkv,
                                             const unsigned short* __restrict__ Vt,
                                             unsigned short* __restrict__ ctx) {
  int qb = blockIdx.x;   // 0..48
  int nh = blockIdx.y;
  int b = blockIdx.z;
  int lane = threadIdx.x;
  int q = lane & 15, g = lane >> 4;
  const f32x4 zero4 = {0.f, 0.f, 0.f, 0.f};

  bf16x8 qf = *(const bf16x8*)(qkv + (size_t)(b * 784 + qb * 16 + q) * 768 + nh * 32 + g * 8);
  const unsigned short* kbase = qkv + (size_t)b * 784 * 768 + 256 + nh * 32;
  const unsigned short* vtb = Vt + (size_t)(b * 8 + nh) * 32 * 800;

  f32x4 acc0 = zero4, acc1 = zero4;
  float m = -INFINITY, l = 0.f;

  for (int c = 0; c < 25; ++c) {
    int k0 = c * 32;
    bf16x8 kfA = *(const bf16x8*)(kbase + (size_t)(k0 + q) * 768 + g * 8);
    f32x4 s0 = __builtin_amdgcn_mfma_f32_16x16x32_bf16(kfA, qf, zero4, 0, 0, 0);
    bool hasB = (k0 + 16) < 784;
    f32x4 s1;
    if (hasB) {
      bf16x8 kfB = *(const bf16x8*)(kbase + (size_t)(k0 + 16 + q) * 768 + g * 8);
      s1 = __builtin_amdgcn_mfma_f32_16x16x32_bf16(kfB, qf, zero4, 0, 0, 0);
    } else {
      s1 = (f32x4){-1e30f, -1e30f, -1e30f, -1e30f};
    }
    float t0[4], t1[4];
    float smax = -1e30f;
    #pragma unroll
    for (int r = 0; r < 4; ++r) {
      t0[r] = s0[r] * SCALE;
      t1[r] = hasB ? s1[r] * SCALE : -1e30f;
      smax = fmaxf(smax, fmaxf(t0[r], t1[r]));
    }
    smax = fmaxf(smax, __shfl_xor(smax, 16));
    smax = fmaxf(smax, __shfl_xor(smax, 32));
    float mnew = fmaxf(m, smax);
    float sc = __expf(m - mnew);
    float p0[4], p1[4];
    float ls = 0.f;
    #pragma unroll
    for (int r = 0; r < 4; ++r) {
      p0[r] = __expf(t0[r] - mnew);
      p1[r] = __expf(t1[r] - mnew);
      ls += p0[r] + p1[r];
    }
    ls += __shfl_xor(ls, 16);
    ls += __shfl_xor(ls, 32);
    l = l * sc + ls;
    m = mnew;
    acc0 = acc0 * sc;
    acc1 = acc1 * sc;
    unsigned w0 = (unsigned)f2b(p0[0]) | ((unsigned)f2b(p1[0]) << 16);
    unsigned w1 = (unsigned)f2b(p0[1]) | ((unsigned)f2b(p1[1]) << 16);
    unsigned w2 = (unsigned)f2b(p0[2]) | ((unsigned)f2b(p1[2]) << 16);
    unsigned w3 = (unsigned)f2b(p0[3]) | ((unsigned)f2b(p1[3]) << 16);
    int src0 = (g & 1) * 32 + q;
    int src1 = src0 + 16;
    unsigned e0 = (unsigned)__shfl((int)w0, src0);
    unsigned e1 = (unsigned)__shfl((int)w1, src0);
    unsigned e2 = (unsigned)__shfl((int)w2, src0);
    unsigned e3 = (unsigned)__shfl((int)w3, src0);
    unsigned e4 = (unsigned)__shfl((int)w0, src1);
    unsigned e5 = (unsigned)__shfl((int)w1, src1);
    unsigned e6 = (unsigned)__shfl((int)w2, src1);
    unsigned e7 = (unsigned)__shfl((int)w3, src1);
    bool lo = (g < 2);
    unsigned h0 = lo ? (e0 & 0xffffu) : (e0 >> 16);
    unsigned h1 = lo ? (e1 & 0xffffu) : (e1 >> 16);
    unsigned h2 = lo ? (e2 & 0xffffu) : (e2 >> 16);
    unsigned h3 = lo ? (e3 & 0xffffu) : (e3 >> 16);
    unsigned h4 = lo ? (e4 & 0xffffu) : (e4 >> 16);
    unsigned h5 = lo ? (e5 & 0xffffu) : (e5 >> 16);
    unsigned h6 = lo ? (e6 & 0xffffu) : (e6 >> 16);
    unsigned h7 = lo ? (e7 & 0xffffu) : (e7 >> 16);
    union { unsigned u[4]; bf16x8 v; } pu;
    pu.u[0] = h0 | (h1 << 16);
    pu.u[1] = h2 | (h3 << 16);
    pu.u[2] = h4 | (h5 << 16);
    pu.u[3] = h6 | (h7 << 16);
    bf16x8 v0 = *(const bf16x8*)(vtb + (size_t)q * 800 + k0 + g * 8);
    bf16x8 v1 = *(const bf16x8*)(vtb + (size_t)(16 + q) * 800 + k0 + g * 8);
    acc0 = __builtin_amdgcn_mfma_f32_16x16x32_bf16(v0, pu.v, acc0, 0, 0, 0);
    acc1 = __builtin_amdgcn_mfma_f32_16x16x32_bf16(v1, pu.v, acc1, 0, 0, 0);
  }
  float linv = 1.f / l;
  unsigned short* cp = ctx + (size_t)(b * 784 + qb * 16 + q) * 256 + nh * 32;
  ushort4 oA = make_ushort4(f2b(acc0[0] * linv), f2b(acc0[1] * linv),
                            f2b(acc0[2] * linv), f2b(acc0[3] * linv));
  ushort4 oB = make_ushort4(f2b(acc1[0] * linv), f2b(acc1[1] * linv),
                            f2b(acc1[2] * linv), f2b(acc1[3] * linv));
  *(ushort4*)(cp + g * 4) = oA;
  *(ushort4*)(cp + 16 + g * 4) = oB;
}

// ---------------- mean pool over sequence ----------------
__global__ __launch_bounds__(1024) void k_pool(const float* __restrict__ ao,
                                               float* __restrict__ out) {
  int b = blockIdx.x;
  int d = threadIdx.x & 255;
  int sg = threadIdx.x >> 8;
  float s = 0.f;
  for (int t = sg; t < 784; t += 4) s += ao[((size_t)b * 784 + t) * 256 + d];
  __shared__ float red[4][256];
  red[sg][d] = s;
  __syncthreads();
  if (sg == 0) {
    float tot = red[0][d] + red[1][d] + red[2][d] + red[3][d];
    out[b * 256 + d] = tot * (1.0f / 784.0f);
  }
}

extern "C" void kernel_launch(void* const* d_in, const int* in_sizes, int n_in,
                              void* d_out, int out_size, void* d_ws, size_t ws_size,
                              hipStream_t stream) {
  (void)in_sizes; (void)n_in; (void)out_size; (void)ws_size;
  const float* x   = (const float*)d_in[0];
  const float* cw  = (const float*)d_in[1];
  const float* ce  = (const float*)d_in[2];
  const float* ipw = (const float*)d_in[3];
  const float* ipb = (const float*)d_in[4];
  const float* opw = (const float*)d_in[5];
  const float* opb = (const float*)d_in[6];

  float* out = (float*)d_out;
  float* pooled  = out;
  float* out_sw  = out + 8192;
  float* out_idx = out + 8192 + NA;

  float* ws = (float*)d_ws;
  float* vbuf = ws;                                   // NA f32
  unsigned* hist16 = (unsigned*)(ws + NA);            // 65536
  unsigned* hist8a = hist16 + 65536;                  // 256
  unsigned* hist8b = hist8a + 256;                    // 256
  unsigned* sel    = hist8b + 256;                    // 16
  unsigned short* seqb = (unsigned short*)(ws + NA + 66080);  // SEQN bf16 (later: ctx)
  unsigned short* qkvb = seqb + SEQN;                 // 3*SEQN bf16 (later: aout f32)
  unsigned short* Vt   = qkvb + 3 * (size_t)SEQN;     // 256*32*800 bf16
  unsigned short* wb   = Vt + 256 * 32 * 800;         // 262144 bf16
  float* aout = (float*)qkvb;

  k_zero<<<(66080 + 255) / 256, 256, 0, stream>>>(hist16, 66080);
  k_cast<<<262144 / 256, 256, 0, stream>>>(ipw, opw, wb);
  k_conv<<<NA / 256, 256, 0, stream>>>(x, cw, vbuf);
  k_h8<<<1024, 256, 0, stream>>>(vbuf, sel, hist8a, 0);
  k_scan8<<<1, 256, 0, stream>>>(hist8a, sel, 0);
  k_h8<<<1024, 256, 0, stream>>>(vbuf, sel, hist8b, 1);
  k_scan8<<<1, 256, 0, stream>>>(hist8b, sel, 1);
  k_h16<<<1024, 256, 0, stream>>>(vbuf, sel, hist16);
  k_scan16<<<1, 1024, 0, stream>>>(hist16, sel);
  k_select<<<25088 / 4, 256, 0, stream>>>(vbuf, sel, ce, seqb, out_sw, out_idx);
  {
    dim3 gq(768 / 128, 25088 / 128);
    k_gemm_mfma<1><<<gq, 256, 0, stream>>>(seqb, wb, ipb, qkvb, 25088, 768, 256);
  }
  {
    dim3 gv(13, 256);
    k_vt<<<gv, 256, 0, stream>>>(qkvb, Vt);
  }
  {
    dim3 ga(49, NHEAD, NB);
    k_attn<<<ga, 64, 0, stream>>>(qkvb, Vt, seqb /* ctx */);
  }
  {
    dim3 go(256 / 128, 25088 / 128);
    k_gemm_mfma<0><<<go, 256, 0, stream>>>(seqb, wb + 196608, opb, aout, 25088, 256, 256);
  }
  k_pool<<<NB, 1024, 0, stream>>>(aout, pooled);
}

// Round 4
// 441.683 us; speedup vs baseline: 9.4331x; 1.0120x over previous
//
#include <hip/hip_runtime.h>
#include <cmath>

#define NB 32
#define C1N 64
#define DIM 256
#define NHEAD 8
#define SEQL 784
#define NA 1605632      /* NB*SEQL*C1N */
#define SEQN 6422528    /* NB*SEQL*DIM */
#define KSEL 803u
#define SCALE 0.17677669529663687f   /* 1/sqrt(32) */
#define PECOEF (-0.03597789207803197f) /* -ln(10000)/256 */

typedef __attribute__((ext_vector_type(8))) short bf16x8;
typedef __attribute__((ext_vector_type(4))) float f32x4;

__device__ __forceinline__ unsigned short f2b(float f) {
  unsigned u = __float_as_uint(f);
  unsigned r = u + 0x7fffu + ((u >> 16) & 1u);
  return (unsigned short)(r >> 16);
}

__device__ __forceinline__ unsigned cvt_pk_bf16(float lo, float hi) {
  unsigned r;
  asm("v_cvt_pk_bf16_f32 %0, %1, %2" : "=v"(r) : "v"(lo), "v"(hi));
  return r;
}

// ---------------- zero ----------------
__global__ void k_zero(unsigned* __restrict__ p, int n) {
  int i = blockIdx.x * 256 + threadIdx.x;
  if (i < n) p[i] = 0u;
}

// ---------------- weights f32 -> bf16 ----------------
__global__ __launch_bounds__(256) void k_cast(const float* __restrict__ ipw,
                                              const float* __restrict__ opw,
                                              unsigned short* __restrict__ wb) {
  int i = blockIdx.x * 256 + threadIdx.x;
  float v = (i < 196608) ? ipw[i] : opw[i - 196608];
  wb[i] = f2b(v);
}

// ---------------- conv + relu (pure) ----------------
__global__ __launch_bounds__(256) void k_conv(const float* __restrict__ x,
                                              const float* __restrict__ cw,
                                              float* __restrict__ vbuf) {
  int idx = blockIdx.x * 256 + threadIdx.x;
  int c = idx & 63;
  int p = idx >> 6;
  int wc = p % 28;
  int t2 = p / 28;
  int hr = t2 % 28;
  int b = t2 / 28;
  const float* xb = x + b * 784;
  const float* wp = cw + c * 81;
  float s = 0.0f;
  #pragma unroll
  for (int dy = 0; dy < 9; ++dy) {
    int iy = hr + dy - 4;
    if (iy < 0 || iy >= 28) continue;
    #pragma unroll
    for (int dx = 0; dx < 9; ++dx) {
      int ix = wc + dx - 4;
      if (ix < 0 || ix >= 28) continue;
      s = fmaf(xb[iy * 28 + ix], wp[dy * 9 + dx], s);
    }
  }
  vbuf[idx] = fmaxf(s, 0.0f);
}

// ---------------- radix stage A/B: 8-bit hist, LDS-privatized ----------------
__global__ __launch_bounds__(256) void k_h8(const float* __restrict__ vbuf,
                                            const unsigned* __restrict__ sel,
                                            unsigned* __restrict__ hist8,
                                            int stage) {
  __shared__ unsigned lh[256];
  int tid = threadIdx.x;
  lh[tid] = 0u;
  __syncthreads();
  if (stage == 0 || sel[2] == 0u) {
    unsigned key = (stage == 1) ? sel[0] : 0u;
    const float4* v4 = (const float4*)vbuf;
    int n4 = NA / 4;
    for (int i = blockIdx.x * 256 + tid; i < n4; i += gridDim.x * 256) {
      float4 v = v4[i];
      float vv[4] = {v.x, v.y, v.z, v.w};
      #pragma unroll
      for (int j = 0; j < 4; ++j) {
        if (vv[j] > 0.0f) {
          unsigned bits = __float_as_uint(vv[j]);
          if (stage == 0) atomicAdd(&lh[bits >> 24], 1u);
          else if ((bits >> 24) == key) atomicAdd(&lh[(bits >> 16) & 0xFFu], 1u);
        }
      }
    }
  }
  __syncthreads();
  if (lh[tid] > 0u) atomicAdd(&hist8[tid], lh[tid]);
}

// ---------------- radix stage A/B scan (256 buckets) ----------------
__global__ __launch_bounds__(256) void k_scan8(const unsigned* __restrict__ hist8,
                                               unsigned* __restrict__ sel,
                                               int stage) {
  if (stage == 1 && sel[2]) return;
  __shared__ unsigned ss[256];
  int t = threadIdx.x;
  ss[t] = hist8[t];
  __syncthreads();
  for (int off = 1; off < 256; off <<= 1) {
    unsigned v = (t + off < 256) ? ss[t + off] : 0u;
    __syncthreads();
    ss[t] += v;
    __syncthreads();
  }
  unsigned rem = (stage == 0) ? KSEL : sel[1];
  if (stage == 0 && t == 0 && ss[0] < KSEL) {
    sel[2] = 1u; sel[3] = 0u;
  }
  unsigned S = ss[t];
  unsigned above = (t < 255) ? ss[t + 1] : 0u;
  if (S >= rem && above < rem) {
    if (stage == 0) { sel[0] = (unsigned)t; sel[1] = rem - above; }
    else            { sel[4] = (unsigned)t; sel[5] = rem - above; }
  }
}

// ---------------- radix stage C: hist of low 16 bits within slice ----------------
__global__ __launch_bounds__(256) void k_h16(const float* __restrict__ vbuf,
                                             const unsigned* __restrict__ sel,
                                             unsigned* __restrict__ hist16) {
  if (sel[2]) return;
  unsigned key16 = (sel[0] << 8) | sel[4];
  const float4* v4 = (const float4*)vbuf;
  int n4 = NA / 4;
  for (int i = blockIdx.x * 256 + threadIdx.x; i < n4; i += gridDim.x * 256) {
    float4 v = v4[i];
    float vv[4] = {v.x, v.y, v.z, v.w};
    #pragma unroll
    for (int j = 0; j < 4; ++j) {
      if (vv[j] > 0.0f) {
        unsigned bits = __float_as_uint(vv[j]);
        if ((bits >> 16) == key16) atomicAdd(&hist16[bits & 0xFFFFu], 1u);
      }
    }
  }
}

// ---------------- radix stage C scan (65536 buckets) ----------------
__global__ __launch_bounds__(1024) void k_scan16(const unsigned* __restrict__ hist16,
                                                 unsigned* __restrict__ sel) {
  if (sel[2]) return;
  __shared__ unsigned ss[1024];
  int t = threadIdx.x;
  unsigned rem = sel[5];
  unsigned sum = 0;
  for (int i = 0; i < 64; ++i) sum += hist16[t * 64 + i];
  ss[t] = sum;
  __syncthreads();
  for (int off = 1; off < 1024; off <<= 1) {
    unsigned v = (t + off < 1024) ? ss[t + off] : 0u;
    __syncthreads();
    ss[t] += v;
    __syncthreads();
  }
  unsigned S = ss[t];
  unsigned above = (t < 1023) ? ss[t + 1] : 0u;
  if (S >= rem && above < rem) {
    unsigned cum = above;
    for (int bb = t * 64 + 63; bb >= t * 64; --bb) {
      unsigned hb = hist16[bb];
      cum += hb;
      if (cum >= rem) {
        sel[3] = (((sel[0] << 8) | sel[4]) << 16) | (unsigned)bb;
        break;
      }
    }
  }
}

// ---------------- top-2 select + sparse softmax + embed + pos-enc (seq in bf16) ----
__global__ __launch_bounds__(256) void k_select(const float* __restrict__ vbuf,
                                                const unsigned* __restrict__ sel,
                                                const float* __restrict__ ce,
                                                unsigned short* __restrict__ seqb,
                                                float* __restrict__ out_sw,
                                                float* __restrict__ out_idx) {
  int wid = threadIdx.x >> 6;
  int lane = threadIdx.x & 63;
  int pos = blockIdx.x * 4 + wid;
  int hw = pos % 784;
  int hr = hw / 28;
  int wc = hw % 28;
  float thr = __uint_as_float(sel[3]);
  float a = vbuf[(size_t)pos * 64 + lane];
  float val = (a >= thr) ? a : 0.0f;
  unsigned long long nzm = __ballot(val > 0.0f);
  int count = __popcll(nzm);
  float v1 = val; int i1 = lane;
  #pragma unroll
  for (int off = 32; off > 0; off >>= 1) {
    float ov = __shfl_xor(v1, off);
    int oi = __shfl_xor(i1, off);
    if (ov > v1 || (ov == v1 && oi < i1)) { v1 = ov; i1 = oi; }
  }
  float vx = (lane == i1) ? -INFINITY : val;
  float v2 = vx; int i2 = lane;
  #pragma unroll
  for (int off = 32; off > 0; off >>= 1) {
    float ov = __shfl_xor(v2, off);
    int oi = __shfl_xor(i2, off);
    if (ov > v2 || (ov == v2 && oi < i2)) { v2 = ov; i2 = oi; }
  }
  float w1 = 0.0f, w2 = 0.0f;
  if (count >= 2) {
    float e = __expf(v2 - v1);
    float invd = 1.0f / (1.0f + e);
    w1 = invd; w2 = e * invd;
  } else if (count == 1) {
    w1 = 1.0f;
  }
  float wt = (lane == i1) ? w1 : ((lane == i2) ? w2 : 0.0f);
  out_sw[(size_t)pos * 64 + lane] = wt;
  if (lane < 2) out_idx[pos * 2 + lane] = (float)(lane == 0 ? i1 : i2);
  int d0 = lane * 4;
  float4 c1v = *(const float4*)(ce + (size_t)i1 * 256 + d0);
  float4 c2v = *(const float4*)(ce + (size_t)i2 * 256 + d0);
  float dv0 = __expf((float)d0 * PECOEF);
  float dv2 = __expf((float)(d0 + 2) * PECOEF);
  float ox = w1 * c1v.x + w2 * c2v.x + sinf((float)hr * dv0);
  float oy = w1 * c1v.y + w2 * c2v.y + cosf((float)wc * dv0);
  float oz = w1 * c1v.z + w2 * c2v.z + sinf((float)hr * dv2);
  float ow = w1 * c1v.w + w2 * c2v.w + cosf((float)wc * dv2);
  ushort4 ob = make_ushort4(f2b(ox), f2b(oy), f2b(oz), f2b(ow));
  *(ushort4*)(seqb + (size_t)pos * 256 + d0) = ob;
}

// ---------------- MFMA bf16 GEMM: C[M][N] = A[M][K] @ W[N][K]^T + bias -----------
// QSCALE: multiply columns <256 (the Q part of QKV) by SCALE after bias.
template<int OUTBF16, int QSCALE>
__global__ __launch_bounds__(256) void k_gemm_mfma(const unsigned short* __restrict__ A,
                                                   const unsigned short* __restrict__ W,
                                                   const float* __restrict__ bias,
                                                   void* __restrict__ Cv,
                                                   int M, int N, int K) {
  int tid = threadIdx.x;
  int lane = tid & 63, wid = tid >> 6;
  int q = lane & 15, g = lane >> 4;
  int m0 = blockIdx.y * 128 + (wid >> 1) * 64;
  int n0 = blockIdx.x * 128 + (wid & 1) * 64;
  f32x4 acc[4][4];
  #pragma unroll
  for (int i = 0; i < 4; ++i)
    #pragma unroll
    for (int j = 0; j < 4; ++j) acc[i][j] = (f32x4){0.f, 0.f, 0.f, 0.f};
  for (int k0 = 0; k0 < K; k0 += 32) {
    bf16x8 af[4], bf[4];
    #pragma unroll
    for (int i = 0; i < 4; ++i)
      af[i] = *(const bf16x8*)(A + (size_t)(m0 + i * 16 + q) * K + k0 + g * 8);
    #pragma unroll
    for (int j = 0; j < 4; ++j)
      bf[j] = *(const bf16x8*)(W + (size_t)(n0 + j * 16 + q) * K + k0 + g * 8);
    #pragma unroll
    for (int i = 0; i < 4; ++i)
      #pragma unroll
      for (int j = 0; j < 4; ++j)
        acc[i][j] = __builtin_amdgcn_mfma_f32_16x16x32_bf16(af[i], bf[j], acc[i][j], 0, 0, 0);
  }
  float bj[4];
  #pragma unroll
  for (int j = 0; j < 4; ++j) bj[j] = bias[n0 + j * 16 + q];
  #pragma unroll
  for (int i = 0; i < 4; ++i) {
    #pragma unroll
    for (int j = 0; j < 4; ++j) {
      int col = n0 + j * 16 + q;
      #pragma unroll
      for (int r = 0; r < 4; ++r) {
        int row = m0 + i * 16 + g * 4 + r;
        float v = acc[i][j][r] + bj[j];
        if (QSCALE && col < 256) v *= SCALE;
        if (OUTBF16) ((unsigned short*)Cv)[(size_t)row * N + col] = f2b(v);
        else ((float*)Cv)[(size_t)row * N + col] = v;
      }
    }
  }
}

// ---------------- V transpose via LDS tiles: qkv V-part -> Vt[(bh)*32+d][800] -------
__global__ __launch_bounds__(256) void k_vt(const unsigned short* __restrict__ qkv,
                                            unsigned short* __restrict__ Vt) {
  __shared__ unsigned short lds[32][72];
  int k0 = blockIdx.x * 64;
  int bh = blockIdx.y;
  int b = bh >> 3, nh = bh & 7;
  int tid = threadIdx.x;
  int key = tid >> 2;
  int c8 = (tid & 3) * 8;
  int kk = k0 + key;
  ushort4 a = make_ushort4(0, 0, 0, 0), bq = a;
  if (kk < 784) {
    const unsigned short* src = qkv + (size_t)(b * 784 + kk) * 768 + 512 + nh * 32 + c8;
    a  = *(const ushort4*)src;
    bq = *(const ushort4*)(src + 4);
  }
  lds[c8 + 0][key] = a.x;  lds[c8 + 1][key] = a.y;
  lds[c8 + 2][key] = a.z;  lds[c8 + 3][key] = a.w;
  lds[c8 + 4][key] = bq.x; lds[c8 + 5][key] = bq.y;
  lds[c8 + 6][key] = bq.z; lds[c8 + 7][key] = bq.w;
  __syncthreads();
  int d = tid >> 3;
  int kc = (tid & 7) * 8;
  if (k0 + kc < 800) {
    ushort4 o0 = make_ushort4(lds[d][kc + 0], lds[d][kc + 1], lds[d][kc + 2], lds[d][kc + 3]);
    ushort4 o1 = make_ushort4(lds[d][kc + 4], lds[d][kc + 5], lds[d][kc + 6], lds[d][kc + 7]);
    unsigned short* dst = Vt + ((size_t)bh * 32 + d) * 800 + k0 + kc;
    *(ushort4*)dst = o0;
    *(ushort4*)(dst + 4) = o1;
  }
}

// ---- MFMA flash attention: 1 wave = (b, head, 16 q-rows); XCD-swizzled 1D grid ----
__global__ __launch_bounds__(64) void k_attn(const unsigned short* __restrict__ qkv,
                                             const unsigned short* __restrict__ Vt,
                                             unsigned short* __restrict__ ctx) {
  // 12544 = 8 XCDs * 1568; give each XCD a contiguous run of (bh, qb) work
  int dd = blockIdx.x;
  int work = (dd & 7) * 1568 + (dd >> 3);
  int bh = work / 49;
  int qb = work - bh * 49;
  int b = bh >> 3, nh = bh & 7;
  int lane = threadIdx.x;
  int q = lane & 15, g = lane >> 4;
  const f32x4 zero4 = {0.f, 0.f, 0.f, 0.f};

  bf16x8 qf = *(const bf16x8*)(qkv + (size_t)(b * 784 + qb * 16 + q) * 768 + nh * 32 + g * 8);
  const unsigned short* kbase = qkv + (size_t)b * 784 * 768 + 256 + nh * 32;
  const unsigned short* vtb = Vt + (size_t)bh * 32 * 800;

  f32x4 acc0 = zero4, acc1 = zero4;
  float m = -INFINITY, l = 0.f;
  unsigned psel = (g < 2) ? 0x05040100u : 0x07060302u;

  for (int c = 0; c < 25; ++c) {
    int k0 = c * 32;
    bf16x8 kfA = *(const bf16x8*)(kbase + (size_t)(k0 + q) * 768 + g * 8);
    f32x4 s0 = __builtin_amdgcn_mfma_f32_16x16x32_bf16(kfA, qf, zero4, 0, 0, 0);
    bool hasB = (k0 + 16) < 784;
    f32x4 s1;
    if (hasB) {
      bf16x8 kfB = *(const bf16x8*)(kbase + (size_t)(k0 + 16 + q) * 768 + g * 8);
      s1 = __builtin_amdgcn_mfma_f32_16x16x32_bf16(kfB, qf, zero4, 0, 0, 0);
    } else {
      s1 = (f32x4){-1e30f, -1e30f, -1e30f, -1e30f};
    }
    // Q was pre-scaled by 1/sqrt(hd) in the QKV GEMM epilogue.
    float pmax = fmaxf(fmaxf(fmaxf(s0[0], s0[1]), fmaxf(s0[2], s0[3])),
                       fmaxf(fmaxf(s1[0], s1[1]), fmaxf(s1[2], s1[3])));
    pmax = fmaxf(pmax, __shfl_xor(pmax, 16));
    pmax = fmaxf(pmax, __shfl_xor(pmax, 32));
    // defer-max: only rescale when the running max grows by >8
    if (!__all(pmax <= m + 8.0f)) {
      float mnew = fmaxf(m, pmax);
      float sc = __expf(m - mnew);
      l *= sc;
      acc0 *= sc;
      acc1 *= sc;
      m = mnew;
    }
    float p0[4], p1[4];
    float ls = 0.f;
    #pragma unroll
    for (int r = 0; r < 4; ++r) {
      p0[r] = __expf(s0[r] - m);
      p1[r] = __expf(s1[r] - m);
      ls += p0[r] + p1[r];
    }
    ls += __shfl_xor(ls, 16);
    ls += __shfl_xor(ls, 32);
    l += ls;
    unsigned w0 = cvt_pk_bf16(p0[0], p1[0]);
    unsigned w1 = cvt_pk_bf16(p0[1], p1[1]);
    unsigned w2 = cvt_pk_bf16(p0[2], p1[2]);
    unsigned w3 = cvt_pk_bf16(p0[3], p1[3]);
    int src0 = (g & 1) * 32 + q;
    int src1 = src0 + 16;
    unsigned e0 = (unsigned)__shfl((int)w0, src0);
    unsigned e1 = (unsigned)__shfl((int)w1, src0);
    unsigned e2 = (unsigned)__shfl((int)w2, src0);
    unsigned e3 = (unsigned)__shfl((int)w3, src0);
    unsigned e4 = (unsigned)__shfl((int)w0, src1);
    unsigned e5 = (unsigned)__shfl((int)w1, src1);
    unsigned e6 = (unsigned)__shfl((int)w2, src1);
    unsigned e7 = (unsigned)__shfl((int)w3, src1);
    union { unsigned u[4]; bf16x8 v; } pu;
    pu.u[0] = __builtin_amdgcn_perm(e1, e0, psel);
    pu.u[1] = __builtin_amdgcn_perm(e3, e2, psel);
    pu.u[2] = __builtin_amdgcn_perm(e5, e4, psel);
    pu.u[3] = __builtin_amdgcn_perm(e7, e6, psel);
    bf16x8 v0 = *(const bf16x8*)(vtb + (size_t)q * 800 + k0 + g * 8);
    bf16x8 v1 = *(const bf16x8*)(vtb + (size_t)(16 + q) * 800 + k0 + g * 8);
    acc0 = __builtin_amdgcn_mfma_f32_16x16x32_bf16(v0, pu.v, acc0, 0, 0, 0);
    acc1 = __builtin_amdgcn_mfma_f32_16x16x32_bf16(v1, pu.v, acc1, 0, 0, 0);
  }
  float linv = 1.f / l;
  unsigned short* cp = ctx + (size_t)(b * 784 + qb * 16 + q) * 256 + nh * 32;
  ushort4 oA = make_ushort4(f2b(acc0[0] * linv), f2b(acc0[1] * linv),
                            f2b(acc0[2] * linv), f2b(acc0[3] * linv));
  ushort4 oB = make_ushort4(f2b(acc1[0] * linv), f2b(acc1[1] * linv),
                            f2b(acc1[2] * linv), f2b(acc1[3] * linv));
  *(ushort4*)(cp + g * 4) = oA;
  *(ushort4*)(cp + 16 + g * 4) = oB;
}

// ---------------- mean pool over sequence ----------------
__global__ __launch_bounds__(1024) void k_pool(const float* __restrict__ ao,
                                               float* __restrict__ out) {
  int b = blockIdx.x;
  int d = threadIdx.x & 255;
  int sg = threadIdx.x >> 8;
  float s = 0.f;
  for (int t = sg; t < 784; t += 4) s += ao[((size_t)b * 784 + t) * 256 + d];
  __shared__ float red[4][256];
  red[sg][d] = s;
  __syncthreads();
  if (sg == 0) {
    float tot = red[0][d] + red[1][d] + red[2][d] + red[3][d];
    out[b * 256 + d] = tot * (1.0f / 784.0f);
  }
}

extern "C" void kernel_launch(void* const* d_in, const int* in_sizes, int n_in,
                              void* d_out, int out_size, void* d_ws, size_t ws_size,
                              hipStream_t stream) {
  (void)in_sizes; (void)n_in; (void)out_size; (void)ws_size;
  const float* x   = (const float*)d_in[0];
  const float* cw  = (const float*)d_in[1];
  const float* ce  = (const float*)d_in[2];
  const float* ipw = (const float*)d_in[3];
  const float* ipb = (const float*)d_in[4];
  const float* opw = (const float*)d_in[5];
  const float* opb = (const float*)d_in[6];

  float* out = (float*)d_out;
  float* pooled  = out;
  float* out_sw  = out + 8192;
  float* out_idx = out + 8192 + NA;

  float* ws = (float*)d_ws;
  float* vbuf = ws;                                   // NA f32
  unsigned* hist16 = (unsigned*)(ws + NA);            // 65536
  unsigned* hist8a = hist16 + 65536;                  // 256
  unsigned* hist8b = hist8a + 256;                    // 256
  unsigned* sel    = hist8b + 256;                    // 16
  unsigned short* seqb = (unsigned short*)(ws + NA + 66080);  // SEQN bf16 (later: ctx)
  unsigned short* qkvb = seqb + SEQN;                 // 3*SEQN bf16 (later: aout f32)
  unsigned short* Vt   = qkvb + 3 * (size_t)SEQN;     // 256*32*800 bf16
  unsigned short* wb   = Vt + 256 * 32 * 800;         // 262144 bf16
  float* aout = (float*)qkvb;

  k_zero<<<(66080 + 255) / 256, 256, 0, stream>>>(hist16, 66080);
  k_cast<<<262144 / 256, 256, 0, stream>>>(ipw, opw, wb);
  k_conv<<<NA / 256, 256, 0, stream>>>(x, cw, vbuf);
  k_h8<<<1024, 256, 0, stream>>>(vbuf, sel, hist8a, 0);
  k_scan8<<<1, 256, 0, stream>>>(hist8a, sel, 0);
  k_h8<<<1024, 256, 0, stream>>>(vbuf, sel, hist8b, 1);
  k_scan8<<<1, 256, 0, stream>>>(hist8b, sel, 1);
  k_h16<<<1024, 256, 0, stream>>>(vbuf, sel, hist16);
  k_scan16<<<1, 1024, 0, stream>>>(hist16, sel);
  k_select<<<25088 / 4, 256, 0, stream>>>(vbuf, sel, ce, seqb, out_sw, out_idx);
  {
    dim3 gq(768 / 128, 25088 / 128);
    k_gemm_mfma<1, 1><<<gq, 256, 0, stream>>>(seqb, wb, ipb, qkvb, 25088, 768, 256);
  }
  {
    dim3 gv(13, 256);
    k_vt<<<gv, 256, 0, stream>>>(qkvb, Vt);
  }
  k_attn<<<12544, 64, 0, stream>>>(qkvb, Vt, seqb /* ctx */);
  {
    dim3 go(256 / 128, 25088 / 128);
    k_gemm_mfma<0, 0><<<go, 256, 0, stream>>>(seqb, wb + 196608, opb, aout, 25088, 256, 256);
  }
  k_pool<<<NB, 1024, 0, stream>>>(aout, pooled);
}

// Round 5
// 334.452 us; speedup vs baseline: 12.4575x; 1.3206x over previous
//
#include <hip/hip_runtime.h>
#include <cmath>

#define NB 32
#define C1N 64
#define DIM 256
#define NHEAD 8
#define SEQL 784
#define NA 1605632      /* NB*SEQL*C1N */
#define SEQN 6422528    /* NB*SEQL*DIM */
#define KSEL 803u
#define SCALE 0.17677669529663687f   /* 1/sqrt(32) */
#define PECOEF (-0.03597789207803197f) /* -ln(10000)/256 */

typedef __attribute__((ext_vector_type(8))) short bf16x8;
typedef __attribute__((ext_vector_type(4))) float f32x4;

__device__ __forceinline__ unsigned short f2b(float f) {
  unsigned u = __float_as_uint(f);
  unsigned r = u + 0x7fffu + ((u >> 16) & 1u);
  return (unsigned short)(r >> 16);
}

__device__ __forceinline__ unsigned cvt_pk_bf16(float lo, float hi) {
  unsigned r;
  asm("v_cvt_pk_bf16_f32 %0, %1, %2" : "=v"(r) : "v"(lo), "v"(hi));
  return r;
}

// ---------------- zero ----------------
__global__ void k_zero(unsigned* __restrict__ p, int n) {
  int i = blockIdx.x * 256 + threadIdx.x;
  if (i < n) p[i] = 0u;
}

// ---------------- weights f32 -> bf16 ----------------
__global__ __launch_bounds__(256) void k_cast(const float* __restrict__ ipw,
                                              const float* __restrict__ opw,
                                              unsigned short* __restrict__ wb) {
  int i = blockIdx.x * 256 + threadIdx.x;
  float v = (i < 196608) ? ipw[i] : opw[i - 196608];
  wb[i] = f2b(v);
}

// ---------------- conv + relu: LDS weights (transposed) + padded LDS image -------
// grid = 32 images x 7 col-blocks; block = 256 thr (4 waves); wave = 64 channels,
// 4 adjacent output columns per iteration.
__global__ __launch_bounds__(256) void k_conv(const float* __restrict__ x,
                                              const float* __restrict__ cw,
                                              float* __restrict__ vbuf) {
  __shared__ __align__(16) float ximg[1296];   // 36x36 zero-padded image
  __shared__ float wlds[5184];                 // [tap 0..80][channel 0..63]
  int tid = threadIdx.x;
  int b = blockIdx.x / 7, sblk = blockIdx.x % 7;
  for (int e = tid; e < 1296; e += 256) ximg[e] = 0.f;
  for (int e = tid; e < 5184; e += 256) {
    int c = e / 81, t = e - c * 81;
    wlds[t * 64 + c] = cw[e];
  }
  __syncthreads();
  const float* xb = x + b * 784;
  for (int e = tid; e < 784; e += 256) {
    int row = e / 28, col = e - row * 28;
    ximg[(row + 4) * 36 + col + 4] = xb[e];
  }
  __syncthreads();
  int wv = tid >> 6, lane = tid & 63;
  for (int it = 0; it < 7; ++it) {
    int grp = sblk * 28 + it * 4 + wv;     // 0..195
    int hr = grp / 7, wc0 = (grp % 7) * 4;
    float a0 = 0.f, a1 = 0.f, a2 = 0.f, a3 = 0.f;
    #pragma unroll
    for (int dy = 0; dy < 9; ++dy) {
      const float4* xr4 = (const float4*)&ximg[(hr + dy) * 36 + wc0];
      float4 xa = xr4[0], xbq = xr4[1], xc = xr4[2];
      float xr[12] = {xa.x, xa.y, xa.z, xa.w, xbq.x, xbq.y, xbq.z, xbq.w,
                      xc.x, xc.y, xc.z, xc.w};
      #pragma unroll
      for (int dx = 0; dx < 9; ++dx) {
        float w = wlds[(dy * 9 + dx) * 64 + lane];
        a0 = fmaf(xr[dx + 0], w, a0);
        a1 = fmaf(xr[dx + 1], w, a1);
        a2 = fmaf(xr[dx + 2], w, a2);
        a3 = fmaf(xr[dx + 3], w, a3);
      }
    }
    size_t base = ((size_t)(b * 784 + hr * 28 + wc0)) * 64 + lane;
    vbuf[base +   0] = fmaxf(a0, 0.f);
    vbuf[base +  64] = fmaxf(a1, 0.f);
    vbuf[base + 128] = fmaxf(a2, 0.f);
    vbuf[base + 192] = fmaxf(a3, 0.f);
  }
}

// ---------------- radix stage A/B: 8-bit hist, LDS-privatized ----------------
__global__ __launch_bounds__(256) void k_h8(const float* __restrict__ vbuf,
                                            const unsigned* __restrict__ sel,
                                            unsigned* __restrict__ hist8,
                                            int stage) {
  __shared__ unsigned lh[256];
  int tid = threadIdx.x;
  lh[tid] = 0u;
  __syncthreads();
  if (stage == 0 || sel[2] == 0u) {
    unsigned key = (stage == 1) ? sel[0] : 0u;
    const float4* v4 = (const float4*)vbuf;
    int n4 = NA / 4;
    for (int i = blockIdx.x * 256 + tid; i < n4; i += gridDim.x * 256) {
      float4 v = v4[i];
      float vv[4] = {v.x, v.y, v.z, v.w};
      #pragma unroll
      for (int j = 0; j < 4; ++j) {
        if (vv[j] > 0.0f) {
          unsigned bits = __float_as_uint(vv[j]);
          if (stage == 0) atomicAdd(&lh[bits >> 24], 1u);
          else if ((bits >> 24) == key) atomicAdd(&lh[(bits >> 16) & 0xFFu], 1u);
        }
      }
    }
  }
  __syncthreads();
  if (lh[tid] > 0u) atomicAdd(&hist8[tid], lh[tid]);
}

// ---------------- radix stage A/B scan (256 buckets) ----------------
__global__ __launch_bounds__(256) void k_scan8(const unsigned* __restrict__ hist8,
                                               unsigned* __restrict__ sel,
                                               int stage) {
  if (stage == 1 && sel[2]) return;
  __shared__ unsigned ss[256];
  int t = threadIdx.x;
  ss[t] = hist8[t];
  __syncthreads();
  for (int off = 1; off < 256; off <<= 1) {
    unsigned v = (t + off < 256) ? ss[t + off] : 0u;
    __syncthreads();
    ss[t] += v;
    __syncthreads();
  }
  unsigned rem = (stage == 0) ? KSEL : sel[1];
  if (stage == 0 && t == 0 && ss[0] < KSEL) {
    sel[2] = 1u; sel[3] = 0u;
  }
  unsigned S = ss[t];
  unsigned above = (t < 255) ? ss[t + 1] : 0u;
  if (S >= rem && above < rem) {
    if (stage == 0) { sel[0] = (unsigned)t; sel[1] = rem - above; }
    else            { sel[4] = (unsigned)t; sel[5] = rem - above; }
  }
}

// ---------------- radix stage C: hist of low 16 bits within slice ----------------
__global__ __launch_bounds__(256) void k_h16(const float* __restrict__ vbuf,
                                             const unsigned* __restrict__ sel,
                                             unsigned* __restrict__ hist16) {
  if (sel[2]) return;
  unsigned key16 = (sel[0] << 8) | sel[4];
  const float4* v4 = (const float4*)vbuf;
  int n4 = NA / 4;
  for (int i = blockIdx.x * 256 + threadIdx.x; i < n4; i += gridDim.x * 256) {
    float4 v = v4[i];
    float vv[4] = {v.x, v.y, v.z, v.w};
    #pragma unroll
    for (int j = 0; j < 4; ++j) {
      if (vv[j] > 0.0f) {
        unsigned bits = __float_as_uint(vv[j]);
        if ((bits >> 16) == key16) atomicAdd(&hist16[bits & 0xFFFFu], 1u);
      }
    }
  }
}

// ---------------- radix stage C scan (65536 buckets) ----------------
__global__ __launch_bounds__(1024) void k_scan16(const unsigned* __restrict__ hist16,
                                                 unsigned* __restrict__ sel) {
  if (sel[2]) return;
  __shared__ unsigned ss[1024];
  int t = threadIdx.x;
  unsigned rem = sel[5];
  unsigned sum = 0;
  for (int i = 0; i < 64; ++i) sum += hist16[t * 64 + i];
  ss[t] = sum;
  __syncthreads();
  for (int off = 1; off < 1024; off <<= 1) {
    unsigned v = (t + off < 1024) ? ss[t + off] : 0u;
    __syncthreads();
    ss[t] += v;
    __syncthreads();
  }
  unsigned S = ss[t];
  unsigned above = (t < 1023) ? ss[t + 1] : 0u;
  if (S >= rem && above < rem) {
    unsigned cum = above;
    for (int bb = t * 64 + 63; bb >= t * 64; --bb) {
      unsigned hb = hist16[bb];
      cum += hb;
      if (cum >= rem) {
        sel[3] = (((sel[0] << 8) | sel[4]) << 16) | (unsigned)bb;
        break;
      }
    }
  }
}

// ---------------- top-2 select + sparse softmax + embed + pos-enc (seq in bf16) ----
__global__ __launch_bounds__(256) void k_select(const float* __restrict__ vbuf,
                                                const unsigned* __restrict__ sel,
                                                const float* __restrict__ ce,
                                                unsigned short* __restrict__ seqb,
                                                float* __restrict__ out_sw,
                                                float* __restrict__ out_idx) {
  int wid = threadIdx.x >> 6;
  int lane = threadIdx.x & 63;
  int pos = blockIdx.x * 4 + wid;
  int hw = pos % 784;
  int hr = hw / 28;
  int wc = hw % 28;
  float thr = __uint_as_float(sel[3]);
  float a = vbuf[(size_t)pos * 64 + lane];
  float val = (a >= thr) ? a : 0.0f;
  unsigned long long nzm = __ballot(val > 0.0f);
  int count = __popcll(nzm);
  float v1 = val; int i1 = lane;
  #pragma unroll
  for (int off = 32; off > 0; off >>= 1) {
    float ov = __shfl_xor(v1, off);
    int oi = __shfl_xor(i1, off);
    if (ov > v1 || (ov == v1 && oi < i1)) { v1 = ov; i1 = oi; }
  }
  float vx = (lane == i1) ? -INFINITY : val;
  float v2 = vx; int i2 = lane;
  #pragma unroll
  for (int off = 32; off > 0; off >>= 1) {
    float ov = __shfl_xor(v2, off);
    int oi = __shfl_xor(i2, off);
    if (ov > v2 || (ov == v2 && oi < i2)) { v2 = ov; i2 = oi; }
  }
  float w1 = 0.0f, w2 = 0.0f;
  if (count >= 2) {
    float e = __expf(v2 - v1);
    float invd = 1.0f / (1.0f + e);
    w1 = invd; w2 = e * invd;
  } else if (count == 1) {
    w1 = 1.0f;
  }
  float wt = (lane == i1) ? w1 : ((lane == i2) ? w2 : 0.0f);
  out_sw[(size_t)pos * 64 + lane] = wt;
  if (lane < 2) out_idx[pos * 2 + lane] = (float)(lane == 0 ? i1 : i2);
  int d0 = lane * 4;
  float4 c1v = *(const float4*)(ce + (size_t)i1 * 256 + d0);
  float4 c2v = *(const float4*)(ce + (size_t)i2 * 256 + d0);
  float dv0 = __expf((float)d0 * PECOEF);
  float dv2 = __expf((float)(d0 + 2) * PECOEF);
  float ox = w1 * c1v.x + w2 * c2v.x + sinf((float)hr * dv0);
  float oy = w1 * c1v.y + w2 * c2v.y + cosf((float)wc * dv0);
  float oz = w1 * c1v.z + w2 * c2v.z + sinf((float)hr * dv2);
  float ow = w1 * c1v.w + w2 * c2v.w + cosf((float)wc * dv2);
  ushort4 ob = make_ushort4(f2b(ox), f2b(oy), f2b(oz), f2b(ow));
  *(ushort4*)(seqb + (size_t)pos * 256 + d0) = ob;
}

// ---------------- MFMA bf16 GEMM: C[M][N] = A[M][K] @ W[N][K]^T + bias -----------
template<int OUTBF16, int QSCALE>
__global__ __launch_bounds__(256) void k_gemm_mfma(const unsigned short* __restrict__ A,
                                                   const unsigned short* __restrict__ W,
                                                   const float* __restrict__ bias,
                                                   void* __restrict__ Cv,
                                                   int M, int N, int K) {
  int tid = threadIdx.x;
  int lane = tid & 63, wid = tid >> 6;
  int q = lane & 15, g = lane >> 4;
  int m0 = blockIdx.y * 128 + (wid >> 1) * 64;
  int n0 = blockIdx.x * 128 + (wid & 1) * 64;
  f32x4 acc[4][4];
  #pragma unroll
  for (int i = 0; i < 4; ++i)
    #pragma unroll
    for (int j = 0; j < 4; ++j) acc[i][j] = (f32x4){0.f, 0.f, 0.f, 0.f};
  for (int k0 = 0; k0 < K; k0 += 32) {
    bf16x8 af[4], bf[4];
    #pragma unroll
    for (int i = 0; i < 4; ++i)
      af[i] = *(const bf16x8*)(A + (size_t)(m0 + i * 16 + q) * K + k0 + g * 8);
    #pragma unroll
    for (int j = 0; j < 4; ++j)
      bf[j] = *(const bf16x8*)(W + (size_t)(n0 + j * 16 + q) * K + k0 + g * 8);
    #pragma unroll
    for (int i = 0; i < 4; ++i)
      #pragma unroll
      for (int j = 0; j < 4; ++j)
        acc[i][j] = __builtin_amdgcn_mfma_f32_16x16x32_bf16(af[i], bf[j], acc[i][j], 0, 0, 0);
  }
  float bj[4];
  #pragma unroll
  for (int j = 0; j < 4; ++j) bj[j] = bias[n0 + j * 16 + q];
  #pragma unroll
  for (int i = 0; i < 4; ++i) {
    #pragma unroll
    for (int j = 0; j < 4; ++j) {
      int col = n0 + j * 16 + q;
      #pragma unroll
      for (int r = 0; r < 4; ++r) {
        int row = m0 + i * 16 + g * 4 + r;
        float v = acc[i][j][r] + bj[j];
        if (QSCALE && col < 256) v *= SCALE;
        if (OUTBF16) ((unsigned short*)Cv)[(size_t)row * N + col] = f2b(v);
        else ((float*)Cv)[(size_t)row * N + col] = v;
      }
    }
  }
}

// ---------------- V transpose via LDS tiles: qkv V-part -> Vt[(bh)*32+d][800] -------
__global__ __launch_bounds__(256) void k_vt(const unsigned short* __restrict__ qkv,
                                            unsigned short* __restrict__ Vt) {
  __shared__ unsigned short lds[32][72];
  int k0 = blockIdx.x * 64;
  int bh = blockIdx.y;
  int b = bh >> 3, nh = bh & 7;
  int tid = threadIdx.x;
  int key = tid >> 2;
  int c8 = (tid & 3) * 8;
  int kk = k0 + key;
  ushort4 a = make_ushort4(0, 0, 0, 0), bq = a;
  if (kk < 784) {
    const unsigned short* src = qkv + (size_t)(b * 784 + kk) * 768 + 512 + nh * 32 + c8;
    a  = *(const ushort4*)src;
    bq = *(const ushort4*)(src + 4);
  }
  lds[c8 + 0][key] = a.x;  lds[c8 + 1][key] = a.y;
  lds[c8 + 2][key] = a.z;  lds[c8 + 3][key] = a.w;
  lds[c8 + 4][key] = bq.x; lds[c8 + 5][key] = bq.y;
  lds[c8 + 6][key] = bq.z; lds[c8 + 7][key] = bq.w;
  __syncthreads();
  int d = tid >> 3;
  int kc = (tid & 7) * 8;
  if (k0 + kc < 800) {
    ushort4 o0 = make_ushort4(lds[d][kc + 0], lds[d][kc + 1], lds[d][kc + 2], lds[d][kc + 3]);
    ushort4 o1 = make_ushort4(lds[d][kc + 4], lds[d][kc + 5], lds[d][kc + 6], lds[d][kc + 7]);
    unsigned short* dst = Vt + ((size_t)bh * 32 + d) * 800 + k0 + kc;
    *(ushort4*)dst = o0;
    *(ushort4*)(dst + 4) = o1;
  }
}

// ---- MFMA flash attention: 1 wave = (b, head, 16 q-rows); XCD-swizzled; pipelined --
__global__ __launch_bounds__(64) void k_attn(const unsigned short* __restrict__ qkv,
                                             const unsigned short* __restrict__ Vt,
                                             unsigned short* __restrict__ ctx) {
  int dd = blockIdx.x;
  int work = (dd & 7) * 1568 + (dd >> 3);
  int bh = work / 49;
  int qb = work - bh * 49;
  int b = bh >> 3, nh = bh & 7;
  int lane = threadIdx.x;
  int q = lane & 15, g = lane >> 4;
  const f32x4 zero4 = {0.f, 0.f, 0.f, 0.f};

  bf16x8 qf = *(const bf16x8*)(qkv + (size_t)(b * 784 + qb * 16 + q) * 768 + nh * 32 + g * 8);
  const unsigned short* kbase = qkv + (size_t)b * 784 * 768 + 256 + nh * 32;
  const unsigned short* vtb = Vt + (size_t)bh * 32 * 800;

  f32x4 acc0 = zero4, acc1 = zero4;
  float m = -INFINITY, l = 0.f;
  unsigned psel = (g < 2) ? 0x05040100u : 0x07060302u;

  // prologue: fragments for c = 0
  bf16x8 kA = *(const bf16x8*)(kbase + (size_t)q * 768 + g * 8);
  bf16x8 kB = *(const bf16x8*)(kbase + (size_t)(16 + q) * 768 + g * 8);
  bf16x8 v0 = *(const bf16x8*)(vtb + (size_t)q * 800 + g * 8);
  bf16x8 v1 = *(const bf16x8*)(vtb + (size_t)(16 + q) * 800 + g * 8);

  for (int c = 0; c < 25; ++c) {
    bool hasB = (c < 24);
    // prefetch next iteration's fragments before the dependent chain
    bf16x8 nkA, nkB, nv0, nv1;
    if (c < 24) {
      int k1 = c * 32 + 32;
      nkA = *(const bf16x8*)(kbase + (size_t)(k1 + q) * 768 + g * 8);
      if (c < 23)
        nkB = *(const bf16x8*)(kbase + (size_t)(k1 + 16 + q) * 768 + g * 8);
      nv0 = *(const bf16x8*)(vtb + (size_t)q * 800 + k1 + g * 8);
      nv1 = *(const bf16x8*)(vtb + (size_t)(16 + q) * 800 + k1 + g * 8);
    }
    __builtin_amdgcn_s_setprio(1);
    f32x4 s0 = __builtin_amdgcn_mfma_f32_16x16x32_bf16(kA, qf, zero4, 0, 0, 0);
    f32x4 s1;
    if (hasB) s1 = __builtin_amdgcn_mfma_f32_16x16x32_bf16(kB, qf, zero4, 0, 0, 0);
    else      s1 = (f32x4){-1e30f, -1e30f, -1e30f, -1e30f};
    __builtin_amdgcn_s_setprio(0);
    float pmax = fmaxf(fmaxf(fmaxf(s0[0], s0[1]), fmaxf(s0[2], s0[3])),
                       fmaxf(fmaxf(s1[0], s1[1]), fmaxf(s1[2], s1[3])));
    pmax = fmaxf(pmax, __shfl_xor(pmax, 16));
    pmax = fmaxf(pmax, __shfl_xor(pmax, 32));
    if (!__all(pmax <= m + 8.0f)) {
      float mnew = fmaxf(m, pmax);
      float sc = __expf(m - mnew);
      l *= sc;
      acc0 *= sc;
      acc1 *= sc;
      m = mnew;
    }
    float p0[4], p1[4];
    float ls = 0.f;
    #pragma unroll
    for (int r = 0; r < 4; ++r) {
      p0[r] = __expf(s0[r] - m);
      p1[r] = __expf(s1[r] - m);
      ls += p0[r] + p1[r];
    }
    ls += __shfl_xor(ls, 16);
    ls += __shfl_xor(ls, 32);
    l += ls;
    unsigned w0 = cvt_pk_bf16(p0[0], p1[0]);
    unsigned w1 = cvt_pk_bf16(p0[1], p1[1]);
    unsigned w2 = cvt_pk_bf16(p0[2], p1[2]);
    unsigned w3 = cvt_pk_bf16(p0[3], p1[3]);
    int src0 = (g & 1) * 32 + q;
    int src1 = src0 + 16;
    unsigned e0 = (unsigned)__shfl((int)w0, src0);
    unsigned e1 = (unsigned)__shfl((int)w1, src0);
    unsigned e2 = (unsigned)__shfl((int)w2, src0);
    unsigned e3 = (unsigned)__shfl((int)w3, src0);
    unsigned e4 = (unsigned)__shfl((int)w0, src1);
    unsigned e5 = (unsigned)__shfl((int)w1, src1);
    unsigned e6 = (unsigned)__shfl((int)w2, src1);
    unsigned e7 = (unsigned)__shfl((int)w3, src1);
    union { unsigned u[4]; bf16x8 v; } pu;
    pu.u[0] = __builtin_amdgcn_perm(e1, e0, psel);
    pu.u[1] = __builtin_amdgcn_perm(e3, e2, psel);
    pu.u[2] = __builtin_amdgcn_perm(e5, e4, psel);
    pu.u[3] = __builtin_amdgcn_perm(e7, e6, psel);
    __builtin_amdgcn_s_setprio(1);
    acc0 = __builtin_amdgcn_mfma_f32_16x16x32_bf16(v0, pu.v, acc0, 0, 0, 0);
    acc1 = __builtin_amdgcn_mfma_f32_16x16x32_bf16(v1, pu.v, acc1, 0, 0, 0);
    __builtin_amdgcn_s_setprio(0);
    kA = nkA; kB = nkB; v0 = nv0; v1 = nv1;
  }
  float linv = 1.f / l;
  unsigned short* cp = ctx + (size_t)(b * 784 + qb * 16 + q) * 256 + nh * 32;
  ushort4 oA = make_ushort4(f2b(acc0[0] * linv), f2b(acc0[1] * linv),
                            f2b(acc0[2] * linv), f2b(acc0[3] * linv));
  ushort4 oB = make_ushort4(f2b(acc1[0] * linv), f2b(acc1[1] * linv),
                            f2b(acc1[2] * linv), f2b(acc1[3] * linv));
  *(ushort4*)(cp + g * 4) = oA;
  *(ushort4*)(cp + 16 + g * 4) = oB;
}

// ---------------- mean pool over sequence ----------------
__global__ __launch_bounds__(1024) void k_pool(const float* __restrict__ ao,
                                               float* __restrict__ out) {
  int b = blockIdx.x;
  int d = threadIdx.x & 255;
  int sg = threadIdx.x >> 8;
  float s = 0.f;
  for (int t = sg; t < 784; t += 4) s += ao[((size_t)b * 784 + t) * 256 + d];
  __shared__ float red[4][256];
  red[sg][d] = s;
  __syncthreads();
  if (sg == 0) {
    float tot = red[0][d] + red[1][d] + red[2][d] + red[3][d];
    out[b * 256 + d] = tot * (1.0f / 784.0f);
  }
}

extern "C" void kernel_launch(void* const* d_in, const int* in_sizes, int n_in,
                              void* d_out, int out_size, void* d_ws, size_t ws_size,
                              hipStream_t stream) {
  (void)in_sizes; (void)n_in; (void)out_size; (void)ws_size;
  const float* x   = (const float*)d_in[0];
  const float* cw  = (const float*)d_in[1];
  const float* ce  = (const float*)d_in[2];
  const float* ipw = (const float*)d_in[3];
  const float* ipb = (const float*)d_in[4];
  const float* opw = (const float*)d_in[5];
  const float* opb = (const float*)d_in[6];

  float* out = (float*)d_out;
  float* pooled  = out;
  float* out_sw  = out + 8192;
  float* out_idx = out + 8192 + NA;

  float* ws = (float*)d_ws;
  float* vbuf = ws;                                   // NA f32
  unsigned* hist16 = (unsigned*)(ws + NA);            // 65536
  unsigned* hist8a = hist16 + 65536;                  // 256
  unsigned* hist8b = hist8a + 256;                    // 256
  unsigned* sel    = hist8b + 256;                    // 16
  unsigned short* seqb = (unsigned short*)(ws + NA + 66080);  // SEQN bf16 (later: ctx)
  unsigned short* qkvb = seqb + SEQN;                 // 3*SEQN bf16 (later: aout f32)
  unsigned short* Vt   = qkvb + 3 * (size_t)SEQN;     // 256*32*800 bf16
  unsigned short* wb   = Vt + 256 * 32 * 800;         // 262144 bf16
  float* aout = (float*)qkvb;

  k_zero<<<(66080 + 255) / 256, 256, 0, stream>>>(hist16, 66080);
  k_cast<<<262144 / 256, 256, 0, stream>>>(ipw, opw, wb);
  k_conv<<<224, 256, 0, stream>>>(x, cw, vbuf);
  k_h8<<<1024, 256, 0, stream>>>(vbuf, sel, hist8a, 0);
  k_scan8<<<1, 256, 0, stream>>>(hist8a, sel, 0);
  k_h8<<<1024, 256, 0, stream>>>(vbuf, sel, hist8b, 1);
  k_scan8<<<1, 256, 0, stream>>>(hist8b, sel, 1);
  k_h16<<<1024, 256, 0, stream>>>(vbuf, sel, hist16);
  k_scan16<<<1, 1024, 0, stream>>>(hist16, sel);
  k_select<<<25088 / 4, 256, 0, stream>>>(vbuf, sel, ce, seqb, out_sw, out_idx);
  {
    dim3 gq(768 / 128, 25088 / 128);
    k_gemm_mfma<1, 1><<<gq, 256, 0, stream>>>(seqb, wb, ipb, qkvb, 25088, 768, 256);
  }
  {
    dim3 gv(13, 256);
    k_vt<<<gv, 256, 0, stream>>>(qkvb, Vt);
  }
  k_attn<<<12544, 64, 0, stream>>>(qkvb, Vt, seqb /* ctx */);
  {
    dim3 go(256 / 128, 25088 / 128);
    k_gemm_mfma<0, 0><<<go, 256, 0, stream>>>(seqb, wb + 196608, opb, aout, 25088, 256, 256);
  }
  k_pool<<<NB, 1024, 0, stream>>>(aout, pooled);
}

// Round 6
// 320.429 us; speedup vs baseline: 13.0026x; 1.0438x over previous
//
#include <hip/hip_runtime.h>
#include <cmath>

#define NB 32
#define C1N 64
#define DIM 256
#define NHEAD 8
#define SEQL 784
#define NA 1605632      /* NB*SEQL*C1N */
#define SEQN 6422528    /* NB*SEQL*DIM */
#define KSEL 803u
#define SCALE 0.17677669529663687f   /* 1/sqrt(32) */
#define QK2S (0.17677669529663687f * 1.4426950408889634f)  /* SCALE * log2(e) */
#define THR2 11.541560f              /* 8 * log2(e) */
#define PECOEF (-0.03597789207803197f) /* -ln(10000)/256 */

typedef __attribute__((ext_vector_type(8))) short bf16x8;
typedef __attribute__((ext_vector_type(4))) short bf16x4;
typedef __attribute__((ext_vector_type(4))) float f32x4;

__device__ __forceinline__ unsigned short f2b(float f) {
  unsigned u = __float_as_uint(f);
  unsigned r = u + 0x7fffu + ((u >> 16) & 1u);
  return (unsigned short)(r >> 16);
}

__device__ __forceinline__ unsigned cvt_pk_bf16(float lo, float hi) {
  unsigned r;
  asm("v_cvt_pk_bf16_f32 %0, %1, %2" : "=v"(r) : "v"(lo), "v"(hi));
  return r;
}

// ---------------- zero ----------------
__global__ void k_zero(unsigned* __restrict__ p, int n) {
  int i = blockIdx.x * 256 + threadIdx.x;
  if (i < n) p[i] = 0u;
}

// ---------------- weights f32 -> bf16 ----------------
__global__ __launch_bounds__(256) void k_cast(const float* __restrict__ ipw,
                                              const float* __restrict__ opw,
                                              unsigned short* __restrict__ wb) {
  int i = blockIdx.x * 256 + threadIdx.x;
  float v = (i < 196608) ? ipw[i] : opw[i - 196608];
  wb[i] = f2b(v);
}

// ---------------- conv + relu: LDS weights (transposed) + padded LDS image -------
__global__ __launch_bounds__(256) void k_conv(const float* __restrict__ x,
                                              const float* __restrict__ cw,
                                              float* __restrict__ vbuf) {
  __shared__ __align__(16) float ximg[1296];   // 36x36 zero-padded image
  __shared__ float wlds[5184];                 // [tap 0..80][channel 0..63]
  int tid = threadIdx.x;
  int b = blockIdx.x / 7, sblk = blockIdx.x % 7;
  for (int e = tid; e < 1296; e += 256) ximg[e] = 0.f;
  for (int e = tid; e < 5184; e += 256) {
    int c = e / 81, t = e - c * 81;
    wlds[t * 64 + c] = cw[e];
  }
  __syncthreads();
  const float* xb = x + b * 784;
  for (int e = tid; e < 784; e += 256) {
    int row = e / 28, col = e - row * 28;
    ximg[(row + 4) * 36 + col + 4] = xb[e];
  }
  __syncthreads();
  int wv = tid >> 6, lane = tid & 63;
  for (int it = 0; it < 7; ++it) {
    int grp = sblk * 28 + it * 4 + wv;     // 0..195
    int hr = grp / 7, wc0 = (grp % 7) * 4;
    float a0 = 0.f, a1 = 0.f, a2 = 0.f, a3 = 0.f;
    #pragma unroll
    for (int dy = 0; dy < 9; ++dy) {
      const float4* xr4 = (const float4*)&ximg[(hr + dy) * 36 + wc0];
      float4 xa = xr4[0], xbq = xr4[1], xc = xr4[2];
      float xr[12] = {xa.x, xa.y, xa.z, xa.w, xbq.x, xbq.y, xbq.z, xbq.w,
                      xc.x, xc.y, xc.z, xc.w};
      #pragma unroll
      for (int dx = 0; dx < 9; ++dx) {
        float w = wlds[(dy * 9 + dx) * 64 + lane];
        a0 = fmaf(xr[dx + 0], w, a0);
        a1 = fmaf(xr[dx + 1], w, a1);
        a2 = fmaf(xr[dx + 2], w, a2);
        a3 = fmaf(xr[dx + 3], w, a3);
      }
    }
    size_t base = ((size_t)(b * 784 + hr * 28 + wc0)) * 64 + lane;
    vbuf[base +   0] = fmaxf(a0, 0.f);
    vbuf[base +  64] = fmaxf(a1, 0.f);
    vbuf[base + 128] = fmaxf(a2, 0.f);
    vbuf[base + 192] = fmaxf(a3, 0.f);
  }
}

// ---------------- radix stage A/B: 8-bit hist, LDS-privatized ----------------
__global__ __launch_bounds__(256) void k_h8(const float* __restrict__ vbuf,
                                            const unsigned* __restrict__ sel,
                                            unsigned* __restrict__ hist8,
                                            int stage) {
  __shared__ unsigned lh[256];
  int tid = threadIdx.x;
  lh[tid] = 0u;
  __syncthreads();
  if (stage == 0 || sel[2] == 0u) {
    unsigned key = (stage == 1) ? sel[0] : 0u;
    const float4* v4 = (const float4*)vbuf;
    int n4 = NA / 4;
    for (int i = blockIdx.x * 256 + tid; i < n4; i += gridDim.x * 256) {
      float4 v = v4[i];
      float vv[4] = {v.x, v.y, v.z, v.w};
      #pragma unroll
      for (int j = 0; j < 4; ++j) {
        if (vv[j] > 0.0f) {
          unsigned bits = __float_as_uint(vv[j]);
          if (stage == 0) atomicAdd(&lh[bits >> 24], 1u);
          else if ((bits >> 24) == key) atomicAdd(&lh[(bits >> 16) & 0xFFu], 1u);
        }
      }
    }
  }
  __syncthreads();
  if (lh[tid] > 0u) atomicAdd(&hist8[tid], lh[tid]);
}

// ---------------- radix stage A/B scan (256 buckets) ----------------
__global__ __launch_bounds__(256) void k_scan8(const unsigned* __restrict__ hist8,
                                               unsigned* __restrict__ sel,
                                               int stage) {
  if (stage == 1 && sel[2]) return;
  __shared__ unsigned ss[256];
  int t = threadIdx.x;
  ss[t] = hist8[t];
  __syncthreads();
  for (int off = 1; off < 256; off <<= 1) {
    unsigned v = (t + off < 256) ? ss[t + off] : 0u;
    __syncthreads();
    ss[t] += v;
    __syncthreads();
  }
  unsigned rem = (stage == 0) ? KSEL : sel[1];
  if (stage == 0 && t == 0 && ss[0] < KSEL) {
    sel[2] = 1u; sel[3] = 0u;
  }
  unsigned S = ss[t];
  unsigned above = (t < 255) ? ss[t + 1] : 0u;
  if (S >= rem && above < rem) {
    if (stage == 0) { sel[0] = (unsigned)t; sel[1] = rem - above; }
    else            { sel[4] = (unsigned)t; sel[5] = rem - above; }
  }
}

// ---------------- radix stage C: hist of low 16 bits within slice ----------------
__global__ __launch_bounds__(256) void k_h16(const float* __restrict__ vbuf,
                                             const unsigned* __restrict__ sel,
                                             unsigned* __restrict__ hist16) {
  if (sel[2]) return;
  unsigned key16 = (sel[0] << 8) | sel[4];
  const float4* v4 = (const float4*)vbuf;
  int n4 = NA / 4;
  for (int i = blockIdx.x * 256 + threadIdx.x; i < n4; i += gridDim.x * 256) {
    float4 v = v4[i];
    float vv[4] = {v.x, v.y, v.z, v.w};
    #pragma unroll
    for (int j = 0; j < 4; ++j) {
      if (vv[j] > 0.0f) {
        unsigned bits = __float_as_uint(vv[j]);
        if ((bits >> 16) == key16) atomicAdd(&hist16[bits & 0xFFFFu], 1u);
      }
    }
  }
}

// ---------------- radix stage C scan (65536 buckets) ----------------
__global__ __launch_bounds__(1024) void k_scan16(const unsigned* __restrict__ hist16,
                                                 unsigned* __restrict__ sel) {
  if (sel[2]) return;
  __shared__ unsigned ss[1024];
  int t = threadIdx.x;
  unsigned rem = sel[5];
  unsigned sum = 0;
  for (int i = 0; i < 64; ++i) sum += hist16[t * 64 + i];
  ss[t] = sum;
  __syncthreads();
  for (int off = 1; off < 1024; off <<= 1) {
    unsigned v = (t + off < 1024) ? ss[t + off] : 0u;
    __syncthreads();
    ss[t] += v;
    __syncthreads();
  }
  unsigned S = ss[t];
  unsigned above = (t < 1023) ? ss[t + 1] : 0u;
  if (S >= rem && above < rem) {
    unsigned cum = above;
    for (int bb = t * 64 + 63; bb >= t * 64; --bb) {
      unsigned hb = hist16[bb];
      cum += hb;
      if (cum >= rem) {
        sel[3] = (((sel[0] << 8) | sel[4]) << 16) | (unsigned)bb;
        break;
      }
    }
  }
}

// ---------------- top-2 select + sparse softmax + embed + pos-enc (seq in bf16) ----
__global__ __launch_bounds__(256) void k_select(const float* __restrict__ vbuf,
                                                const unsigned* __restrict__ sel,
                                                const float* __restrict__ ce,
                                                unsigned short* __restrict__ seqb,
                                                float* __restrict__ out_sw,
                                                float* __restrict__ out_idx) {
  int wid = threadIdx.x >> 6;
  int lane = threadIdx.x & 63;
  int pos = blockIdx.x * 4 + wid;
  int hw = pos % 784;
  int hr = hw / 28;
  int wc = hw % 28;
  float thr = __uint_as_float(sel[3]);
  float a = vbuf[(size_t)pos * 64 + lane];
  float val = (a >= thr) ? a : 0.0f;
  unsigned long long nzm = __ballot(val > 0.0f);
  int count = __popcll(nzm);
  float v1 = val; int i1 = lane;
  #pragma unroll
  for (int off = 32; off > 0; off >>= 1) {
    float ov = __shfl_xor(v1, off);
    int oi = __shfl_xor(i1, off);
    if (ov > v1 || (ov == v1 && oi < i1)) { v1 = ov; i1 = oi; }
  }
  float vx = (lane == i1) ? -INFINITY : val;
  float v2 = vx; int i2 = lane;
  #pragma unroll
  for (int off = 32; off > 0; off >>= 1) {
    float ov = __shfl_xor(v2, off);
    int oi = __shfl_xor(i2, off);
    if (ov > v2 || (ov == v2 && oi < i2)) { v2 = ov; i2 = oi; }
  }
  float w1 = 0.0f, w2 = 0.0f;
  if (count >= 2) {
    float e = __expf(v2 - v1);
    float invd = 1.0f / (1.0f + e);
    w1 = invd; w2 = e * invd;
  } else if (count == 1) {
    w1 = 1.0f;
  }
  float wt = (lane == i1) ? w1 : ((lane == i2) ? w2 : 0.0f);
  out_sw[(size_t)pos * 64 + lane] = wt;
  if (lane < 2) out_idx[pos * 2 + lane] = (float)(lane == 0 ? i1 : i2);
  int d0 = lane * 4;
  float4 c1v = *(const float4*)(ce + (size_t)i1 * 256 + d0);
  float4 c2v = *(const float4*)(ce + (size_t)i2 * 256 + d0);
  float dv0 = __expf((float)d0 * PECOEF);
  float dv2 = __expf((float)(d0 + 2) * PECOEF);
  float ox = w1 * c1v.x + w2 * c2v.x + sinf((float)hr * dv0);
  float oy = w1 * c1v.y + w2 * c2v.y + cosf((float)wc * dv0);
  float oz = w1 * c1v.z + w2 * c2v.z + sinf((float)hr * dv2);
  float ow = w1 * c1v.w + w2 * c2v.w + cosf((float)wc * dv2);
  ushort4 ob = make_ushort4(f2b(ox), f2b(oy), f2b(oz), f2b(ow));
  *(ushort4*)(seqb + (size_t)pos * 256 + d0) = ob;
}

// ---------------- MFMA bf16 GEMM: C[M][N] = A[M][K] @ W[N][K]^T + bias -----------
// QSCALE: multiply columns <256 (the Q part of QKV) by SCALE*log2e (exp2-domain attn).
template<int OUTBF16, int QSCALE>
__global__ __launch_bounds__(256) void k_gemm_mfma(const unsigned short* __restrict__ A,
                                                   const unsigned short* __restrict__ W,
                                                   const float* __restrict__ bias,
                                                   void* __restrict__ Cv,
                                                   int M, int N, int K) {
  int tid = threadIdx.x;
  int lane = tid & 63, wid = tid >> 6;
  int q = lane & 15, g = lane >> 4;
  int m0 = blockIdx.y * 128 + (wid >> 1) * 64;
  int n0 = blockIdx.x * 128 + (wid & 1) * 64;
  f32x4 acc[4][4];
  #pragma unroll
  for (int i = 0; i < 4; ++i)
    #pragma unroll
    for (int j = 0; j < 4; ++j) acc[i][j] = (f32x4){0.f, 0.f, 0.f, 0.f};
  for (int k0 = 0; k0 < K; k0 += 32) {
    bf16x8 af[4], bf[4];
    #pragma unroll
    for (int i = 0; i < 4; ++i)
      af[i] = *(const bf16x8*)(A + (size_t)(m0 + i * 16 + q) * K + k0 + g * 8);
    #pragma unroll
    for (int j = 0; j < 4; ++j)
      bf[j] = *(const bf16x8*)(W + (size_t)(n0 + j * 16 + q) * K + k0 + g * 8);
    #pragma unroll
    for (int i = 0; i < 4; ++i)
      #pragma unroll
      for (int j = 0; j < 4; ++j)
        acc[i][j] = __builtin_amdgcn_mfma_f32_16x16x32_bf16(af[i], bf[j], acc[i][j], 0, 0, 0);
  }
  float bj[4];
  #pragma unroll
  for (int j = 0; j < 4; ++j) bj[j] = bias[n0 + j * 16 + q];
  #pragma unroll
  for (int i = 0; i < 4; ++i) {
    #pragma unroll
    for (int j = 0; j < 4; ++j) {
      int col = n0 + j * 16 + q;
      #pragma unroll
      for (int r = 0; r < 4; ++r) {
        int row = m0 + i * 16 + g * 4 + r;
        float v = acc[i][j][r] + bj[j];
        if (QSCALE && col < 256) v *= QK2S;
        if (OUTBF16) ((unsigned short*)Cv)[(size_t)row * N + col] = f2b(v);
        else ((float*)Cv)[(size_t)row * N + col] = v;
      }
    }
  }
}

// ---------------- V transpose via LDS tiles: qkv V-part -> Vt[(bh)*32+d][800] -------
__global__ __launch_bounds__(256) void k_vt(const unsigned short* __restrict__ qkv,
                                            unsigned short* __restrict__ Vt) {
  __shared__ unsigned short lds[32][72];
  int k0 = blockIdx.x * 64;
  int bh = blockIdx.y;
  int b = bh >> 3, nh = bh & 7;
  int tid = threadIdx.x;
  int key = tid >> 2;
  int c8 = (tid & 3) * 8;
  int kk = k0 + key;
  ushort4 a = make_ushort4(0, 0, 0, 0), bq = a;
  if (kk < 784) {
    const unsigned short* src = qkv + (size_t)(b * 784 + kk) * 768 + 512 + nh * 32 + c8;
    a  = *(const ushort4*)src;
    bq = *(const ushort4*)(src + 4);
  }
  lds[c8 + 0][key] = a.x;  lds[c8 + 1][key] = a.y;
  lds[c8 + 2][key] = a.z;  lds[c8 + 3][key] = a.w;
  lds[c8 + 4][key] = bq.x; lds[c8 + 5][key] = bq.y;
  lds[c8 + 6][key] = bq.z; lds[c8 + 7][key] = bq.w;
  __syncthreads();
  int d = tid >> 3;
  int kc = (tid & 7) * 8;
  if (k0 + kc < 800) {
    ushort4 o0 = make_ushort4(lds[d][kc + 0], lds[d][kc + 1], lds[d][kc + 2], lds[d][kc + 3]);
    ushort4 o1 = make_ushort4(lds[d][kc + 4], lds[d][kc + 5], lds[d][kc + 6], lds[d][kc + 7]);
    unsigned short* dst = Vt + ((size_t)bh * 32 + d) * 800 + k0 + kc;
    *(ushort4*)dst = o0;
    *(ushort4*)(dst + 4) = o1;
  }
}

// ---- MFMA flash attention: 4 waves/block, zero cross-lane ops in hot loop ----
// k-permutation trick: PV MFMA's k-reduction is order-invariant, so the P
// fragment stays lane-local (S^T C/D layout keys {g*4+r, 16+g*4+r}) and V is
// loaded with the SAME permuted key order (two 8B loads per fragment).
__global__ __launch_bounds__(256) void k_attn(const unsigned short* __restrict__ qkv,
                                              const unsigned short* __restrict__ Vt,
                                              unsigned short* __restrict__ ctx) {
  int wid = threadIdx.x >> 6;
  int lane = threadIdx.x & 63;
  int blk = blockIdx.x;                       // 3136 = 8 XCDs * 392
  int work = (((blk & 7) * 392 + (blk >> 3)) << 2) + wid;
  int bh = work / 49;
  int qb = work - bh * 49;
  int b = bh >> 3, nh = bh & 7;
  int q = lane & 15, g = lane >> 4;
  int g4 = g * 4, g8 = g * 8;
  const f32x4 zero4 = {0.f, 0.f, 0.f, 0.f};

  bf16x8 qf = *(const bf16x8*)(qkv + (size_t)(b * 784 + qb * 16 + q) * 768 + nh * 32 + g8);
  const unsigned short* kbase = qkv + (size_t)b * 784 * 768 + 256 + nh * 32;
  const unsigned short* vrow0 = Vt + (size_t)bh * 32 * 800 + (size_t)q * 800;
  const unsigned short* vrow1 = vrow0 + 16 * 800;

  f32x4 acc0 = zero4, acc1 = zero4;
  float m = -INFINITY, lp = 0.f;

  #pragma unroll 2
  for (int c = 0; c < 24; ++c) {
    int k0 = c * 32;
    bf16x8 kA = *(const bf16x8*)(kbase + (size_t)(k0 + q) * 768 + g8);
    bf16x8 kB = *(const bf16x8*)(kbase + (size_t)(k0 + 16 + q) * 768 + g8);
    union { bf16x4 h[2]; bf16x8 v; } va, vb;
    va.h[0] = *(const bf16x4*)(vrow0 + k0 + g4);
    va.h[1] = *(const bf16x4*)(vrow0 + k0 + 16 + g4);
    vb.h[0] = *(const bf16x4*)(vrow1 + k0 + g4);
    vb.h[1] = *(const bf16x4*)(vrow1 + k0 + 16 + g4);
    __builtin_amdgcn_s_setprio(1);
    f32x4 s0 = __builtin_amdgcn_mfma_f32_16x16x32_bf16(kA, qf, zero4, 0, 0, 0);
    f32x4 s1 = __builtin_amdgcn_mfma_f32_16x16x32_bf16(kB, qf, zero4, 0, 0, 0);
    __builtin_amdgcn_s_setprio(0);
    float pl = fmaxf(fmaxf(fmaxf(s0[0], s0[1]), fmaxf(s0[2], s0[3])),
                     fmaxf(fmaxf(s1[0], s1[1]), fmaxf(s1[2], s1[3])));
    if (!__all(pl <= m + THR2)) {
      float pm = fmaxf(pl, __shfl_xor(pl, 16));
      pm = fmaxf(pm, __shfl_xor(pm, 32));
      float mnew = fmaxf(m, pm);
      float sc = __builtin_amdgcn_exp2f(m - mnew);
      lp *= sc; acc0 *= sc; acc1 *= sc;
      m = mnew;
    }
    float p0[4], p1[4];
    #pragma unroll
    for (int r = 0; r < 4; ++r) {
      p0[r] = __builtin_amdgcn_exp2f(s0[r] - m);
      p1[r] = __builtin_amdgcn_exp2f(s1[r] - m);
    }
    lp += ((p0[0] + p0[1]) + (p0[2] + p0[3])) + ((p1[0] + p1[1]) + (p1[2] + p1[3]));
    union { unsigned u[4]; bf16x8 v; } pu;
    pu.u[0] = cvt_pk_bf16(p0[0], p0[1]);
    pu.u[1] = cvt_pk_bf16(p0[2], p0[3]);
    pu.u[2] = cvt_pk_bf16(p1[0], p1[1]);
    pu.u[3] = cvt_pk_bf16(p1[2], p1[3]);
    __builtin_amdgcn_s_setprio(1);
    acc0 = __builtin_amdgcn_mfma_f32_16x16x32_bf16(va.v, pu.v, acc0, 0, 0, 0);
    acc1 = __builtin_amdgcn_mfma_f32_16x16x32_bf16(vb.v, pu.v, acc1, 0, 0, 0);
    __builtin_amdgcn_s_setprio(0);
  }
  { // epilogue: keys 768..783 (16 keys, tile A only)
    const int k0 = 768;
    bf16x8 kA = *(const bf16x8*)(kbase + (size_t)(k0 + q) * 768 + g8);
    union { bf16x4 h[2]; bf16x8 v; } va, vb;
    va.h[0] = *(const bf16x4*)(vrow0 + k0 + g4);
    va.h[1] = (bf16x4){0, 0, 0, 0};
    vb.h[0] = *(const bf16x4*)(vrow1 + k0 + g4);
    vb.h[1] = (bf16x4){0, 0, 0, 0};
    f32x4 s0 = __builtin_amdgcn_mfma_f32_16x16x32_bf16(kA, qf, zero4, 0, 0, 0);
    float pl = fmaxf(fmaxf(s0[0], s0[1]), fmaxf(s0[2], s0[3]));
    if (!__all(pl <= m + THR2)) {
      float pm = fmaxf(pl, __shfl_xor(pl, 16));
      pm = fmaxf(pm, __shfl_xor(pm, 32));
      float mnew = fmaxf(m, pm);
      float sc = __builtin_amdgcn_exp2f(m - mnew);
      lp *= sc; acc0 *= sc; acc1 *= sc;
      m = mnew;
    }
    float p0[4];
    #pragma unroll
    for (int r = 0; r < 4; ++r) p0[r] = __builtin_amdgcn_exp2f(s0[r] - m);
    lp += (p0[0] + p0[1]) + (p0[2] + p0[3]);
    union { unsigned u[4]; bf16x8 v; } pu;
    pu.u[0] = cvt_pk_bf16(p0[0], p0[1]);
    pu.u[1] = cvt_pk_bf16(p0[2], p0[3]);
    pu.u[2] = 0u;
    pu.u[3] = 0u;
    acc0 = __builtin_amdgcn_mfma_f32_16x16x32_bf16(va.v, pu.v, acc0, 0, 0, 0);
    acc1 = __builtin_amdgcn_mfma_f32_16x16x32_bf16(vb.v, pu.v, acc1, 0, 0, 0);
  }
  float l = lp + __shfl_xor(lp, 16);
  l += __shfl_xor(l, 32);
  float linv = 1.f / l;
  unsigned short* cp = ctx + (size_t)(b * 784 + qb * 16 + q) * 256 + nh * 32;
  ushort4 oA = make_ushort4(f2b(acc0[0] * linv), f2b(acc0[1] * linv),
                            f2b(acc0[2] * linv), f2b(acc0[3] * linv));
  ushort4 oB = make_ushort4(f2b(acc1[0] * linv), f2b(acc1[1] * linv),
                            f2b(acc1[2] * linv), f2b(acc1[3] * linv));
  *(ushort4*)(cp + g * 4) = oA;
  *(ushort4*)(cp + 16 + g * 4) = oB;
}

// ---------------- mean pool: stage 1 partials (256 blocks), stage 2 combine ------
__global__ __launch_bounds__(256) void k_pool1(const float* __restrict__ ao,
                                               float* __restrict__ part) {
  int b = blockIdx.x >> 3, s = blockIdx.x & 7;
  int d = threadIdx.x;
  const float* base = ao + ((size_t)b * 784 + s * 98) * 256 + d;
  float acc = 0.f;
  for (int t = 0; t < 98; ++t) acc += base[(size_t)t * 256];
  part[(size_t)blockIdx.x * 256 + d] = acc;
}

__global__ __launch_bounds__(256) void k_pool2(const float* __restrict__ part,
                                               float* __restrict__ out) {
  int b = blockIdx.x;
  int d = threadIdx.x;
  float s = 0.f;
  #pragma unroll
  for (int i = 0; i < 8; ++i) s += part[(size_t)(b * 8 + i) * 256 + d];
  out[b * 256 + d] = s * (1.0f / 784.0f);
}

extern "C" void kernel_launch(void* const* d_in, const int* in_sizes, int n_in,
                              void* d_out, int out_size, void* d_ws, size_t ws_size,
                              hipStream_t stream) {
  (void)in_sizes; (void)n_in; (void)out_size; (void)ws_size;
  const float* x   = (const float*)d_in[0];
  const float* cw  = (const float*)d_in[1];
  const float* ce  = (const float*)d_in[2];
  const float* ipw = (const float*)d_in[3];
  const float* ipb = (const float*)d_in[4];
  const float* opw = (const float*)d_in[5];
  const float* opb = (const float*)d_in[6];

  float* out = (float*)d_out;
  float* pooled  = out;
  float* out_sw  = out + 8192;
  float* out_idx = out + 8192 + NA;

  float* ws = (float*)d_ws;
  float* vbuf = ws;                                   // NA f32
  unsigned* hist16 = (unsigned*)(ws + NA);            // 65536
  unsigned* hist8a = hist16 + 65536;                  // 256
  unsigned* hist8b = hist8a + 256;                    // 256
  unsigned* sel    = hist8b + 256;                    // 16
  unsigned short* seqb = (unsigned short*)(ws + NA + 66080);  // SEQN bf16 (later: ctx)
  unsigned short* qkvb = seqb + SEQN;                 // 3*SEQN bf16 (later: aout f32)
  unsigned short* Vt   = qkvb + 3 * (size_t)SEQN;     // 256*32*800 bf16
  unsigned short* wb   = Vt + 256 * 32 * 800;         // 262144 bf16
  float* part = (float*)(wb + 262144);                // 65536 f32
  float* aout = (float*)qkvb;

  k_zero<<<(66080 + 255) / 256, 256, 0, stream>>>(hist16, 66080);
  k_cast<<<262144 / 256, 256, 0, stream>>>(ipw, opw, wb);
  k_conv<<<224, 256, 0, stream>>>(x, cw, vbuf);
  k_h8<<<1024, 256, 0, stream>>>(vbuf, sel, hist8a, 0);
  k_scan8<<<1, 256, 0, stream>>>(hist8a, sel, 0);
  k_h8<<<1024, 256, 0, stream>>>(vbuf, sel, hist8b, 1);
  k_scan8<<<1, 256, 0, stream>>>(hist8b, sel, 1);
  k_h16<<<1024, 256, 0, stream>>>(vbuf, sel, hist16);
  k_scan16<<<1, 1024, 0, stream>>>(hist16, sel);
  k_select<<<25088 / 4, 256, 0, stream>>>(vbuf, sel, ce, seqb, out_sw, out_idx);
  {
    dim3 gq(768 / 128, 25088 / 128);
    k_gemm_mfma<1, 1><<<gq, 256, 0, stream>>>(seqb, wb, ipb, qkvb, 25088, 768, 256);
  }
  {
    dim3 gv(13, 256);
    k_vt<<<gv, 256, 0, stream>>>(qkvb, Vt);
  }
  k_attn<<<3136, 256, 0, stream>>>(qkvb, Vt, seqb /* ctx */);
  {
    dim3 go(256 / 128, 25088 / 128);
    k_gemm_mfma<0, 0><<<go, 256, 0, stream>>>(seqb, wb + 196608, opb, aout, 25088, 256, 256);
  }
  k_pool1<<<256, 256, 0, stream>>>(aout, part);
  k_pool2<<<NB, 256, 0, stream>>>(part, pooled);
}

// Round 7
// 223.816 us; speedup vs baseline: 18.6154x; 1.4317x over previous
//
#include <hip/hip_runtime.h>
#include <cmath>

#define NB 32
#define C1N 64
#define DIM 256
#define NHEAD 8
#define SEQL 784
#define NA 1605632      /* NB*SEQL*C1N */
#define SEQN 6422528    /* NB*SEQL*DIM */
#define KSEL 803u
#define SCALE 0.17677669529663687f   /* 1/sqrt(32) */
#define QK2S (0.17677669529663687f * 1.4426950408889634f)  /* SCALE * log2(e) */
#define THR2 11.541560f              /* 8 * log2(e) */
#define PECOEF (-0.03597789207803197f) /* -ln(10000)/256 */

#define AS1 __attribute__((address_space(1)))
#define AS3 __attribute__((address_space(3)))

typedef __attribute__((ext_vector_type(8))) short bf16x8;
typedef __attribute__((ext_vector_type(4))) float f32x4;

__device__ __forceinline__ unsigned short f2b(float f) {
  unsigned u = __float_as_uint(f);
  unsigned r = u + 0x7fffu + ((u >> 16) & 1u);
  return (unsigned short)(r >> 16);
}

__device__ __forceinline__ unsigned cvt_pk_bf16(float lo, float hi) {
  unsigned r;
  asm("v_cvt_pk_bf16_f32 %0, %1, %2" : "=v"(r) : "v"(lo), "v"(hi));
  return r;
}

// ---------------- zero ----------------
__global__ void k_zero(unsigned* __restrict__ p, int n) {
  int i = blockIdx.x * 256 + threadIdx.x;
  if (i < n) p[i] = 0u;
}

// ---------------- weights f32 -> bf16 ----------------
__global__ __launch_bounds__(256) void k_cast(const float* __restrict__ ipw,
                                              const float* __restrict__ opw,
                                              unsigned short* __restrict__ wb) {
  int i = blockIdx.x * 256 + threadIdx.x;
  float v = (i < 196608) ? ipw[i] : opw[i - 196608];
  wb[i] = f2b(v);
}

// ---------------- conv + relu: LDS weights (transposed) + padded LDS image -------
__global__ __launch_bounds__(256) void k_conv(const float* __restrict__ x,
                                              const float* __restrict__ cw,
                                              float* __restrict__ vbuf) {
  __shared__ __align__(16) float ximg[1296];   // 36x36 zero-padded image
  __shared__ float wlds[5184];                 // [tap 0..80][channel 0..63]
  int tid = threadIdx.x;
  int b = blockIdx.x / 7, sblk = blockIdx.x % 7;
  for (int e = tid; e < 1296; e += 256) ximg[e] = 0.f;
  for (int e = tid; e < 5184; e += 256) {
    int c = e / 81, t = e - c * 81;
    wlds[t * 64 + c] = cw[e];
  }
  __syncthreads();
  const float* xb = x + b * 784;
  for (int e = tid; e < 784; e += 256) {
    int row = e / 28, col = e - row * 28;
    ximg[(row + 4) * 36 + col + 4] = xb[e];
  }
  __syncthreads();
  int wv = tid >> 6, lane = tid & 63;
  for (int it = 0; it < 7; ++it) {
    int grp = sblk * 28 + it * 4 + wv;     // 0..195
    int hr = grp / 7, wc0 = (grp % 7) * 4;
    float a0 = 0.f, a1 = 0.f, a2 = 0.f, a3 = 0.f;
    #pragma unroll
    for (int dy = 0; dy < 9; ++dy) {
      const float4* xr4 = (const float4*)&ximg[(hr + dy) * 36 + wc0];
      float4 xa = xr4[0], xbq = xr4[1], xc = xr4[2];
      float xr[12] = {xa.x, xa.y, xa.z, xa.w, xbq.x, xbq.y, xbq.z, xbq.w,
                      xc.x, xc.y, xc.z, xc.w};
      #pragma unroll
      for (int dx = 0; dx < 9; ++dx) {
        float w = wlds[(dy * 9 + dx) * 64 + lane];
        a0 = fmaf(xr[dx + 0], w, a0);
        a1 = fmaf(xr[dx + 1], w, a1);
        a2 = fmaf(xr[dx + 2], w, a2);
        a3 = fmaf(xr[dx + 3], w, a3);
      }
    }
    size_t base = ((size_t)(b * 784 + hr * 28 + wc0)) * 64 + lane;
    vbuf[base +   0] = fmaxf(a0, 0.f);
    vbuf[base +  64] = fmaxf(a1, 0.f);
    vbuf[base + 128] = fmaxf(a2, 0.f);
    vbuf[base + 192] = fmaxf(a3, 0.f);
  }
}

// ---------------- radix stage A/B: 8-bit hist, LDS-privatized ----------------
__global__ __launch_bounds__(256) void k_h8(const float* __restrict__ vbuf,
                                            const unsigned* __restrict__ sel,
                                            unsigned* __restrict__ hist8,
                                            int stage) {
  __shared__ unsigned lh[256];
  int tid = threadIdx.x;
  lh[tid] = 0u;
  __syncthreads();
  if (stage == 0 || sel[2] == 0u) {
    unsigned key = (stage == 1) ? sel[0] : 0u;
    const float4* v4 = (const float4*)vbuf;
    int n4 = NA / 4;
    for (int i = blockIdx.x * 256 + tid; i < n4; i += gridDim.x * 256) {
      float4 v = v4[i];
      float vv[4] = {v.x, v.y, v.z, v.w};
      #pragma unroll
      for (int j = 0; j < 4; ++j) {
        if (vv[j] > 0.0f) {
          unsigned bits = __float_as_uint(vv[j]);
          if (stage == 0) atomicAdd(&lh[bits >> 24], 1u);
          else if ((bits >> 24) == key) atomicAdd(&lh[(bits >> 16) & 0xFFu], 1u);
        }
      }
    }
  }
  __syncthreads();
  if (lh[tid] > 0u) atomicAdd(&hist8[tid], lh[tid]);
}

// ---------------- radix stage A/B scan (256 buckets) ----------------
__global__ __launch_bounds__(256) void k_scan8(const unsigned* __restrict__ hist8,
                                               unsigned* __restrict__ sel,
                                               int stage) {
  if (stage == 1 && sel[2]) return;
  __shared__ unsigned ss[256];
  int t = threadIdx.x;
  ss[t] = hist8[t];
  __syncthreads();
  for (int off = 1; off < 256; off <<= 1) {
    unsigned v = (t + off < 256) ? ss[t + off] : 0u;
    __syncthreads();
    ss[t] += v;
    __syncthreads();
  }
  unsigned rem = (stage == 0) ? KSEL : sel[1];
  if (stage == 0 && t == 0 && ss[0] < KSEL) {
    sel[2] = 1u; sel[3] = 0u;
  }
  unsigned S = ss[t];
  unsigned above = (t < 255) ? ss[t + 1] : 0u;
  if (S >= rem && above < rem) {
    if (stage == 0) { sel[0] = (unsigned)t; sel[1] = rem - above; }
    else            { sel[4] = (unsigned)t; sel[5] = rem - above; }
  }
}

// ---------------- radix stage C: hist of low 16 bits within slice ----------------
__global__ __launch_bounds__(256) void k_h16(const float* __restrict__ vbuf,
                                             const unsigned* __restrict__ sel,
                                             unsigned* __restrict__ hist16) {
  if (sel[2]) return;
  unsigned key16 = (sel[0] << 8) | sel[4];
  const float4* v4 = (const float4*)vbuf;
  int n4 = NA / 4;
  for (int i = blockIdx.x * 256 + threadIdx.x; i < n4; i += gridDim.x * 256) {
    float4 v = v4[i];
    float vv[4] = {v.x, v.y, v.z, v.w};
    #pragma unroll
    for (int j = 0; j < 4; ++j) {
      if (vv[j] > 0.0f) {
        unsigned bits = __float_as_uint(vv[j]);
        if ((bits >> 16) == key16) atomicAdd(&hist16[bits & 0xFFFFu], 1u);
      }
    }
  }
}

// ---------------- radix stage C scan (65536 buckets) ----------------
__global__ __launch_bounds__(1024) void k_scan16(const unsigned* __restrict__ hist16,
                                                 unsigned* __restrict__ sel) {
  if (sel[2]) return;
  __shared__ unsigned ss[1024];
  int t = threadIdx.x;
  unsigned rem = sel[5];
  unsigned sum = 0;
  for (int i = 0; i < 64; ++i) sum += hist16[t * 64 + i];
  ss[t] = sum;
  __syncthreads();
  for (int off = 1; off < 1024; off <<= 1) {
    unsigned v = (t + off < 1024) ? ss[t + off] : 0u;
    __syncthreads();
    ss[t] += v;
    __syncthreads();
  }
  unsigned S = ss[t];
  unsigned above = (t < 1023) ? ss[t + 1] : 0u;
  if (S >= rem && above < rem) {
    unsigned cum = above;
    for (int bb = t * 64 + 63; bb >= t * 64; --bb) {
      unsigned hb = hist16[bb];
      cum += hb;
      if (cum >= rem) {
        sel[3] = (((sel[0] << 8) | sel[4]) << 16) | (unsigned)bb;
        break;
      }
    }
  }
}

// ---------------- top-2 select + sparse softmax + embed + pos-enc (seq in bf16) ----
__global__ __launch_bounds__(256) void k_select(const float* __restrict__ vbuf,
                                                const unsigned* __restrict__ sel,
                                                const float* __restrict__ ce,
                                                unsigned short* __restrict__ seqb,
                                                float* __restrict__ out_sw,
                                                float* __restrict__ out_idx) {
  int wid = threadIdx.x >> 6;
  int lane = threadIdx.x & 63;
  int pos = blockIdx.x * 4 + wid;
  int hw = pos % 784;
  int hr = hw / 28;
  int wc = hw % 28;
  float thr = __uint_as_float(sel[3]);
  float a = vbuf[(size_t)pos * 64 + lane];
  float val = (a >= thr) ? a : 0.0f;
  unsigned long long nzm = __ballot(val > 0.0f);
  int count = __popcll(nzm);
  float v1 = val; int i1 = lane;
  #pragma unroll
  for (int off = 32; off > 0; off >>= 1) {
    float ov = __shfl_xor(v1, off);
    int oi = __shfl_xor(i1, off);
    if (ov > v1 || (ov == v1 && oi < i1)) { v1 = ov; i1 = oi; }
  }
  float vx = (lane == i1) ? -INFINITY : val;
  float v2 = vx; int i2 = lane;
  #pragma unroll
  for (int off = 32; off > 0; off >>= 1) {
    float ov = __shfl_xor(v2, off);
    int oi = __shfl_xor(i2, off);
    if (ov > v2 || (ov == v2 && oi < i2)) { v2 = ov; i2 = oi; }
  }
  float w1 = 0.0f, w2 = 0.0f;
  if (count >= 2) {
    float e = __expf(v2 - v1);
    float invd = 1.0f / (1.0f + e);
    w1 = invd; w2 = e * invd;
  } else if (count == 1) {
    w1 = 1.0f;
  }
  float wt = (lane == i1) ? w1 : ((lane == i2) ? w2 : 0.0f);
  out_sw[(size_t)pos * 64 + lane] = wt;
  if (lane < 2) out_idx[pos * 2 + lane] = (float)(lane == 0 ? i1 : i2);
  int d0 = lane * 4;
  float4 c1v = *(const float4*)(ce + (size_t)i1 * 256 + d0);
  float4 c2v = *(const float4*)(ce + (size_t)i2 * 256 + d0);
  float dv0 = __expf((float)d0 * PECOEF);
  float dv2 = __expf((float)(d0 + 2) * PECOEF);
  float ox = w1 * c1v.x + w2 * c2v.x + sinf((float)hr * dv0);
  float oy = w1 * c1v.y + w2 * c2v.y + cosf((float)wc * dv0);
  float oz = w1 * c1v.z + w2 * c2v.z + sinf((float)hr * dv2);
  float ow = w1 * c1v.w + w2 * c2v.w + cosf((float)wc * dv2);
  ushort4 ob = make_ushort4(f2b(ox), f2b(oy), f2b(oz), f2b(ow));
  *(ushort4*)(seqb + (size_t)pos * 256 + d0) = ob;
}

// ---------------- MFMA bf16 GEMM: C[M][N] = A[M][K] @ W[N][K]^T + bias -----------
template<int OUTBF16, int QSCALE>
__global__ __launch_bounds__(256) void k_gemm_mfma(const unsigned short* __restrict__ A,
                                                   const unsigned short* __restrict__ W,
                                                   const float* __restrict__ bias,
                                                   void* __restrict__ Cv,
                                                   int M, int N, int K) {
  int tid = threadIdx.x;
  int lane = tid & 63, wid = tid >> 6;
  int q = lane & 15, g = lane >> 4;
  int m0 = blockIdx.y * 128 + (wid >> 1) * 64;
  int n0 = blockIdx.x * 128 + (wid & 1) * 64;
  f32x4 acc[4][4];
  #pragma unroll
  for (int i = 0; i < 4; ++i)
    #pragma unroll
    for (int j = 0; j < 4; ++j) acc[i][j] = (f32x4){0.f, 0.f, 0.f, 0.f};
  for (int k0 = 0; k0 < K; k0 += 32) {
    bf16x8 af[4], bf[4];
    #pragma unroll
    for (int i = 0; i < 4; ++i)
      af[i] = *(const bf16x8*)(A + (size_t)(m0 + i * 16 + q) * K + k0 + g * 8);
    #pragma unroll
    for (int j = 0; j < 4; ++j)
      bf[j] = *(const bf16x8*)(W + (size_t)(n0 + j * 16 + q) * K + k0 + g * 8);
    #pragma unroll
    for (int i = 0; i < 4; ++i)
      #pragma unroll
      for (int j = 0; j < 4; ++j)
        acc[i][j] = __builtin_amdgcn_mfma_f32_16x16x32_bf16(af[i], bf[j], acc[i][j], 0, 0, 0);
  }
  float bj[4];
  #pragma unroll
  for (int j = 0; j < 4; ++j) bj[j] = bias[n0 + j * 16 + q];
  #pragma unroll
  for (int i = 0; i < 4; ++i) {
    #pragma unroll
    for (int j = 0; j < 4; ++j) {
      int col = n0 + j * 16 + q;
      #pragma unroll
      for (int r = 0; r < 4; ++r) {
        int row = m0 + i * 16 + g * 4 + r;
        float v = acc[i][j][r] + bj[j];
        if (QSCALE && col < 256) v *= QK2S;
        if (OUTBF16) ((unsigned short*)Cv)[(size_t)row * N + col] = f2b(v);
        else ((float*)Cv)[(size_t)row * N + col] = v;
      }
    }
  }
}

// ------- V transpose WITH per-32-key permutation: Vt[(bh)*32+d][pos], where within
// each 32-col block, position p = g*8 + hi*4 + r  holds key  g*4 + hi*16 + r. -------
__global__ __launch_bounds__(256) void k_vt(const unsigned short* __restrict__ qkv,
                                            unsigned short* __restrict__ Vt) {
  __shared__ unsigned short lds[32][72];
  int k0 = blockIdx.x * 64;
  int bh = blockIdx.y;
  int b = bh >> 3, nh = bh & 7;
  int tid = threadIdx.x;
  int key = tid >> 2;
  int c8 = (tid & 3) * 8;
  int kk = k0 + key;
  ushort4 a = make_ushort4(0, 0, 0, 0), bq = a;
  if (kk < 784) {
    const unsigned short* src = qkv + (size_t)(b * 784 + kk) * 768 + 512 + nh * 32 + c8;
    a  = *(const ushort4*)src;
    bq = *(const ushort4*)(src + 4);
  }
  lds[c8 + 0][key] = a.x;  lds[c8 + 1][key] = a.y;
  lds[c8 + 2][key] = a.z;  lds[c8 + 3][key] = a.w;
  lds[c8 + 4][key] = bq.x; lds[c8 + 5][key] = bq.y;
  lds[c8 + 6][key] = bq.z; lds[c8 + 7][key] = bq.w;
  __syncthreads();
  int d = tid >> 3;
  int kc = (tid & 7) * 8;            // output position group
  if (k0 + kc < 800) {
    int sb = (kc & 32) + ((kc >> 3) & 3) * 4;   // source col base: blk32*32 + g*4
    ushort4 o0 = make_ushort4(lds[d][sb + 0],  lds[d][sb + 1],
                              lds[d][sb + 2],  lds[d][sb + 3]);    // hi=0
    ushort4 o1 = make_ushort4(lds[d][sb + 16], lds[d][sb + 17],
                              lds[d][sb + 18], lds[d][sb + 19]);   // hi=1
    unsigned short* dst = Vt + ((size_t)bh * 32 + d) * 800 + k0 + kc;
    *(ushort4*)dst = o0;
    *(ushort4*)(dst + 4) = o1;
  }
}

// ---- MFMA flash attention: 4 waves/block share (b,head); K/V LDS-staged via
// global_load_lds (1 instr/wave/iter), double-buffered, source-side XOR swizzle. ----
__global__ __launch_bounds__(256) void k_attn(const unsigned short* __restrict__ qkv,
                                              const unsigned short* __restrict__ Vt,
                                              unsigned short* __restrict__ ctx) {
  __shared__ __align__(16) unsigned short Kt[2][1024];   // [buf][32 keys x 32 dims]
  __shared__ __align__(16) unsigned short Vti[2][1024];  // [buf][32 dims x 32 kpos]
  int wid = threadIdx.x >> 6;
  int lane = threadIdx.x & 63;
  int blk = blockIdx.x;                       // 3328 = 8 XCDs * 416
  int wb = (blk & 7) * 416 + (blk >> 3);
  int bh = wb / 13;
  int qb = (wb - bh * 13) * 4 + wid;          // 0..51
  int b = bh >> 3, nh = bh & 7;
  int q = lane & 15, g = lane >> 4;
  bool active = (qb < 49);
  const f32x4 zero4 = {0.f, 0.f, 0.f, 0.f};

  int qrow = b * 784 + (active ? qb * 16 + q : q);
  bf16x8 qf = *(const bf16x8*)(qkv + (size_t)qrow * 768 + nh * 32 + g * 8);
  const unsigned short* kbase = qkv + (size_t)b * 784 * 768 + 256 + nh * 32;
  const unsigned short* vbase = Vt + (size_t)bh * 32 * 800;

  // staging geometry: wave 0 -> K rows 0-15, 1 -> K rows 16-31, 2 -> V rows 0-15,
  // 3 -> V rows 16-31. lane -> row r0+(lane>>2), lds 16B slot lane&3.
  int rit = ((wid & 1) << 4) + (lane >> 2);   // row in tile 0..31
  int sG = (lane & 3) ^ (rit & 3);            // swizzled source slot
  bool isK = (wid < 2);
  int ldsoff = ((wid & 1) << 4) * 32;         // ushort offset of wave's half-tile

  // compute-side LDS addresses (swizzled slot)
  int slotr = ((g ^ (q & 3)) << 3);           // ushort offset of 16B slot in row
  int rowA = q * 32 + slotr;
  int rowB = (16 + q) * 32 + slotr;

  f32x4 acc0 = zero4, acc1 = zero4;
  float m = -INFINITY, lp = 0.f;

#define STAGE(buf, k0v)                                                         \
  {                                                                             \
    if (isK) {                                                                  \
      int key_ = (k0v) + rit; if (key_ > 783) key_ = 783;                       \
      __builtin_amdgcn_global_load_lds(                                         \
        (const AS1 void*)(kbase + (size_t)key_ * 768 + sG * 8),                 \
        (AS3 void*)(&Kt[buf][ldsoff]), 16, 0, 0);                               \
    } else {                                                                    \
      __builtin_amdgcn_global_load_lds(                                         \
        (const AS1 void*)(vbase + (size_t)rit * 800 + (k0v) + sG * 8),          \
        (AS3 void*)(&Vti[buf][ldsoff]), 16, 0, 0);                              \
    }                                                                           \
  }

  STAGE(0, 0);
  __syncthreads();

  for (int c = 0; c < 24; ++c) {
    int cur = c & 1;
    STAGE(cur ^ 1, (c + 1) * 32);
    bf16x8 kA = *(const bf16x8*)&Kt[cur][rowA];
    bf16x8 kB = *(const bf16x8*)&Kt[cur][rowB];
    bf16x8 va = *(const bf16x8*)&Vti[cur][rowA];
    bf16x8 vb = *(const bf16x8*)&Vti[cur][rowB];
    __builtin_amdgcn_s_setprio(1);
    f32x4 s0 = __builtin_amdgcn_mfma_f32_16x16x32_bf16(kA, qf, zero4, 0, 0, 0);
    f32x4 s1 = __builtin_amdgcn_mfma_f32_16x16x32_bf16(kB, qf, zero4, 0, 0, 0);
    __builtin_amdgcn_s_setprio(0);
    float pl = fmaxf(fmaxf(fmaxf(s0[0], s0[1]), fmaxf(s0[2], s0[3])),
                     fmaxf(fmaxf(s1[0], s1[1]), fmaxf(s1[2], s1[3])));
    if (!__all(pl <= m + THR2)) {
      float pm = fmaxf(pl, __shfl_xor(pl, 16));
      pm = fmaxf(pm, __shfl_xor(pm, 32));
      float mnew = fmaxf(m, pm);
      float sc = __builtin_amdgcn_exp2f(m - mnew);
      lp *= sc; acc0 *= sc; acc1 *= sc;
      m = mnew;
    }
    float p0[4], p1[4];
    #pragma unroll
    for (int r = 0; r < 4; ++r) {
      p0[r] = __builtin_amdgcn_exp2f(s0[r] - m);
      p1[r] = __builtin_amdgcn_exp2f(s1[r] - m);
    }
    lp += ((p0[0] + p0[1]) + (p0[2] + p0[3])) + ((p1[0] + p1[1]) + (p1[2] + p1[3]));
    union { unsigned u[4]; bf16x8 v; } pu;
    pu.u[0] = cvt_pk_bf16(p0[0], p0[1]);
    pu.u[1] = cvt_pk_bf16(p0[2], p0[3]);
    pu.u[2] = cvt_pk_bf16(p1[0], p1[1]);
    pu.u[3] = cvt_pk_bf16(p1[2], p1[3]);
    __builtin_amdgcn_s_setprio(1);
    acc0 = __builtin_amdgcn_mfma_f32_16x16x32_bf16(va, pu.v, acc0, 0, 0, 0);
    acc1 = __builtin_amdgcn_mfma_f32_16x16x32_bf16(vb, pu.v, acc1, 0, 0, 0);
    __builtin_amdgcn_s_setprio(0);
    __syncthreads();
  }
  { // tail: keys 768..783 in buf0 (staged during c=23); K rows 16-31 are clamped
    // garbage (never read); V positions for keys >=784 are zeros from Vt padding.
    bf16x8 kA = *(const bf16x8*)&Kt[0][rowA];
    bf16x8 va = *(const bf16x8*)&Vti[0][rowA];
    bf16x8 vb = *(const bf16x8*)&Vti[0][rowB];
    f32x4 s0 = __builtin_amdgcn_mfma_f32_16x16x32_bf16(kA, qf, zero4, 0, 0, 0);
    float pl = fmaxf(fmaxf(s0[0], s0[1]), fmaxf(s0[2], s0[3]));
    if (!__all(pl <= m + THR2)) {
      float pm = fmaxf(pl, __shfl_xor(pl, 16));
      pm = fmaxf(pm, __shfl_xor(pm, 32));
      float mnew = fmaxf(m, pm);
      float sc = __builtin_amdgcn_exp2f(m - mnew);
      lp *= sc; acc0 *= sc; acc1 *= sc;
      m = mnew;
    }
    float p0[4];
    #pragma unroll
    for (int r = 0; r < 4; ++r) p0[r] = __builtin_amdgcn_exp2f(s0[r] - m);
    lp += (p0[0] + p0[1]) + (p0[2] + p0[3]);
    union { unsigned u[4]; bf16x8 v; } pu;
    pu.u[0] = cvt_pk_bf16(p0[0], p0[1]);
    pu.u[1] = cvt_pk_bf16(p0[2], p0[3]);
    pu.u[2] = 0u;
    pu.u[3] = 0u;
    acc0 = __builtin_amdgcn_mfma_f32_16x16x32_bf16(va, pu.v, acc0, 0, 0, 0);
    acc1 = __builtin_amdgcn_mfma_f32_16x16x32_bf16(vb, pu.v, acc1, 0, 0, 0);
  }
#undef STAGE
  float l = lp + __shfl_xor(lp, 16);
  l += __shfl_xor(l, 32);
  float linv = 1.f / l;
  if (active) {
    unsigned short* cp = ctx + (size_t)(b * 784 + qb * 16 + q) * 256 + nh * 32;
    ushort4 oA = make_ushort4(f2b(acc0[0] * linv), f2b(acc0[1] * linv),
                              f2b(acc0[2] * linv), f2b(acc0[3] * linv));
    ushort4 oB = make_ushort4(f2b(acc1[0] * linv), f2b(acc1[1] * linv),
                              f2b(acc1[2] * linv), f2b(acc1[3] * linv));
    *(ushort4*)(cp + g * 4) = oA;
    *(ushort4*)(cp + 16 + g * 4) = oB;
  }
}

// ---------------- mean pool: stage 1 partials (256 blocks), stage 2 combine ------
__global__ __launch_bounds__(256) void k_pool1(const float* __restrict__ ao,
                                               float* __restrict__ part) {
  int b = blockIdx.x >> 3, s = blockIdx.x & 7;
  int d = threadIdx.x;
  const float* base = ao + ((size_t)b * 784 + s * 98) * 256 + d;
  float acc = 0.f;
  for (int t = 0; t < 98; ++t) acc += base[(size_t)t * 256];
  part[(size_t)blockIdx.x * 256 + d] = acc;
}

__global__ __launch_bounds__(256) void k_pool2(const float* __restrict__ part,
                                               float* __restrict__ out) {
  int b = blockIdx.x;
  int d = threadIdx.x;
  float s = 0.f;
  #pragma unroll
  for (int i = 0; i < 8; ++i) s += part[(size_t)(b * 8 + i) * 256 + d];
  out[b * 256 + d] = s * (1.0f / 784.0f);
}

extern "C" void kernel_launch(void* const* d_in, const int* in_sizes, int n_in,
                              void* d_out, int out_size, void* d_ws, size_t ws_size,
                              hipStream_t stream) {
  (void)in_sizes; (void)n_in; (void)out_size; (void)ws_size;
  const float* x   = (const float*)d_in[0];
  const float* cw  = (const float*)d_in[1];
  const float* ce  = (const float*)d_in[2];
  const float* ipw = (const float*)d_in[3];
  const float* ipb = (const float*)d_in[4];
  const float* opw = (const float*)d_in[5];
  const float* opb = (const float*)d_in[6];

  float* out = (float*)d_out;
  float* pooled  = out;
  float* out_sw  = out + 8192;
  float* out_idx = out + 8192 + NA;

  float* ws = (float*)d_ws;
  float* vbuf = ws;                                   // NA f32
  unsigned* hist16 = (unsigned*)(ws + NA);            // 65536
  unsigned* hist8a = hist16 + 65536;                  // 256
  unsigned* hist8b = hist8a + 256;                    // 256
  unsigned* sel    = hist8b + 256;                    // 16
  unsigned short* seqb = (unsigned short*)(ws + NA + 66080);  // SEQN bf16 (later: ctx)
  unsigned short* qkvb = seqb + SEQN;                 // 3*SEQN bf16 (later: aout f32)
  unsigned short* Vt   = qkvb + 3 * (size_t)SEQN;     // 256*32*800 bf16
  unsigned short* wb   = Vt + 256 * 32 * 800;         // 262144 bf16
  float* part = (float*)(wb + 262144);                // 65536 f32
  float* aout = (float*)qkvb;

  k_zero<<<(66080 + 255) / 256, 256, 0, stream>>>(hist16, 66080);
  k_cast<<<262144 / 256, 256, 0, stream>>>(ipw, opw, wb);
  k_conv<<<224, 256, 0, stream>>>(x, cw, vbuf);
  k_h8<<<1024, 256, 0, stream>>>(vbuf, sel, hist8a, 0);
  k_scan8<<<1, 256, 0, stream>>>(hist8a, sel, 0);
  k_h8<<<1024, 256, 0, stream>>>(vbuf, sel, hist8b, 1);
  k_scan8<<<1, 256, 0, stream>>>(hist8b, sel, 1);
  k_h16<<<1024, 256, 0, stream>>>(vbuf, sel, hist16);
  k_scan16<<<1, 1024, 0, stream>>>(hist16, sel);
  k_select<<<25088 / 4, 256, 0, stream>>>(vbuf, sel, ce, seqb, out_sw, out_idx);
  {
    dim3 gq(768 / 128, 25088 / 128);
    k_gemm_mfma<1, 1><<<gq, 256, 0, stream>>>(seqb, wb, ipb, qkvb, 25088, 768, 256);
  }
  {
    dim3 gv(13, 256);
    k_vt<<<gv, 256, 0, stream>>>(qkvb, Vt);
  }
  k_attn<<<3328, 256, 0, stream>>>(qkvb, Vt, seqb /* ctx */);
  {
    dim3 go(256 / 128, 25088 / 128);
    k_gemm_mfma<0, 0><<<go, 256, 0, stream>>>(seqb, wb + 196608, opb, aout, 25088, 256, 256);
  }
  k_pool1<<<256, 256, 0, stream>>>(aout, part);
  k_pool2<<<NB, 256, 0, stream>>>(part, pooled);
}

// Round 8
// 191.143 us; speedup vs baseline: 21.7974x; 1.1709x over previous
//
#include <hip/hip_runtime.h>
#include <cmath>

#define NB 32
#define C1N 64
#define DIM 256
#define NHEAD 8
#define SEQL 784
#define NA 1605632      /* NB*SEQL*C1N */
#define SEQN 6422528    /* NB*SEQL*DIM */
#define KSEL 803u
#define QK2S (0.17677669529663687f * 1.4426950408889634f)  /* (1/sqrt(32)) * log2(e) */
#define THR2 11.541560f              /* 8 * log2(e) */
#define PECOEF (-0.03597789207803197f) /* -ln(10000)/256 */

#define AS1 __attribute__((address_space(1)))
#define AS3 __attribute__((address_space(3)))

typedef __attribute__((ext_vector_type(8))) short bf16x8;
typedef __attribute__((ext_vector_type(4))) float f32x4;

__device__ __forceinline__ unsigned short f2b(float f) {
  unsigned u = __float_as_uint(f);
  unsigned r = u + 0x7fffu + ((u >> 16) & 1u);
  return (unsigned short)(r >> 16);
}

__device__ __forceinline__ unsigned cvt_pk_bf16(float lo, float hi) {
  unsigned r;
  asm("v_cvt_pk_bf16_f32 %0, %1, %2" : "=v"(r) : "v"(lo), "v"(hi));
  return r;
}

// ---------------- zero ----------------
__global__ void k_zero(unsigned* __restrict__ p, int n) {
  int i = blockIdx.x * 256 + threadIdx.x;
  if (i < n) p[i] = 0u;
}

// ---------------- in_proj weights f32 -> bf16 ----------------
__global__ __launch_bounds__(256) void k_cast(const float* __restrict__ ipw,
                                              unsigned short* __restrict__ wb) {
  int i = blockIdx.x * 256 + threadIdx.x;
  wb[i] = f2b(ipw[i]);
}

// ---------------- conv + relu: LDS weights (transposed) + padded LDS image -------
__global__ __launch_bounds__(256) void k_conv(const float* __restrict__ x,
                                              const float* __restrict__ cw,
                                              float* __restrict__ vbuf) {
  __shared__ __align__(16) float ximg[1296];   // 36x36 zero-padded image
  __shared__ float wlds[5184];                 // [tap 0..80][channel 0..63]
  int tid = threadIdx.x;
  int b = blockIdx.x / 7, sblk = blockIdx.x % 7;
  for (int e = tid; e < 1296; e += 256) ximg[e] = 0.f;
  for (int e = tid; e < 5184; e += 256) {
    int c = e / 81, t = e - c * 81;
    wlds[t * 64 + c] = cw[e];
  }
  __syncthreads();
  const float* xb = x + b * 784;
  for (int e = tid; e < 784; e += 256) {
    int row = e / 28, col = e - row * 28;
    ximg[(row + 4) * 36 + col + 4] = xb[e];
  }
  __syncthreads();
  int wv = tid >> 6, lane = tid & 63;
  for (int it = 0; it < 7; ++it) {
    int grp = sblk * 28 + it * 4 + wv;     // 0..195
    int hr = grp / 7, wc0 = (grp % 7) * 4;
    float a0 = 0.f, a1 = 0.f, a2 = 0.f, a3 = 0.f;
    #pragma unroll
    for (int dy = 0; dy < 9; ++dy) {
      const float4* xr4 = (const float4*)&ximg[(hr + dy) * 36 + wc0];
      float4 xa = xr4[0], xbq = xr4[1], xc = xr4[2];
      float xr[12] = {xa.x, xa.y, xa.z, xa.w, xbq.x, xbq.y, xbq.z, xbq.w,
                      xc.x, xc.y, xc.z, xc.w};
      #pragma unroll
      for (int dx = 0; dx < 9; ++dx) {
        float w = wlds[(dy * 9 + dx) * 64 + lane];
        a0 = fmaf(xr[dx + 0], w, a0);
        a1 = fmaf(xr[dx + 1], w, a1);
        a2 = fmaf(xr[dx + 2], w, a2);
        a3 = fmaf(xr[dx + 3], w, a3);
      }
    }
    size_t base = ((size_t)(b * 784 + hr * 28 + wc0)) * 64 + lane;
    vbuf[base +   0] = fmaxf(a0, 0.f);
    vbuf[base +  64] = fmaxf(a1, 0.f);
    vbuf[base + 128] = fmaxf(a2, 0.f);
    vbuf[base + 192] = fmaxf(a3, 0.f);
  }
}

// ---------------- radix stage A/B: 8-bit hist, LDS-privatized ----------------
__global__ __launch_bounds__(256) void k_h8(const float* __restrict__ vbuf,
                                            const unsigned* __restrict__ sel,
                                            unsigned* __restrict__ hist8,
                                            int stage) {
  __shared__ unsigned lh[256];
  int tid = threadIdx.x;
  lh[tid] = 0u;
  __syncthreads();
  if (stage == 0 || sel[2] == 0u) {
    unsigned key = (stage == 1) ? sel[0] : 0u;
    const float4* v4 = (const float4*)vbuf;
    int n4 = NA / 4;
    for (int i = blockIdx.x * 256 + tid; i < n4; i += gridDim.x * 256) {
      float4 v = v4[i];
      float vv[4] = {v.x, v.y, v.z, v.w};
      #pragma unroll
      for (int j = 0; j < 4; ++j) {
        if (vv[j] > 0.0f) {
          unsigned bits = __float_as_uint(vv[j]);
          if (stage == 0) atomicAdd(&lh[bits >> 24], 1u);
          else if ((bits >> 24) == key) atomicAdd(&lh[(bits >> 16) & 0xFFu], 1u);
        }
      }
    }
  }
  __syncthreads();
  if (lh[tid] > 0u) atomicAdd(&hist8[tid], lh[tid]);
}

// ---------------- radix stage A/B scan (256 buckets) ----------------
__global__ __launch_bounds__(256) void k_scan8(const unsigned* __restrict__ hist8,
                                               unsigned* __restrict__ sel,
                                               int stage) {
  if (stage == 1 && sel[2]) return;
  __shared__ unsigned ss[256];
  int t = threadIdx.x;
  ss[t] = hist8[t];
  __syncthreads();
  for (int off = 1; off < 256; off <<= 1) {
    unsigned v = (t + off < 256) ? ss[t + off] : 0u;
    __syncthreads();
    ss[t] += v;
    __syncthreads();
  }
  unsigned rem = (stage == 0) ? KSEL : sel[1];
  if (stage == 0 && t == 0 && ss[0] < KSEL) {
    sel[2] = 1u; sel[3] = 0u;
  }
  unsigned S = ss[t];
  unsigned above = (t < 255) ? ss[t + 1] : 0u;
  if (S >= rem && above < rem) {
    if (stage == 0) { sel[0] = (unsigned)t; sel[1] = rem - above; }
    else            { sel[4] = (unsigned)t; sel[5] = rem - above; }
  }
}

// ---------------- radix stage C: hist of low 16 bits within slice ----------------
__global__ __launch_bounds__(256) void k_h16(const float* __restrict__ vbuf,
                                             const unsigned* __restrict__ sel,
                                             unsigned* __restrict__ hist16) {
  if (sel[2]) return;
  unsigned key16 = (sel[0] << 8) | sel[4];
  const float4* v4 = (const float4*)vbuf;
  int n4 = NA / 4;
  for (int i = blockIdx.x * 256 + threadIdx.x; i < n4; i += gridDim.x * 256) {
    float4 v = v4[i];
    float vv[4] = {v.x, v.y, v.z, v.w};
    #pragma unroll
    for (int j = 0; j < 4; ++j) {
      if (vv[j] > 0.0f) {
        unsigned bits = __float_as_uint(vv[j]);
        if ((bits >> 16) == key16) atomicAdd(&hist16[bits & 0xFFFFu], 1u);
      }
    }
  }
}

// ---------------- radix stage C scan (65536 buckets) ----------------
__global__ __launch_bounds__(1024) void k_scan16(const unsigned* __restrict__ hist16,
                                                 unsigned* __restrict__ sel) {
  if (sel[2]) return;
  __shared__ unsigned ss[1024];
  int t = threadIdx.x;
  unsigned rem = sel[5];
  unsigned sum = 0;
  for (int i = 0; i < 64; ++i) sum += hist16[t * 64 + i];
  ss[t] = sum;
  __syncthreads();
  for (int off = 1; off < 1024; off <<= 1) {
    unsigned v = (t + off < 1024) ? ss[t + off] : 0u;
    __syncthreads();
    ss[t] += v;
    __syncthreads();
  }
  unsigned S = ss[t];
  unsigned above = (t < 1023) ? ss[t + 1] : 0u;
  if (S >= rem && above < rem) {
    unsigned cum = above;
    for (int bb = t * 64 + 63; bb >= t * 64; --bb) {
      unsigned hb = hist16[bb];
      cum += hb;
      if (cum >= rem) {
        sel[3] = (((sel[0] << 8) | sel[4]) << 16) | (unsigned)bb;
        break;
      }
    }
  }
}

// ---------------- top-2 select + sparse softmax + embed + pos-enc (seq in bf16) ----
__global__ __launch_bounds__(256) void k_select(const float* __restrict__ vbuf,
                                                const unsigned* __restrict__ sel,
                                                const float* __restrict__ ce,
                                                unsigned short* __restrict__ seqb,
                                                float* __restrict__ out_sw,
                                                float* __restrict__ out_idx) {
  int wid = threadIdx.x >> 6;
  int lane = threadIdx.x & 63;
  int pos = blockIdx.x * 4 + wid;
  int hw = pos % 784;
  int hr = hw / 28;
  int wc = hw % 28;
  float thr = __uint_as_float(sel[3]);
  float a = vbuf[(size_t)pos * 64 + lane];
  float val = (a >= thr) ? a : 0.0f;
  unsigned long long nzm = __ballot(val > 0.0f);
  int count = __popcll(nzm);
  float v1 = val; int i1 = lane;
  #pragma unroll
  for (int off = 32; off > 0; off >>= 1) {
    float ov = __shfl_xor(v1, off);
    int oi = __shfl_xor(i1, off);
    if (ov > v1 || (ov == v1 && oi < i1)) { v1 = ov; i1 = oi; }
  }
  float vx = (lane == i1) ? -INFINITY : val;
  float v2 = vx; int i2 = lane;
  #pragma unroll
  for (int off = 32; off > 0; off >>= 1) {
    float ov = __shfl_xor(v2, off);
    int oi = __shfl_xor(i2, off);
    if (ov > v2 || (ov == v2 && oi < i2)) { v2 = ov; i2 = oi; }
  }
  float w1 = 0.0f, w2 = 0.0f;
  if (count >= 2) {
    float e = __expf(v2 - v1);
    float invd = 1.0f / (1.0f + e);
    w1 = invd; w2 = e * invd;
  } else if (count == 1) {
    w1 = 1.0f;
  }
  float wt = (lane == i1) ? w1 : ((lane == i2) ? w2 : 0.0f);
  out_sw[(size_t)pos * 64 + lane] = wt;
  if (lane < 2) out_idx[pos * 2 + lane] = (float)(lane == 0 ? i1 : i2);
  int d0 = lane * 4;
  float4 c1v = *(const float4*)(ce + (size_t)i1 * 256 + d0);
  float4 c2v = *(const float4*)(ce + (size_t)i2 * 256 + d0);
  float dv0 = __expf((float)d0 * PECOEF);
  float dv2 = __expf((float)(d0 + 2) * PECOEF);
  float ox = w1 * c1v.x + w2 * c2v.x + __sinf((float)hr * dv0);
  float oy = w1 * c1v.y + w2 * c2v.y + __cosf((float)wc * dv0);
  float oz = w1 * c1v.z + w2 * c2v.z + __sinf((float)hr * dv2);
  float ow = w1 * c1v.w + w2 * c2v.w + __cosf((float)wc * dv2);
  ushort4 ob = make_ushort4(f2b(ox), f2b(oy), f2b(oz), f2b(ow));
  *(ushort4*)(seqb + (size_t)pos * 256 + d0) = ob;
}

// ---- LDS-staged MFMA bf16 GEMM (m97 pattern): C = A[M][K] @ W[N][K]^T + bias ----
// 128x128 tile, BK=64, global_load_lds w16 staging with slot^row&7 swizzle.
// Q columns (<256) pre-scaled by QK2S for exp2-domain attention.
__global__ __launch_bounds__(256) void k_gemm_lds(const unsigned short* __restrict__ A,
                                                  const unsigned short* __restrict__ W,
                                                  const float* __restrict__ bias,
                                                  unsigned short* __restrict__ C,
                                                  int M, int N, int K) {
  __shared__ __align__(16) unsigned short As[8192];   // [128][64]
  __shared__ __align__(16) unsigned short Bs[8192];
  int tid = threadIdx.x;
  int lane = tid & 63, wid = tid >> 6;
  int q = lane & 15, g = lane >> 4;
  int m0 = blockIdx.y * 128, n0 = blockIdx.x * 128;
  int lrow = lane >> 3, s = lane & 7;          // staging: 8 rows x 8 slots per wave-instr
  const unsigned short* aSrc = A + (size_t)(m0 + wid * 8 + lrow) * K + (s ^ lrow) * 8;
  const unsigned short* bSrc = W + (size_t)(n0 + wid * 8 + lrow) * K + (s ^ lrow) * 8;
  int dstW = wid * 512;                        // ushort offset, wave-uniform
  int mloc = (wid >> 1) * 64, nloc = (wid & 1) * 64;
  int q7 = q & 7;
  f32x4 acc[4][4];
  #pragma unroll
  for (int i = 0; i < 4; ++i)
    #pragma unroll
    for (int j = 0; j < 4; ++j) acc[i][j] = (f32x4){0.f, 0.f, 0.f, 0.f};
  for (int k0 = 0; k0 < K; k0 += 64) {
    #pragma unroll
    for (int i = 0; i < 4; ++i) {
      __builtin_amdgcn_global_load_lds((const AS1 void*)(aSrc + (size_t)i * 32 * K + k0),
                                       (AS3 void*)(&As[i * 2048 + dstW]), 16, 0, 0);
      __builtin_amdgcn_global_load_lds((const AS1 void*)(bSrc + (size_t)i * 32 * K + k0),
                                       (AS3 void*)(&Bs[i * 2048 + dstW]), 16, 0, 0);
    }
    __syncthreads();
    #pragma unroll
    for (int kk = 0; kk < 2; ++kk) {
      bf16x8 af[4], bf[4];
      #pragma unroll
      for (int i = 0; i < 4; ++i)
        af[i] = *(const bf16x8*)&As[(mloc + i * 16 + q) * 64 + (((kk * 4 + g) ^ q7) * 8)];
      #pragma unroll
      for (int j = 0; j < 4; ++j)
        bf[j] = *(const bf16x8*)&Bs[(nloc + j * 16 + q) * 64 + (((kk * 4 + g) ^ q7) * 8)];
      __builtin_amdgcn_s_setprio(1);
      #pragma unroll
      for (int i = 0; i < 4; ++i)
        #pragma unroll
        for (int j = 0; j < 4; ++j)
          acc[i][j] = __builtin_amdgcn_mfma_f32_16x16x32_bf16(af[i], bf[j], acc[i][j], 0, 0, 0);
      __builtin_amdgcn_s_setprio(0);
    }
    __syncthreads();
  }
  #pragma unroll
  for (int j = 0; j < 4; ++j) {
    int col = n0 + nloc + j * 16 + q;
    float bj = bias[col];
    float qs = (col < 256) ? QK2S : 1.0f;
    #pragma unroll
    for (int i = 0; i < 4; ++i) {
      #pragma unroll
      for (int r = 0; r < 4; ++r) {
        int row = m0 + mloc + i * 16 + g * 4 + r;
        C[(size_t)row * N + col] = f2b((acc[i][j][r] + bj) * qs);
      }
    }
  }
}

// ------- V transpose WITH per-32-key permutation: Vt[(bh)*32+d][pos], where within
// each 32-col block, position p = g*8 + hi*4 + r  holds key  g*4 + hi*16 + r. -------
__global__ __launch_bounds__(256) void k_vt(const unsigned short* __restrict__ qkv,
                                            unsigned short* __restrict__ Vt) {
  __shared__ unsigned short lds[32][72];
  int k0 = blockIdx.x * 64;
  int bh = blockIdx.y;
  int b = bh >> 3, nh = bh & 7;
  int tid = threadIdx.x;
  int key = tid >> 2;
  int c8 = (tid & 3) * 8;
  int kk = k0 + key;
  ushort4 a = make_ushort4(0, 0, 0, 0), bq = a;
  if (kk < 784) {
    const unsigned short* src = qkv + (size_t)(b * 784 + kk) * 768 + 512 + nh * 32 + c8;
    a  = *(const ushort4*)src;
    bq = *(const ushort4*)(src + 4);
  }
  lds[c8 + 0][key] = a.x;  lds[c8 + 1][key] = a.y;
  lds[c8 + 2][key] = a.z;  lds[c8 + 3][key] = a.w;
  lds[c8 + 4][key] = bq.x; lds[c8 + 5][key] = bq.y;
  lds[c8 + 6][key] = bq.z; lds[c8 + 7][key] = bq.w;
  __syncthreads();
  int d = tid >> 3;
  int kc = (tid & 7) * 8;            // output position group
  if (k0 + kc < 800) {
    int sb = (kc & 32) + ((kc >> 3) & 3) * 4;   // source col base: blk32*32 + g*4
    ushort4 o0 = make_ushort4(lds[d][sb + 0],  lds[d][sb + 1],
                              lds[d][sb + 2],  lds[d][sb + 3]);    // hi=0
    ushort4 o1 = make_ushort4(lds[d][sb + 16], lds[d][sb + 17],
                              lds[d][sb + 18], lds[d][sb + 19]);   // hi=1
    unsigned short* dst = Vt + ((size_t)bh * 32 + d) * 800 + k0 + kc;
    *(ushort4*)dst = o0;
    *(ushort4*)(dst + 4) = o1;
  }
}

// ---- MFMA flash attention: 4 waves/block share (b,head); K/V LDS-staged via
// global_load_lds, double-buffered; conflict-free swz(q)=(q+(q>>2))&3 slot swizzle. ----
__global__ __launch_bounds__(256) void k_attn(const unsigned short* __restrict__ qkv,
                                              const unsigned short* __restrict__ Vt,
                                              unsigned short* __restrict__ ctx) {
  __shared__ __align__(16) unsigned short Kt[2][1024];   // [buf][32 keys x 32 dims]
  __shared__ __align__(16) unsigned short Vti[2][1024];  // [buf][32 dims x 32 kpos]
  int wid = threadIdx.x >> 6;
  int lane = threadIdx.x & 63;
  int blk = blockIdx.x;                       // 3328 = 8 XCDs * 416
  int wb = (blk & 7) * 416 + (blk >> 3);
  int bh = wb / 13;
  int qb = (wb - bh * 13) * 4 + wid;          // 0..51
  int b = bh >> 3, nh = bh & 7;
  int q = lane & 15, g = lane >> 4;
  bool active = (qb < 49);
  const f32x4 zero4 = {0.f, 0.f, 0.f, 0.f};

  int qrow = b * 784 + (active ? qb * 16 + q : q);
  bf16x8 qf = *(const bf16x8*)(qkv + (size_t)qrow * 768 + nh * 32 + g * 8);
  const unsigned short* kbase = qkv + (size_t)b * 784 * 768 + 256 + nh * 32;
  const unsigned short* vbase = Vt + (size_t)bh * 32 * 800;

  // staging geometry: wave 0 -> K rows 0-15, 1 -> K rows 16-31, 2 -> V rows 0-15,
  // 3 -> V rows 16-31. lane -> row r0+(lane>>2), lds 16B slot lane&3.
  int rit = ((wid & 1) << 4) + (lane >> 2);   // row in tile 0..31
  int sG = (lane & 3) ^ ((rit + (rit >> 2)) & 3);  // swizzled source slot
  bool isK = (wid < 2);
  int ldsoff = ((wid & 1) << 4) * 32;         // ushort offset of wave's half-tile

  // compute-side LDS addresses (swizzled slot; swz(16+q)==swz(q))
  int slotr = ((g ^ ((q + (q >> 2)) & 3)) << 3);
  int rowA = q * 32 + slotr;
  int rowB = (16 + q) * 32 + slotr;

  f32x4 acc0 = zero4, acc1 = zero4;
  float m = -INFINITY, lp = 0.f;

#define STAGE(buf, k0v)                                                         \
  {                                                                             \
    if (isK) {                                                                  \
      int key_ = (k0v) + rit; if (key_ > 783) key_ = 783;                       \
      __builtin_amdgcn_global_load_lds(                                         \
        (const AS1 void*)(kbase + (size_t)key_ * 768 + sG * 8),                 \
        (AS3 void*)(&Kt[buf][ldsoff]), 16, 0, 0);                               \
    } else {                                                                    \
      __builtin_amdgcn_global_load_lds(                                         \
        (const AS1 void*)(vbase + (size_t)rit * 800 + (k0v) + sG * 8),          \
        (AS3 void*)(&Vti[buf][ldsoff]), 16, 0, 0);                              \
    }                                                                           \
  }

  STAGE(0, 0);
  __syncthreads();

  for (int c = 0; c < 24; ++c) {
    int cur = c & 1;
    STAGE(cur ^ 1, (c + 1) * 32);
    bf16x8 kA = *(const bf16x8*)&Kt[cur][rowA];
    bf16x8 kB = *(const bf16x8*)&Kt[cur][rowB];
    bf16x8 va = *(const bf16x8*)&Vti[cur][rowA];
    bf16x8 vb = *(const bf16x8*)&Vti[cur][rowB];
    __builtin_amdgcn_s_setprio(1);
    f32x4 s0 = __builtin_amdgcn_mfma_f32_16x16x32_bf16(kA, qf, zero4, 0, 0, 0);
    f32x4 s1 = __builtin_amdgcn_mfma_f32_16x16x32_bf16(kB, qf, zero4, 0, 0, 0);
    __builtin_amdgcn_s_setprio(0);
    float pl = fmaxf(fmaxf(fmaxf(s0[0], s0[1]), fmaxf(s0[2], s0[3])),
                     fmaxf(fmaxf(s1[0], s1[1]), fmaxf(s1[2], s1[3])));
    if (!__all(pl <= m + THR2)) {
      float pm = fmaxf(pl, __shfl_xor(pl, 16));
      pm = fmaxf(pm, __shfl_xor(pm, 32));
      float mnew = fmaxf(m, pm);
      float sc = __builtin_amdgcn_exp2f(m - mnew);
      lp *= sc; acc0 *= sc; acc1 *= sc;
      m = mnew;
    }
    float p0[4], p1[4];
    #pragma unroll
    for (int r = 0; r < 4; ++r) {
      p0[r] = __builtin_amdgcn_exp2f(s0[r] - m);
      p1[r] = __builtin_amdgcn_exp2f(s1[r] - m);
    }
    lp += ((p0[0] + p0[1]) + (p0[2] + p0[3])) + ((p1[0] + p1[1]) + (p1[2] + p1[3]));
    union { unsigned u[4]; bf16x8 v; } pu;
    pu.u[0] = cvt_pk_bf16(p0[0], p0[1]);
    pu.u[1] = cvt_pk_bf16(p0[2], p0[3]);
    pu.u[2] = cvt_pk_bf16(p1[0], p1[1]);
    pu.u[3] = cvt_pk_bf16(p1[2], p1[3]);
    __builtin_amdgcn_s_setprio(1);
    acc0 = __builtin_amdgcn_mfma_f32_16x16x32_bf16(va, pu.v, acc0, 0, 0, 0);
    acc1 = __builtin_amdgcn_mfma_f32_16x16x32_bf16(vb, pu.v, acc1, 0, 0, 0);
    __builtin_amdgcn_s_setprio(0);
    __syncthreads();
  }
  { // tail: keys 768..783 in buf0 (staged during c=23)
    bf16x8 kA = *(const bf16x8*)&Kt[0][rowA];
    bf16x8 va = *(const bf16x8*)&Vti[0][rowA];
    bf16x8 vb = *(const bf16x8*)&Vti[0][rowB];
    f32x4 s0 = __builtin_amdgcn_mfma_f32_16x16x32_bf16(kA, qf, zero4, 0, 0, 0);
    float pl = fmaxf(fmaxf(s0[0], s0[1]), fmaxf(s0[2], s0[3]));
    if (!__all(pl <= m + THR2)) {
      float pm = fmaxf(pl, __shfl_xor(pl, 16));
      pm = fmaxf(pm, __shfl_xor(pm, 32));
      float mnew = fmaxf(m, pm);
      float sc = __builtin_amdgcn_exp2f(m - mnew);
      lp *= sc; acc0 *= sc; acc1 *= sc;
      m = mnew;
    }
    float p0[4];
    #pragma unroll
    for (int r = 0; r < 4; ++r) p0[r] = __builtin_amdgcn_exp2f(s0[r] - m);
    lp += (p0[0] + p0[1]) + (p0[2] + p0[3]);
    union { unsigned u[4]; bf16x8 v; } pu;
    pu.u[0] = cvt_pk_bf16(p0[0], p0[1]);
    pu.u[1] = cvt_pk_bf16(p0[2], p0[3]);
    pu.u[2] = 0u;
    pu.u[3] = 0u;
    acc0 = __builtin_amdgcn_mfma_f32_16x16x32_bf16(va, pu.v, acc0, 0, 0, 0);
    acc1 = __builtin_amdgcn_mfma_f32_16x16x32_bf16(vb, pu.v, acc1, 0, 0, 0);
  }
#undef STAGE
  float l = lp + __shfl_xor(lp, 16);
  l += __shfl_xor(l, 32);
  float linv = 1.f / l;
  if (active) {
    unsigned short* cp = ctx + (size_t)(b * 784 + qb * 16 + q) * 256 + nh * 32;
    ushort4 oA = make_ushort4(f2b(acc0[0] * linv), f2b(acc0[1] * linv),
                              f2b(acc0[2] * linv), f2b(acc0[3] * linv));
    ushort4 oB = make_ushort4(f2b(acc1[0] * linv), f2b(acc1[1] * linv),
                              f2b(acc1[2] * linv), f2b(acc1[3] * linv));
    *(ushort4*)(cp + g * 4) = oA;
    *(ushort4*)(cp + 16 + g * 4) = oB;
  }
}

// ---- mean-pool ctx (bf16 -> f32 partials): out-proj is deferred to a tiny GEMV ----
__global__ __launch_bounds__(256) void k_poolctx(const unsigned short* __restrict__ ctx,
                                                 float* __restrict__ part) {
  int b = blockIdx.x >> 3, sseg = blockIdx.x & 7;
  int d = threadIdx.x;
  const unsigned short* base = ctx + ((size_t)b * 784 + sseg * 98) * 256 + d;
  float acc = 0.f;
  for (int t = 0; t < 98; ++t)
    acc += __uint_as_float((unsigned)base[(size_t)t * 256] << 16);
  part[(size_t)blockIdx.x * 256 + d] = acc;
}

// ---- pooled[b] = mean_ctx[b] @ opw^T + opb  (f32, exact out-proj of the mean) ----
__global__ __launch_bounds__(256) void k_pgemv(const float* __restrict__ part,
                                               const float* __restrict__ opw,
                                               const float* __restrict__ opb,
                                               float* __restrict__ out) {
  __shared__ float mc[256];
  int b = blockIdx.x, d = threadIdx.x;
  float s = 0.f;
  #pragma unroll
  for (int i = 0; i < 8; ++i) s += part[(size_t)(b * 8 + i) * 256 + d];
  mc[d] = s * (1.0f / 784.0f);
  __syncthreads();
  float acc = opb[d];
  const float4* wr = (const float4*)(opw + (size_t)d * 256);
  #pragma unroll 8
  for (int j = 0; j < 64; ++j) {
    float4 w = wr[j];
    float4 m4 = *(const float4*)&mc[j * 4];
    acc += m4.x * w.x + m4.y * w.y + m4.z * w.z + m4.w * w.w;
  }
  out[b * 256 + d] = acc;
}

extern "C" void kernel_launch(void* const* d_in, const int* in_sizes, int n_in,
                              void* d_out, int out_size, void* d_ws, size_t ws_size,
                              hipStream_t stream) {
  (void)in_sizes; (void)n_in; (void)out_size; (void)ws_size;
  const float* x   = (const float*)d_in[0];
  const float* cw  = (const float*)d_in[1];
  const float* ce  = (const float*)d_in[2];
  const float* ipw = (const float*)d_in[3];
  const float* ipb = (const float*)d_in[4];
  const float* opw = (const float*)d_in[5];
  const float* opb = (const float*)d_in[6];

  float* out = (float*)d_out;
  float* pooled  = out;
  float* out_sw  = out + 8192;
  float* out_idx = out + 8192 + NA;

  float* ws = (float*)d_ws;
  float* vbuf = ws;                                   // NA f32
  unsigned* hist16 = (unsigned*)(ws + NA);            // 65536
  unsigned* hist8a = hist16 + 65536;                  // 256
  unsigned* hist8b = hist8a + 256;                    // 256
  unsigned* sel    = hist8b + 256;                    // 16
  unsigned short* seqb = (unsigned short*)(ws + NA + 66080);  // SEQN bf16 (later: ctx)
  unsigned short* qkvb = seqb + SEQN;                 // 3*SEQN bf16
  unsigned short* Vt   = qkvb + 3 * (size_t)SEQN;     // 256*32*800 bf16
  unsigned short* wb   = Vt + 256 * 32 * 800;         // 196608 bf16 (in_proj only)
  float* part = (float*)(wb + 262144);                // 65536 f32

  k_zero<<<(66080 + 255) / 256, 256, 0, stream>>>(hist16, 66080);
  k_cast<<<768, 256, 0, stream>>>(ipw, wb);
  k_conv<<<224, 256, 0, stream>>>(x, cw, vbuf);
  k_h8<<<1024, 256, 0, stream>>>(vbuf, sel, hist8a, 0);
  k_scan8<<<1, 256, 0, stream>>>(hist8a, sel, 0);
  k_h8<<<1024, 256, 0, stream>>>(vbuf, sel, hist8b, 1);
  k_scan8<<<1, 256, 0, stream>>>(hist8b, sel, 1);
  k_h16<<<1024, 256, 0, stream>>>(vbuf, sel, hist16);
  k_scan16<<<1, 1024, 0, stream>>>(hist16, sel);
  k_select<<<25088 / 4, 256, 0, stream>>>(vbuf, sel, ce, seqb, out_sw, out_idx);
  {
    dim3 gq(768 / 128, 25088 / 128);
    k_gemm_lds<<<gq, 256, 0, stream>>>(seqb, wb, ipb, qkvb, 25088, 768, 256);
  }
  {
    dim3 gv(13, 256);
    k_vt<<<gv, 256, 0, stream>>>(qkvb, Vt);
  }
  k_attn<<<3328, 256, 0, stream>>>(qkvb, Vt, seqb /* ctx */);
  k_poolctx<<<256, 256, 0, stream>>>(seqb, part);
  k_pgemv<<<NB, 256, 0, stream>>>(part, opw, opb, pooled);
}

// Round 9
// 183.239 us; speedup vs baseline: 22.7376x; 1.0431x over previous
//
#include <hip/hip_runtime.h>
#include <cmath>

#define NB 32
#define C1N 64
#define DIM 256
#define NHEAD 8
#define SEQL 784
#define NA 1605632      /* NB*SEQL*C1N */
#define SEQN 6422528    /* NB*SEQL*DIM */
#define KSEL 803u
#define QK2S (0.17677669529663687f * 1.4426950408889634f)  /* (1/sqrt(32)) * log2(e) */
#define THR2 11.541560f              /* 8 * log2(e) */
#define PECOEF (-0.03597789207803197f) /* -ln(10000)/256 */

#define AS1 __attribute__((address_space(1)))
#define AS3 __attribute__((address_space(3)))

typedef __attribute__((ext_vector_type(8))) short bf16x8;
typedef __attribute__((ext_vector_type(4))) float f32x4;

__device__ __forceinline__ unsigned short f2b(float f) {
  unsigned u = __float_as_uint(f);
  unsigned r = u + 0x7fffu + ((u >> 16) & 1u);
  return (unsigned short)(r >> 16);
}

__device__ __forceinline__ unsigned cvt_pk_bf16(float lo, float hi) {
  unsigned r;
  asm("v_cvt_pk_bf16_f32 %0, %1, %2" : "=v"(r) : "v"(lo), "v"(hi));
  return r;
}

// ---------------- zero hist + cast in_proj weights (fused) ----------------
__global__ __launch_bounds__(256) void k_init(const float* __restrict__ ipw,
                                              unsigned short* __restrict__ wbuf,
                                              unsigned* __restrict__ z) {
  int i = blockIdx.x * 256 + threadIdx.x;
  if (i < 66080) z[i] = 0u;
  wbuf[i] = f2b(ipw[i]);   // grid covers exactly 196608
}

// ---------------- conv + relu: LDS weights (transposed) + padded LDS image -------
__global__ __launch_bounds__(256) void k_conv(const float* __restrict__ x,
                                              const float* __restrict__ cw,
                                              float* __restrict__ vbuf) {
  __shared__ __align__(16) float ximg[1296];   // 36x36 zero-padded image
  __shared__ float wlds[5184];                 // [tap 0..80][channel 0..63]
  int tid = threadIdx.x;
  int b = blockIdx.x / 7, sblk = blockIdx.x % 7;
  for (int e = tid; e < 1296; e += 256) ximg[e] = 0.f;
  for (int e = tid; e < 5184; e += 256) {
    int c = e / 81, t = e - c * 81;
    wlds[t * 64 + c] = cw[e];
  }
  __syncthreads();
  const float* xb = x + b * 784;
  for (int e = tid; e < 784; e += 256) {
    int row = e / 28, col = e - row * 28;
    ximg[(row + 4) * 36 + col + 4] = xb[e];
  }
  __syncthreads();
  int wv = tid >> 6, lane = tid & 63;
  for (int it = 0; it < 7; ++it) {
    int grp = sblk * 28 + it * 4 + wv;     // 0..195
    int hr = grp / 7, wc0 = (grp % 7) * 4;
    float a0 = 0.f, a1 = 0.f, a2 = 0.f, a3 = 0.f;
    #pragma unroll
    for (int dy = 0; dy < 9; ++dy) {
      const float4* xr4 = (const float4*)&ximg[(hr + dy) * 36 + wc0];
      float4 xa = xr4[0], xbq = xr4[1], xc = xr4[2];
      float xr[12] = {xa.x, xa.y, xa.z, xa.w, xbq.x, xbq.y, xbq.z, xbq.w,
                      xc.x, xc.y, xc.z, xc.w};
      #pragma unroll
      for (int dx = 0; dx < 9; ++dx) {
        float w = wlds[(dy * 9 + dx) * 64 + lane];
        a0 = fmaf(xr[dx + 0], w, a0);
        a1 = fmaf(xr[dx + 1], w, a1);
        a2 = fmaf(xr[dx + 2], w, a2);
        a3 = fmaf(xr[dx + 3], w, a3);
      }
    }
    size_t base = ((size_t)(b * 784 + hr * 28 + wc0)) * 64 + lane;
    vbuf[base +   0] = fmaxf(a0, 0.f);
    vbuf[base +  64] = fmaxf(a1, 0.f);
    vbuf[base + 128] = fmaxf(a2, 0.f);
    vbuf[base + 192] = fmaxf(a3, 0.f);
  }
}

// ---------------- radix stage A/B: 8-bit hist, LDS-privatized ----------------
__global__ __launch_bounds__(256) void k_h8(const float* __restrict__ vbuf,
                                            const unsigned* __restrict__ sel,
                                            unsigned* __restrict__ hist8,
                                            int stage) {
  __shared__ unsigned lh[256];
  int tid = threadIdx.x;
  lh[tid] = 0u;
  __syncthreads();
  if (stage == 0 || sel[2] == 0u) {
    unsigned key = (stage == 1) ? sel[0] : 0u;
    const float4* v4 = (const float4*)vbuf;
    int n4 = NA / 4;
    for (int i = blockIdx.x * 256 + tid; i < n4; i += gridDim.x * 256) {
      float4 v = v4[i];
      float vv[4] = {v.x, v.y, v.z, v.w};
      #pragma unroll
      for (int j = 0; j < 4; ++j) {
        if (vv[j] > 0.0f) {
          unsigned bits = __float_as_uint(vv[j]);
          if (stage == 0) atomicAdd(&lh[bits >> 24], 1u);
          else if ((bits >> 24) == key) atomicAdd(&lh[(bits >> 16) & 0xFFu], 1u);
        }
      }
    }
  }
  __syncthreads();
  if (lh[tid] > 0u) atomicAdd(&hist8[tid], lh[tid]);
}

// ---------------- radix stage A/B scan (256 buckets) ----------------
__global__ __launch_bounds__(256) void k_scan8(const unsigned* __restrict__ hist8,
                                               unsigned* __restrict__ sel,
                                               int stage) {
  if (stage == 1 && sel[2]) return;
  __shared__ unsigned ss[256];
  int t = threadIdx.x;
  ss[t] = hist8[t];
  __syncthreads();
  for (int off = 1; off < 256; off <<= 1) {
    unsigned v = (t + off < 256) ? ss[t + off] : 0u;
    __syncthreads();
    ss[t] += v;
    __syncthreads();
  }
  unsigned rem = (stage == 0) ? KSEL : sel[1];
  if (stage == 0 && t == 0 && ss[0] < KSEL) {
    sel[2] = 1u; sel[3] = 0u;
  }
  unsigned S = ss[t];
  unsigned above = (t < 255) ? ss[t + 1] : 0u;
  if (S >= rem && above < rem) {
    if (stage == 0) { sel[0] = (unsigned)t; sel[1] = rem - above; }
    else            { sel[4] = (unsigned)t; sel[5] = rem - above; }
  }
}

// ---------------- radix stage C: hist of low 16 bits within slice ----------------
__global__ __launch_bounds__(256) void k_h16(const float* __restrict__ vbuf,
                                             const unsigned* __restrict__ sel,
                                             unsigned* __restrict__ hist16) {
  if (sel[2]) return;
  unsigned key16 = (sel[0] << 8) | sel[4];
  const float4* v4 = (const float4*)vbuf;
  int n4 = NA / 4;
  for (int i = blockIdx.x * 256 + threadIdx.x; i < n4; i += gridDim.x * 256) {
    float4 v = v4[i];
    float vv[4] = {v.x, v.y, v.z, v.w};
    #pragma unroll
    for (int j = 0; j < 4; ++j) {
      if (vv[j] > 0.0f) {
        unsigned bits = __float_as_uint(vv[j]);
        if ((bits >> 16) == key16) atomicAdd(&hist16[bits & 0xFFFFu], 1u);
      }
    }
  }
}

// ---------------- radix stage C scan (65536 buckets) ----------------
__global__ __launch_bounds__(1024) void k_scan16(const unsigned* __restrict__ hist16,
                                                 unsigned* __restrict__ sel) {
  if (sel[2]) return;
  __shared__ unsigned ss[1024];
  int t = threadIdx.x;
  unsigned rem = sel[5];
  unsigned sum = 0;
  for (int i = 0; i < 64; ++i) sum += hist16[t * 64 + i];
  ss[t] = sum;
  __syncthreads();
  for (int off = 1; off < 1024; off <<= 1) {
    unsigned v = (t + off < 1024) ? ss[t + off] : 0u;
    __syncthreads();
    ss[t] += v;
    __syncthreads();
  }
  unsigned S = ss[t];
  unsigned above = (t < 1023) ? ss[t + 1] : 0u;
  if (S >= rem && above < rem) {
    unsigned cum = above;
    for (int bb = t * 64 + 63; bb >= t * 64; --bb) {
      unsigned hb = hist16[bb];
      cum += hb;
      if (cum >= rem) {
        sel[3] = (((sel[0] << 8) | sel[4]) << 16) | (unsigned)bb;
        break;
      }
    }
  }
}

// ---------------- top-2 select + sparse softmax + embed + pos-enc (seq in bf16) ----
__global__ __launch_bounds__(256) void k_select(const float* __restrict__ vbuf,
                                                const unsigned* __restrict__ sel,
                                                const float* __restrict__ ce,
                                                unsigned short* __restrict__ seqb,
                                                float* __restrict__ out_sw,
                                                float* __restrict__ out_idx) {
  int wid = threadIdx.x >> 6;
  int lane = threadIdx.x & 63;
  int pos = blockIdx.x * 4 + wid;
  int hw = pos % 784;
  int hr = hw / 28;
  int wc = hw % 28;
  float thr = __uint_as_float(sel[3]);
  float a = vbuf[(size_t)pos * 64 + lane];
  float val = (a >= thr) ? a : 0.0f;
  unsigned long long nzm = __ballot(val > 0.0f);
  int count = __popcll(nzm);
  float v1 = val; int i1 = lane;
  #pragma unroll
  for (int off = 32; off > 0; off >>= 1) {
    float ov = __shfl_xor(v1, off);
    int oi = __shfl_xor(i1, off);
    if (ov > v1 || (ov == v1 && oi < i1)) { v1 = ov; i1 = oi; }
  }
  float vx = (lane == i1) ? -INFINITY : val;
  float v2 = vx; int i2 = lane;
  #pragma unroll
  for (int off = 32; off > 0; off >>= 1) {
    float ov = __shfl_xor(v2, off);
    int oi = __shfl_xor(i2, off);
    if (ov > v2 || (ov == v2 && oi < i2)) { v2 = ov; i2 = oi; }
  }
  float w1 = 0.0f, w2 = 0.0f;
  if (count >= 2) {
    float e = __expf(v2 - v1);
    float invd = 1.0f / (1.0f + e);
    w1 = invd; w2 = e * invd;
  } else if (count == 1) {
    w1 = 1.0f;
  }
  float wt = (lane == i1) ? w1 : ((lane == i2) ? w2 : 0.0f);
  out_sw[(size_t)pos * 64 + lane] = wt;
  if (lane < 2) out_idx[pos * 2 + lane] = (float)(lane == 0 ? i1 : i2);
  int d0 = lane * 4;
  float4 c1v = *(const float4*)(ce + (size_t)i1 * 256 + d0);
  float4 c2v = *(const float4*)(ce + (size_t)i2 * 256 + d0);
  float dv0 = __expf((float)d0 * PECOEF);
  float dv2 = __expf((float)(d0 + 2) * PECOEF);
  float ox = w1 * c1v.x + w2 * c2v.x + __sinf((float)hr * dv0);
  float oy = w1 * c1v.y + w2 * c2v.y + __cosf((float)wc * dv0);
  float oz = w1 * c1v.z + w2 * c2v.z + __sinf((float)hr * dv2);
  float ow = w1 * c1v.w + w2 * c2v.w + __cosf((float)wc * dv2);
  ushort4 ob = make_ushort4(f2b(ox), f2b(oy), f2b(oz), f2b(ow));
  *(ushort4*)(seqb + (size_t)pos * 256 + d0) = ob;
}

// ---- LDS-staged MFMA bf16 GEMM (m97 pattern): C = A[M][K] @ W[N][K]^T + bias ----
__global__ __launch_bounds__(256) void k_gemm_lds(const unsigned short* __restrict__ A,
                                                  const unsigned short* __restrict__ W,
                                                  const float* __restrict__ bias,
                                                  unsigned short* __restrict__ C,
                                                  int M, int N, int K) {
  __shared__ __align__(16) unsigned short As[8192];   // [128][64]
  __shared__ __align__(16) unsigned short Bs[8192];
  int tid = threadIdx.x;
  int lane = tid & 63, wid = tid >> 6;
  int q = lane & 15, g = lane >> 4;
  int m0 = blockIdx.y * 128, n0 = blockIdx.x * 128;
  int lrow = lane >> 3, s = lane & 7;
  const unsigned short* aSrc = A + (size_t)(m0 + wid * 8 + lrow) * K + (s ^ lrow) * 8;
  const unsigned short* bSrc = W + (size_t)(n0 + wid * 8 + lrow) * K + (s ^ lrow) * 8;
  int dstW = wid * 512;
  int mloc = (wid >> 1) * 64, nloc = (wid & 1) * 64;
  int q7 = q & 7;
  f32x4 acc[4][4];
  #pragma unroll
  for (int i = 0; i < 4; ++i)
    #pragma unroll
    for (int j = 0; j < 4; ++j) acc[i][j] = (f32x4){0.f, 0.f, 0.f, 0.f};
  for (int k0 = 0; k0 < K; k0 += 64) {
    #pragma unroll
    for (int i = 0; i < 4; ++i) {
      __builtin_amdgcn_global_load_lds((const AS1 void*)(aSrc + (size_t)i * 32 * K + k0),
                                       (AS3 void*)(&As[i * 2048 + dstW]), 16, 0, 0);
      __builtin_amdgcn_global_load_lds((const AS1 void*)(bSrc + (size_t)i * 32 * K + k0),
                                       (AS3 void*)(&Bs[i * 2048 + dstW]), 16, 0, 0);
    }
    __syncthreads();
    #pragma unroll
    for (int kk = 0; kk < 2; ++kk) {
      bf16x8 af[4], bf[4];
      #pragma unroll
      for (int i = 0; i < 4; ++i)
        af[i] = *(const bf16x8*)&As[(mloc + i * 16 + q) * 64 + (((kk * 4 + g) ^ q7) * 8)];
      #pragma unroll
      for (int j = 0; j < 4; ++j)
        bf[j] = *(const bf16x8*)&Bs[(nloc + j * 16 + q) * 64 + (((kk * 4 + g) ^ q7) * 8)];
      __builtin_amdgcn_s_setprio(1);
      #pragma unroll
      for (int i = 0; i < 4; ++i)
        #pragma unroll
        for (int j = 0; j < 4; ++j)
          acc[i][j] = __builtin_amdgcn_mfma_f32_16x16x32_bf16(af[i], bf[j], acc[i][j], 0, 0, 0);
      __builtin_amdgcn_s_setprio(0);
    }
    __syncthreads();
  }
  #pragma unroll
  for (int j = 0; j < 4; ++j) {
    int col = n0 + nloc + j * 16 + q;
    float bj = bias[col];
    float qs = (col < 256) ? QK2S : 1.0f;
    #pragma unroll
    for (int i = 0; i < 4; ++i) {
      #pragma unroll
      for (int r = 0; r < 4; ++r) {
        int row = m0 + mloc + i * 16 + g * 4 + r;
        C[(size_t)row * N + col] = f2b((acc[i][j][r] + bj) * qs);
      }
    }
  }
}

// ------- V transpose WITH per-32-key permutation: Vt[(bh)*32+d][pos], where within
// each 32-col block, position p = g*8 + hi*4 + r  holds key  g*4 + hi*16 + r. -------
__global__ __launch_bounds__(256) void k_vt(const unsigned short* __restrict__ qkv,
                                            unsigned short* __restrict__ Vt) {
  __shared__ unsigned short lds[32][72];
  int k0 = blockIdx.x * 64;
  int bh = blockIdx.y;
  int b = bh >> 3, nh = bh & 7;
  int tid = threadIdx.x;
  int key = tid >> 2;
  int c8 = (tid & 3) * 8;
  int kk = k0 + key;
  ushort4 a = make_ushort4(0, 0, 0, 0), bq = a;
  if (kk < 784) {
    const unsigned short* src = qkv + (size_t)(b * 784 + kk) * 768 + 512 + nh * 32 + c8;
    a  = *(const ushort4*)src;
    bq = *(const ushort4*)(src + 4);
  }
  lds[c8 + 0][key] = a.x;  lds[c8 + 1][key] = a.y;
  lds[c8 + 2][key] = a.z;  lds[c8 + 3][key] = a.w;
  lds[c8 + 4][key] = bq.x; lds[c8 + 5][key] = bq.y;
  lds[c8 + 6][key] = bq.z; lds[c8 + 7][key] = bq.w;
  __syncthreads();
  int d = tid >> 3;
  int kc = (tid & 7) * 8;
  if (k0 + kc < 800) {
    int sb = (kc & 32) + ((kc >> 3) & 3) * 4;
    ushort4 o0 = make_ushort4(lds[d][sb + 0],  lds[d][sb + 1],
                              lds[d][sb + 2],  lds[d][sb + 3]);
    ushort4 o1 = make_ushort4(lds[d][sb + 16], lds[d][sb + 17],
                              lds[d][sb + 18], lds[d][sb + 19]);
    unsigned short* dst = Vt + ((size_t)bh * 32 + d) * 800 + k0 + kc;
    *(ushort4*)dst = o0;
    *(ushort4*)(dst + 4) = o1;
  }
}

// ---- MFMA flash attention: 4 waves/block share (b,head); 3-buffer LDS pipeline,
// stage 2 tiles ahead, raw s_barrier + counted s_waitcnt vmcnt(1) (T3/T4). ----
__global__ __launch_bounds__(256) void k_attn(const unsigned short* __restrict__ qkv,
                                              const unsigned short* __restrict__ Vt,
                                              unsigned short* __restrict__ ctx) {
  __shared__ __align__(16) unsigned short Kt[3][1024];   // [buf][32 keys x 32 dims]
  __shared__ __align__(16) unsigned short Vti[3][1024];  // [buf][32 dims x 32 kpos]
  int wid = threadIdx.x >> 6;
  int lane = threadIdx.x & 63;
  int blk = blockIdx.x;                       // 3328 = 8 XCDs * 416
  int wrk = (blk & 7) * 416 + (blk >> 3);
  int bh = wrk / 13;
  int qb = (wrk - bh * 13) * 4 + wid;         // 0..51
  int b = bh >> 3, nh = bh & 7;
  int q = lane & 15, g = lane >> 4;
  bool active = (qb < 49);
  const f32x4 zero4 = {0.f, 0.f, 0.f, 0.f};

  int qrow = b * 784 + (active ? qb * 16 + q : q);
  bf16x8 qf = *(const bf16x8*)(qkv + (size_t)qrow * 768 + nh * 32 + g * 8);
  asm volatile("s_waitcnt vmcnt(0)" ::: "memory");   // qf resident; vmcnt baseline 0

  const unsigned short* kbase = qkv + (size_t)b * 784 * 768 + 256 + nh * 32;
  const unsigned short* vbase = Vt + (size_t)bh * 32 * 800;

  // staging: wave 0 -> K rows 0-15, 1 -> K rows 16-31, 2 -> V d-rows 0-15,
  // 3 -> V d-rows 16-31; lane -> row r0+(lane>>2), 16B slot (lane&3) swizzled.
  int rit = ((wid & 1) << 4) + (lane >> 2);
  int sG = (lane & 3) ^ ((rit + (rit >> 2)) & 3);
  bool isK = (wid < 2);
  int ldsoff = ((wid & 1) << 4) * 32;
  const unsigned short* sp = isK ? (kbase + (size_t)rit * 768 + sG * 8)
                                 : (vbase + (size_t)rit * 800 + sG * 8);
  const int sstride = isK ? (32 * 768) : 32;
  unsigned short* ldsb = (isK ? &Kt[0][0] : &Vti[0][0]) + ldsoff;

  int slotr = ((g ^ ((q + (q >> 2)) & 3)) << 3);
  int rowA = q * 32 + slotr;
  int rowB = (16 + q) * 32 + slotr;

  f32x4 acc0 = zero4, acc1 = zero4;
  float m = -INFINITY, lp = 0.f;

#define STAGE(BUFO) {                                                          \
    __builtin_amdgcn_global_load_lds((const AS1 void*)sp,                      \
                                     (AS3 void*)(ldsb + (BUFO)), 16, 0, 0);    \
    sp += sstride; }

#define STEP(CUR, NXT) {                                                       \
    asm volatile("s_waitcnt vmcnt(1)" ::: "memory");                           \
    __builtin_amdgcn_s_barrier();                                              \
    asm volatile("" ::: "memory");                                             \
    STAGE(NXT);                                                                \
    bf16x8 kA = *(const bf16x8*)&Kt[0][(CUR) + rowA];                          \
    bf16x8 kB = *(const bf16x8*)&Kt[0][(CUR) + rowB];                          \
    bf16x8 va = *(const bf16x8*)&Vti[0][(CUR) + rowA];                         \
    bf16x8 vb = *(const bf16x8*)&Vti[0][(CUR) + rowB];                         \
    __builtin_amdgcn_s_setprio(1);                                             \
    f32x4 s0 = __builtin_amdgcn_mfma_f32_16x16x32_bf16(kA, qf, zero4, 0, 0, 0);\
    f32x4 s1 = __builtin_amdgcn_mfma_f32_16x16x32_bf16(kB, qf, zero4, 0, 0, 0);\
    __builtin_amdgcn_s_setprio(0);                                             \
    float pl = fmaxf(fmaxf(fmaxf(s0[0], s0[1]), fmaxf(s0[2], s0[3])),          \
                     fmaxf(fmaxf(s1[0], s1[1]), fmaxf(s1[2], s1[3])));         \
    if (!__all(pl <= m + THR2)) {                                              \
      float pm = fmaxf(pl, __shfl_xor(pl, 16));                                \
      pm = fmaxf(pm, __shfl_xor(pm, 32));                                      \
      float mnew = fmaxf(m, pm);                                               \
      float sc = __builtin_amdgcn_exp2f(m - mnew);                             \
      lp *= sc; acc0 *= sc; acc1 *= sc;                                        \
      m = mnew;                                                                \
    }                                                                          \
    float p0[4], p1[4];                                                        \
    _Pragma("unroll")                                                          \
    for (int r = 0; r < 4; ++r) {                                              \
      p0[r] = __builtin_amdgcn_exp2f(s0[r] - m);                               \
      p1[r] = __builtin_amdgcn_exp2f(s1[r] - m);                               \
    }                                                                          \
    lp += ((p0[0] + p0[1]) + (p0[2] + p0[3]))                                  \
        + ((p1[0] + p1[1]) + (p1[2] + p1[3]));                                 \
    union { unsigned u[4]; bf16x8 v; } pu;                                     \
    pu.u[0] = cvt_pk_bf16(p0[0], p0[1]);                                       \
    pu.u[1] = cvt_pk_bf16(p0[2], p0[3]);                                       \
    pu.u[2] = cvt_pk_bf16(p1[0], p1[1]);                                       \
    pu.u[3] = cvt_pk_bf16(p1[2], p1[3]);                                       \
    __builtin_amdgcn_s_setprio(1);                                             \
    acc0 = __builtin_amdgcn_mfma_f32_16x16x32_bf16(va, pu.v, acc0, 0, 0, 0);   \
    acc1 = __builtin_amdgcn_mfma_f32_16x16x32_bf16(vb, pu.v, acc1, 0, 0, 0);   \
    __builtin_amdgcn_s_setprio(0);                                             \
  }

  STAGE(0);     // tile 0 -> buf0
  STAGE(1024);  // tile 1 -> buf1

  // 24 full tiles (keys 0..767); stages run 2 ahead (tiles 2..25; 25 is a dummy
  // over-read into adjacent mapped ws buffers, never consumed).
  for (int t = 0; t < 8; ++t) {
    STEP(0, 2048);
    STEP(1024, 0);
    STEP(2048, 1024);
  }
  { // tail: tile 24 (keys 768..799) in buf0; K rows 16-31 / V pos >=784 unused/zero.
    asm volatile("s_waitcnt vmcnt(1)" ::: "memory");
    __builtin_amdgcn_s_barrier();
    asm volatile("" ::: "memory");
    bf16x8 kA = *(const bf16x8*)&Kt[0][rowA];
    bf16x8 va = *(const bf16x8*)&Vti[0][rowA];
    bf16x8 vb = *(const bf16x8*)&Vti[0][rowB];
    f32x4 s0 = __builtin_amdgcn_mfma_f32_16x16x32_bf16(kA, qf, zero4, 0, 0, 0);
    float pl = fmaxf(fmaxf(s0[0], s0[1]), fmaxf(s0[2], s0[3]));
    if (!__all(pl <= m + THR2)) {
      float pm = fmaxf(pl, __shfl_xor(pl, 16));
      pm = fmaxf(pm, __shfl_xor(pm, 32));
      float mnew = fmaxf(m, pm);
      float sc = __builtin_amdgcn_exp2f(m - mnew);
      lp *= sc; acc0 *= sc; acc1 *= sc;
      m = mnew;
    }
    float p0[4];
    #pragma unroll
    for (int r = 0; r < 4; ++r) p0[r] = __builtin_amdgcn_exp2f(s0[r] - m);
    lp += (p0[0] + p0[1]) + (p0[2] + p0[3]);
    union { unsigned u[4]; bf16x8 v; } pu;
    pu.u[0] = cvt_pk_bf16(p0[0], p0[1]);
    pu.u[1] = cvt_pk_bf16(p0[2], p0[3]);
    pu.u[2] = 0u;
    pu.u[3] = 0u;
    acc0 = __builtin_amdgcn_mfma_f32_16x16x32_bf16(va, pu.v, acc0, 0, 0, 0);
    acc1 = __builtin_amdgcn_mfma_f32_16x16x32_bf16(vb, pu.v, acc1, 0, 0, 0);
  }
#undef STEP
#undef STAGE
  float l = lp + __shfl_xor(lp, 16);
  l += __shfl_xor(l, 32);
  float linv = 1.f / l;
  if (active) {
    unsigned short* cp = ctx + (size_t)(b * 784 + qb * 16 + q) * 256 + nh * 32;
    ushort4 oA = make_ushort4(f2b(acc0[0] * linv), f2b(acc0[1] * linv),
                              f2b(acc0[2] * linv), f2b(acc0[3] * linv));
    ushort4 oB = make_ushort4(f2b(acc1[0] * linv), f2b(acc1[1] * linv),
                              f2b(acc1[2] * linv), f2b(acc1[3] * linv));
    *(ushort4*)(cp + g * 4) = oA;
    *(ushort4*)(cp + 16 + g * 4) = oB;
  }
}

// ---- mean-pool ctx (bf16 -> f32 partials): out-proj is deferred to a tiny GEMV ----
__global__ __launch_bounds__(256) void k_poolctx(const unsigned short* __restrict__ ctx,
                                                 float* __restrict__ part) {
  int b = blockIdx.x >> 3, sseg = blockIdx.x & 7;
  int d = threadIdx.x;
  const unsigned short* base = ctx + ((size_t)b * 784 + sseg * 98) * 256 + d;
  float acc = 0.f;
  for (int t = 0; t < 98; ++t)
    acc += __uint_as_float((unsigned)base[(size_t)t * 256] << 16);
  part[(size_t)blockIdx.x * 256 + d] = acc;
}

// ---- pooled[b] = mean_ctx[b] @ opw^T + opb  (f32, exact out-proj of the mean) ----
__global__ __launch_bounds__(256) void k_pgemv(const float* __restrict__ part,
                                               const float* __restrict__ opw,
                                               const float* __restrict__ opb,
                                               float* __restrict__ out) {
  __shared__ float mc[256];
  int b = blockIdx.x, d = threadIdx.x;
  float s = 0.f;
  #pragma unroll
  for (int i = 0; i < 8; ++i) s += part[(size_t)(b * 8 + i) * 256 + d];
  mc[d] = s * (1.0f / 784.0f);
  __syncthreads();
  float acc = opb[d];
  const float4* wr = (const float4*)(opw + (size_t)d * 256);
  #pragma unroll 8
  for (int j = 0; j < 64; ++j) {
    float4 w = wr[j];
    float4 m4 = *(const float4*)&mc[j * 4];
    acc += m4.x * w.x + m4.y * w.y + m4.z * w.z + m4.w * w.w;
  }
  out[b * 256 + d] = acc;
}

extern "C" void kernel_launch(void* const* d_in, const int* in_sizes, int n_in,
                              void* d_out, int out_size, void* d_ws, size_t ws_size,
                              hipStream_t stream) {
  (void)in_sizes; (void)n_in; (void)out_size; (void)ws_size;
  const float* x   = (const float*)d_in[0];
  const float* cw  = (const float*)d_in[1];
  const float* ce  = (const float*)d_in[2];
  const float* ipw = (const float*)d_in[3];
  const float* ipb = (const float*)d_in[4];
  const float* opw = (const float*)d_in[5];
  const float* opb = (const float*)d_in[6];

  float* out = (float*)d_out;
  float* pooled  = out;
  float* out_sw  = out + 8192;
  float* out_idx = out + 8192 + NA;

  float* ws = (float*)d_ws;
  float* vbuf = ws;                                   // NA f32
  unsigned* hist16 = (unsigned*)(ws + NA);            // 65536
  unsigned* hist8a = hist16 + 65536;                  // 256
  unsigned* hist8b = hist8a + 256;                    // 256
  unsigned* sel    = hist8b + 256;                    // 16
  unsigned short* seqb = (unsigned short*)(ws + NA + 66080);  // SEQN bf16 (later: ctx)
  unsigned short* qkvb = seqb + SEQN;                 // 3*SEQN bf16
  unsigned short* Vt   = qkvb + 3 * (size_t)SEQN;     // 256*32*800 bf16
  unsigned short* wbuf = Vt + 256 * 32 * 800;         // 196608 bf16 (in_proj only)
  float* part = (float*)(wbuf + 262144);              // 65536 f32

  k_init<<<768, 256, 0, stream>>>(ipw, wbuf, hist16);
  k_conv<<<224, 256, 0, stream>>>(x, cw, vbuf);
  k_h8<<<1024, 256, 0, stream>>>(vbuf, sel, hist8a, 0);
  k_scan8<<<1, 256, 0, stream>>>(hist8a, sel, 0);
  k_h8<<<1024, 256, 0, stream>>>(vbuf, sel, hist8b, 1);
  k_scan8<<<1, 256, 0, stream>>>(hist8b, sel, 1);
  k_h16<<<1024, 256, 0, stream>>>(vbuf, sel, hist16);
  k_scan16<<<1, 1024, 0, stream>>>(hist16, sel);
  k_select<<<25088 / 4, 256, 0, stream>>>(vbuf, sel, ce, seqb, out_sw, out_idx);
  {
    dim3 gq(768 / 128, 25088 / 128);
    k_gemm_lds<<<gq, 256, 0, stream>>>(seqb, wbuf, ipb, qkvb, 25088, 768, 256);
  }
  {
    dim3 gv(13, 256);
    k_vt<<<gv, 256, 0, stream>>>(qkvb, Vt);
  }
  k_attn<<<3328, 256, 0, stream>>>(qkvb, Vt, seqb /* ctx */);
  k_poolctx<<<256, 256, 0, stream>>>(seqb, part);
  k_pgemv<<<NB, 256, 0, stream>>>(part, opw, opb, pooled);
}

// Round 10
// 164.773 us; speedup vs baseline: 25.2859x; 1.1121x over previous
//
#include <hip/hip_runtime.h>
#include <cmath>

#define NB 32
#define C1N 64
#define DIM 256
#define NHEAD 8
#define SEQL 784
#define NA 1605632      /* NB*SEQL*C1N */
#define SEQN 6422528    /* NB*SEQL*DIM */
#define KSEL 803u
#define QK2S (0.17677669529663687f * 1.4426950408889634f)  /* (1/sqrt(32)) * log2(e) */
#define THR2 11.541560f              /* 8 * log2(e) */
#define PECOEF (-0.03597789207803197f) /* -ln(10000)/256 */

#define AS1 __attribute__((address_space(1)))
#define AS3 __attribute__((address_space(3)))

typedef __attribute__((ext_vector_type(8))) short bf16x8;
typedef __attribute__((ext_vector_type(4))) float f32x4;

__device__ __forceinline__ unsigned short f2b(float f) {
  unsigned u = __float_as_uint(f);
  unsigned r = u + 0x7fffu + ((u >> 16) & 1u);
  return (unsigned short)(r >> 16);
}

__device__ __forceinline__ unsigned cvt_pk_bf16(float lo, float hi) {
  unsigned r;
  asm("v_cvt_pk_bf16_f32 %0, %1, %2" : "=v"(r) : "v"(lo), "v"(hi));
  return r;
}

// 256-wide suffix scan in LDS (256 participating threads)
__device__ __forceinline__ void scan256_suffix(unsigned* ss, int t) {
  #pragma unroll
  for (int off = 1; off < 256; off <<= 1) {
    unsigned v = (t + off < 256) ? ss[t + off] : 0u;
    __syncthreads();
    ss[t] += v;
    __syncthreads();
  }
}

// ---------------- zero hists/sel + cast in_proj weights (fused) ----------------
__global__ __launch_bounds__(256) void k_init(const float* __restrict__ ipw,
                                              unsigned short* __restrict__ wbuf,
                                              unsigned* __restrict__ z) {
  int i = blockIdx.x * 256 + threadIdx.x;
  if (i < 66080) z[i] = 0u;
  wbuf[i] = f2b(ipw[i]);   // grid covers exactly 196608
}

// ---- conv + relu + radix stage-A (top-byte) LDS-privatized histogram ----
__global__ __launch_bounds__(256) void k_conv(const float* __restrict__ x,
                                              const float* __restrict__ cw,
                                              float* __restrict__ vbuf,
                                              unsigned* __restrict__ hist8a) {
  __shared__ __align__(16) float ximg[1296];   // 36x36 zero-padded image
  __shared__ float wlds[5184];                 // [tap 0..80][channel 0..63]
  __shared__ unsigned lh[256];
  int tid = threadIdx.x;
  int b = blockIdx.x / 7, sblk = blockIdx.x % 7;
  lh[tid] = 0u;
  for (int e = tid; e < 1296; e += 256) ximg[e] = 0.f;
  for (int e = tid; e < 5184; e += 256) {
    int c = e / 81, t = e - c * 81;
    wlds[t * 64 + c] = cw[e];
  }
  __syncthreads();
  const float* xb = x + b * 784;
  for (int e = tid; e < 784; e += 256) {
    int row = e / 28, col = e - row * 28;
    ximg[(row + 4) * 36 + col + 4] = xb[e];
  }
  __syncthreads();
  int wv = tid >> 6, lane = tid & 63;
  for (int it = 0; it < 7; ++it) {
    int grp = sblk * 28 + it * 4 + wv;     // 0..195
    int hr = grp / 7, wc0 = (grp % 7) * 4;
    float a0 = 0.f, a1 = 0.f, a2 = 0.f, a3 = 0.f;
    #pragma unroll
    for (int dy = 0; dy < 9; ++dy) {
      const float4* xr4 = (const float4*)&ximg[(hr + dy) * 36 + wc0];
      float4 xa = xr4[0], xbq = xr4[1], xc = xr4[2];
      float xr[12] = {xa.x, xa.y, xa.z, xa.w, xbq.x, xbq.y, xbq.z, xbq.w,
                      xc.x, xc.y, xc.z, xc.w};
      #pragma unroll
      for (int dx = 0; dx < 9; ++dx) {
        float w = wlds[(dy * 9 + dx) * 64 + lane];
        a0 = fmaf(xr[dx + 0], w, a0);
        a1 = fmaf(xr[dx + 1], w, a1);
        a2 = fmaf(xr[dx + 2], w, a2);
        a3 = fmaf(xr[dx + 3], w, a3);
      }
    }
    a0 = fmaxf(a0, 0.f); a1 = fmaxf(a1, 0.f);
    a2 = fmaxf(a2, 0.f); a3 = fmaxf(a3, 0.f);
    size_t base = ((size_t)(b * 784 + hr * 28 + wc0)) * 64 + lane;
    vbuf[base +   0] = a0;
    vbuf[base +  64] = a1;
    vbuf[base + 128] = a2;
    vbuf[base + 192] = a3;
    if (a0 > 0.f) atomicAdd(&lh[__float_as_uint(a0) >> 24], 1u);
    if (a1 > 0.f) atomicAdd(&lh[__float_as_uint(a1) >> 24], 1u);
    if (a2 > 0.f) atomicAdd(&lh[__float_as_uint(a2) >> 24], 1u);
    if (a3 > 0.f) atomicAdd(&lh[__float_as_uint(a3) >> 24], 1u);
  }
  __syncthreads();
  if (lh[tid] > 0u) atomicAdd(&hist8a[tid], lh[tid]);
}

// ---- radix stage B: re-derive stage-A bucket per block, hist next byte ----
__global__ __launch_bounds__(256) void k_h8b(const float* __restrict__ vbuf,
                                             const unsigned* __restrict__ hist8a,
                                             unsigned* __restrict__ hist8b) {
  __shared__ unsigned ss[256];
  __shared__ unsigned lh[256];
  __shared__ unsigned bkey;
  int t = threadIdx.x;
  ss[t] = hist8a[t];
  lh[t] = 0u;
  __syncthreads();
  scan256_suffix(ss, t);
  if (ss[0] < KSEL) return;                 // uniform fallback: threshold 0
  unsigned S = ss[t], ab = (t < 255) ? ss[t + 1] : 0u;
  if (S >= KSEL && ab < KSEL) bkey = (unsigned)t;
  __syncthreads();
  unsigned key = bkey;
  const float4* v4 = (const float4*)vbuf;
  int n4 = NA / 4;
  for (int i = blockIdx.x * 256 + t; i < n4; i += gridDim.x * 256) {
    float4 v = v4[i];
    float vv[4] = {v.x, v.y, v.z, v.w};
    #pragma unroll
    for (int j = 0; j < 4; ++j) {
      if (vv[j] > 0.0f) {
        unsigned bits = __float_as_uint(vv[j]);
        if ((bits >> 24) == key) atomicAdd(&lh[(bits >> 16) & 0xFFu], 1u);
      }
    }
  }
  __syncthreads();
  if (lh[t] > 0u) atomicAdd(&hist8b[t], lh[t]);
}

// ---- radix stage C: re-derive A+B buckets per block, hist low 16 bits ----
__global__ __launch_bounds__(256) void k_h16(const float* __restrict__ vbuf,
                                             const unsigned* __restrict__ hist8a,
                                             const unsigned* __restrict__ hist8b,
                                             unsigned* __restrict__ hist16) {
  __shared__ unsigned ss[256];
  __shared__ unsigned bk0, bk1, brem;
  int t = threadIdx.x;
  ss[t] = hist8a[t];
  __syncthreads();
  scan256_suffix(ss, t);
  if (ss[0] < KSEL) return;
  unsigned S = ss[t], ab = (t < 255) ? ss[t + 1] : 0u;
  if (S >= KSEL && ab < KSEL) { bk0 = (unsigned)t; brem = KSEL - ab; }
  __syncthreads();
  unsigned key0 = bk0, rem1 = brem;
  __syncthreads();
  ss[t] = hist8b[t];
  __syncthreads();
  scan256_suffix(ss, t);
  S = ss[t]; ab = (t < 255) ? ss[t + 1] : 0u;
  if (S >= rem1 && ab < rem1) bk1 = (unsigned)t;
  __syncthreads();
  unsigned key16 = (key0 << 8) | bk1;
  const float4* v4 = (const float4*)vbuf;
  int n4 = NA / 4;
  for (int i = blockIdx.x * 256 + t; i < n4; i += gridDim.x * 256) {
    float4 v = v4[i];
    float vv[4] = {v.x, v.y, v.z, v.w};
    #pragma unroll
    for (int j = 0; j < 4; ++j) {
      if (vv[j] > 0.0f) {
        unsigned bits = __float_as_uint(vv[j]);
        if ((bits >> 16) == key16) atomicAdd(&hist16[bits & 0xFFFFu], 1u);
      }
    }
  }
}

// ---- radix final: re-derive A+B, scan 65536 bins, write threshold sel[3] ----
__global__ __launch_bounds__(1024) void k_scan16(const unsigned* __restrict__ hist8a,
                                                 const unsigned* __restrict__ hist8b,
                                                 const unsigned* __restrict__ hist16,
                                                 unsigned* __restrict__ sel) {
  __shared__ unsigned ss[1024];
  __shared__ unsigned bk0, bk1, brem, brem2;
  int t = threadIdx.x;
  if (t < 256) ss[t] = hist8a[t];
  __syncthreads();
  for (int off = 1; off < 256; off <<= 1) {
    unsigned v = 0u;
    if (t < 256) v = (t + off < 256) ? ss[t + off] : 0u;
    __syncthreads();
    if (t < 256) ss[t] += v;
    __syncthreads();
  }
  if (ss[0] < KSEL) { if (t == 0) sel[3] = 0u; return; }
  if (t < 256) {
    unsigned S = ss[t], ab = (t < 255) ? ss[t + 1] : 0u;
    if (S >= KSEL && ab < KSEL) { bk0 = (unsigned)t; brem = KSEL - ab; }
  }
  __syncthreads();
  unsigned key0 = bk0, rem1 = brem;
  if (t < 256) ss[t] = hist8b[t];
  __syncthreads();
  for (int off = 1; off < 256; off <<= 1) {
    unsigned v = 0u;
    if (t < 256) v = (t + off < 256) ? ss[t + off] : 0u;
    __syncthreads();
    if (t < 256) ss[t] += v;
    __syncthreads();
  }
  if (t < 256) {
    unsigned S = ss[t], ab = (t < 255) ? ss[t + 1] : 0u;
    if (S >= rem1 && ab < rem1) { bk1 = (unsigned)t; brem2 = rem1 - ab; }
  }
  __syncthreads();
  unsigned key16 = (key0 << 8) | bk1;
  unsigned rem2 = brem2;
  unsigned sum = 0;
  for (int i = 0; i < 64; ++i) sum += hist16[t * 64 + i];
  ss[t] = sum;
  __syncthreads();
  for (int off = 1; off < 1024; off <<= 1) {
    unsigned v = (t + off < 1024) ? ss[t + off] : 0u;
    __syncthreads();
    ss[t] += v;
    __syncthreads();
  }
  unsigned S = ss[t];
  unsigned above = (t < 1023) ? ss[t + 1] : 0u;
  if (S >= rem2 && above < rem2) {
    unsigned cum = above;
    for (int bb = t * 64 + 63; bb >= t * 64; --bb) {
      unsigned hb = hist16[bb];
      cum += hb;
      if (cum >= rem2) {
        sel[3] = (key16 << 16) | (unsigned)bb;
        break;
      }
    }
  }
}

// ---------------- top-2 select + sparse softmax + embed + pos-enc (seq in bf16) ----
__global__ __launch_bounds__(256) void k_select(const float* __restrict__ vbuf,
                                                const unsigned* __restrict__ sel,
                                                const float* __restrict__ ce,
                                                unsigned short* __restrict__ seqb,
                                                float* __restrict__ out_sw,
                                                float* __restrict__ out_idx) {
  int wid = threadIdx.x >> 6;
  int lane = threadIdx.x & 63;
  int pos = blockIdx.x * 4 + wid;
  int hw = pos % 784;
  int hr = hw / 28;
  int wc = hw % 28;
  float thr = __uint_as_float(sel[3]);
  float a = vbuf[(size_t)pos * 64 + lane];
  float val = (a >= thr) ? a : 0.0f;
  unsigned long long nzm = __ballot(val > 0.0f);
  int count = __popcll(nzm);
  float v1 = val; int i1 = lane;
  #pragma unroll
  for (int off = 32; off > 0; off >>= 1) {
    float ov = __shfl_xor(v1, off);
    int oi = __shfl_xor(i1, off);
    if (ov > v1 || (ov == v1 && oi < i1)) { v1 = ov; i1 = oi; }
  }
  float vx = (lane == i1) ? -INFINITY : val;
  float v2 = vx; int i2 = lane;
  #pragma unroll
  for (int off = 32; off > 0; off >>= 1) {
    float ov = __shfl_xor(v2, off);
    int oi = __shfl_xor(i2, off);
    if (ov > v2 || (ov == v2 && oi < i2)) { v2 = ov; i2 = oi; }
  }
  float w1 = 0.0f, w2 = 0.0f;
  if (count >= 2) {
    float e = __expf(v2 - v1);
    float invd = 1.0f / (1.0f + e);
    w1 = invd; w2 = e * invd;
  } else if (count == 1) {
    w1 = 1.0f;
  }
  float wt = (lane == i1) ? w1 : ((lane == i2) ? w2 : 0.0f);
  out_sw[(size_t)pos * 64 + lane] = wt;
  if (lane < 2) out_idx[pos * 2 + lane] = (float)(lane == 0 ? i1 : i2);
  int d0 = lane * 4;
  float4 c1v = *(const float4*)(ce + (size_t)i1 * 256 + d0);
  float4 c2v = *(const float4*)(ce + (size_t)i2 * 256 + d0);
  float dv0 = __expf((float)d0 * PECOEF);
  float dv2 = __expf((float)(d0 + 2) * PECOEF);
  float ox = w1 * c1v.x + w2 * c2v.x + __sinf((float)hr * dv0);
  float oy = w1 * c1v.y + w2 * c2v.y + __cosf((float)wc * dv0);
  float oz = w1 * c1v.z + w2 * c2v.z + __sinf((float)hr * dv2);
  float ow = w1 * c1v.w + w2 * c2v.w + __cosf((float)wc * dv2);
  ushort4 ob = make_ushort4(f2b(ox), f2b(oy), f2b(oz), f2b(ow));
  *(ushort4*)(seqb + (size_t)pos * 256 + d0) = ob;
}

// ---- LDS-staged MFMA bf16 GEMM: C = A[M][K] @ W[N][K]^T + bias. Q cols pre-scaled
// by QK2S. V-blocks (n0>=512) store DIRECTLY to Vt (transposed + k-permuted):
// position p = g*8 + hi*4 + r  <-  key kk = g*4 + hi*16 + r within each 32-block. ----
__global__ __launch_bounds__(256) void k_gemm_lds(const unsigned short* __restrict__ A,
                                                  const unsigned short* __restrict__ W,
                                                  const float* __restrict__ bias,
                                                  unsigned short* __restrict__ C,
                                                  unsigned short* __restrict__ Vt,
                                                  int M, int N, int K) {
  __shared__ __align__(16) unsigned short As[8192];   // [128][64]
  __shared__ __align__(16) unsigned short Bs[8192];
  int tid = threadIdx.x;
  int lane = tid & 63, wid = tid >> 6;
  int q = lane & 15, g = lane >> 4;
  int m0 = blockIdx.y * 128, n0 = blockIdx.x * 128;
  int lrow = lane >> 3, s = lane & 7;
  const unsigned short* aSrc = A + (size_t)(m0 + wid * 8 + lrow) * K + (s ^ lrow) * 8;
  const unsigned short* bSrc = W + (size_t)(n0 + wid * 8 + lrow) * K + (s ^ lrow) * 8;
  int dstW = wid * 512;
  int mloc = (wid >> 1) * 64, nloc = (wid & 1) * 64;
  int q7 = q & 7;
  f32x4 acc[4][4];
  #pragma unroll
  for (int i = 0; i < 4; ++i)
    #pragma unroll
    for (int j = 0; j < 4; ++j) acc[i][j] = (f32x4){0.f, 0.f, 0.f, 0.f};
  for (int k0 = 0; k0 < K; k0 += 64) {
    #pragma unroll
    for (int i = 0; i < 4; ++i) {
      __builtin_amdgcn_global_load_lds((const AS1 void*)(aSrc + (size_t)i * 32 * K + k0),
                                       (AS3 void*)(&As[i * 2048 + dstW]), 16, 0, 0);
      __builtin_amdgcn_global_load_lds((const AS1 void*)(bSrc + (size_t)i * 32 * K + k0),
                                       (AS3 void*)(&Bs[i * 2048 + dstW]), 16, 0, 0);
    }
    __syncthreads();
    #pragma unroll
    for (int kk = 0; kk < 2; ++kk) {
      bf16x8 af[4], bf[4];
      #pragma unroll
      for (int i = 0; i < 4; ++i)
        af[i] = *(const bf16x8*)&As[(mloc + i * 16 + q) * 64 + (((kk * 4 + g) ^ q7) * 8)];
      #pragma unroll
      for (int j = 0; j < 4; ++j)
        bf[j] = *(const bf16x8*)&Bs[(nloc + j * 16 + q) * 64 + (((kk * 4 + g) ^ q7) * 8)];
      __builtin_amdgcn_s_setprio(1);
      #pragma unroll
      for (int i = 0; i < 4; ++i)
        #pragma unroll
        for (int j = 0; j < 4; ++j)
          acc[i][j] = __builtin_amdgcn_mfma_f32_16x16x32_bf16(af[i], bf[j], acc[i][j], 0, 0, 0);
      __builtin_amdgcn_s_setprio(0);
    }
    __syncthreads();
  }
  if (n0 < 512) {   // Q/K blocks -> qkv layout
    #pragma unroll
    for (int j = 0; j < 4; ++j) {
      int col = n0 + nloc + j * 16 + q;
      float bj = bias[col];
      float qs = (col < 256) ? QK2S : 1.0f;
      #pragma unroll
      for (int i = 0; i < 4; ++i) {
        #pragma unroll
        for (int r = 0; r < 4; ++r) {
          int row = m0 + mloc + i * 16 + g * 4 + r;
          C[(size_t)row * N + col] = f2b((acc[i][j][r] + bj) * qs);
        }
      }
    }
  } else {          // V blocks -> transposed + permuted Vt[(b*8+nh)*32+d][800]
    #pragma unroll
    for (int j = 0; j < 4; ++j) {
      int colV = n0 + nloc + j * 16 + q;
      float bj = bias[colV];
      int dtot = colV - 512;
      size_t vrow = ((size_t)(dtot >> 5) * 32 + (dtot & 31)) * 800;  // + b*8*32*800
      #pragma unroll
      for (int i = 0; i < 4; ++i) {
        int rowbase = m0 + mloc + i * 16;        // 16-aligned; whole group same b
        int b = rowbase / 784;
        int t16 = rowbase - b * 784;             // multiple of 16
        int pos = ((t16 >> 5) << 5) + ((t16 >> 4) & 1) * 4 + g * 8;
        uint2 o;
        o.x = cvt_pk_bf16(acc[i][j][0] + bj, acc[i][j][1] + bj);
        o.y = cvt_pk_bf16(acc[i][j][2] + bj, acc[i][j][3] + bj);
        *(uint2*)(Vt + (size_t)b * 8 * 32 * 800 + vrow + pos) = o;
      }
    }
  }
}

// ---- MFMA flash attention: 4 waves/block share (b,head); 3-buffer LDS pipeline,
// stage 2 tiles ahead, raw s_barrier + counted s_waitcnt vmcnt(1) (T3/T4). ----
__global__ __launch_bounds__(256) void k_attn(const unsigned short* __restrict__ qkv,
                                              const unsigned short* __restrict__ Vt,
                                              unsigned short* __restrict__ ctx) {
  __shared__ __align__(16) unsigned short Kt[3][1024];   // [buf][32 keys x 32 dims]
  __shared__ __align__(16) unsigned short Vti[3][1024];  // [buf][32 dims x 32 kpos]
  int wid = threadIdx.x >> 6;
  int lane = threadIdx.x & 63;
  int blk = blockIdx.x;                       // 3328 = 8 XCDs * 416
  int wrk = (blk & 7) * 416 + (blk >> 3);
  int bh = wrk / 13;
  int qb = (wrk - bh * 13) * 4 + wid;         // 0..51
  int b = bh >> 3, nh = bh & 7;
  int q = lane & 15, g = lane >> 4;
  bool active = (qb < 49);
  const f32x4 zero4 = {0.f, 0.f, 0.f, 0.f};

  int qrow = b * 784 + (active ? qb * 16 + q : q);
  bf16x8 qf = *(const bf16x8*)(qkv + (size_t)qrow * 768 + nh * 32 + g * 8);
  asm volatile("s_waitcnt vmcnt(0)" ::: "memory");   // qf resident; vmcnt baseline 0

  const unsigned short* kbase = qkv + (size_t)b * 784 * 768 + 256 + nh * 32;
  const unsigned short* vbase = Vt + (size_t)bh * 32 * 800;

  int rit = ((wid & 1) << 4) + (lane >> 2);
  int sG = (lane & 3) ^ ((rit + (rit >> 2)) & 3);
  bool isK = (wid < 2);
  int ldsoff = ((wid & 1) << 4) * 32;
  const unsigned short* sp = isK ? (kbase + (size_t)rit * 768 + sG * 8)
                                 : (vbase + (size_t)rit * 800 + sG * 8);
  const int sstride = isK ? (32 * 768) : 32;
  unsigned short* ldsb = (isK ? &Kt[0][0] : &Vti[0][0]) + ldsoff;

  int slotr = ((g ^ ((q + (q >> 2)) & 3)) << 3);
  int rowA = q * 32 + slotr;
  int rowB = (16 + q) * 32 + slotr;

  f32x4 acc0 = zero4, acc1 = zero4;
  float m = -INFINITY, lp = 0.f;

#define STAGE(BUFO) {                                                          \
    __builtin_amdgcn_global_load_lds((const AS1 void*)sp,                      \
                                     (AS3 void*)(ldsb + (BUFO)), 16, 0, 0);    \
    sp += sstride; }

#define STEP(CUR, NXT) {                                                       \
    asm volatile("s_waitcnt vmcnt(1)" ::: "memory");                           \
    __builtin_amdgcn_s_barrier();                                              \
    asm volatile("" ::: "memory");                                             \
    STAGE(NXT);                                                                \
    bf16x8 kA = *(const bf16x8*)&Kt[0][(CUR) + rowA];                          \
    bf16x8 kB = *(const bf16x8*)&Kt[0][(CUR) + rowB];                          \
    bf16x8 va = *(const bf16x8*)&Vti[0][(CUR) + rowA];                         \
    bf16x8 vb = *(const bf16x8*)&Vti[0][(CUR) + rowB];                         \
    __builtin_amdgcn_s_setprio(1);                                             \
    f32x4 s0 = __builtin_amdgcn_mfma_f32_16x16x32_bf16(kA, qf, zero4, 0, 0, 0);\
    f32x4 s1 = __builtin_amdgcn_mfma_f32_16x16x32_bf16(kB, qf, zero4, 0, 0, 0);\
    __builtin_amdgcn_s_setprio(0);                                             \
    float pl = fmaxf(fmaxf(fmaxf(s0[0], s0[1]), fmaxf(s0[2], s0[3])),          \
                     fmaxf(fmaxf(s1[0], s1[1]), fmaxf(s1[2], s1[3])));         \
    if (!__all(pl <= m + THR2)) {                                              \
      float pm = fmaxf(pl, __shfl_xor(pl, 16));                                \
      pm = fmaxf(pm, __shfl_xor(pm, 32));                                      \
      float mnew = fmaxf(m, pm);                                               \
      float sc = __builtin_amdgcn_exp2f(m - mnew);                             \
      lp *= sc; acc0 *= sc; acc1 *= sc;                                        \
      m = mnew;                                                                \
    }                                                                          \
    float p0[4], p1[4];                                                        \
    _Pragma("unroll")                                                          \
    for (int r = 0; r < 4; ++r) {                                              \
      p0[r] = __builtin_amdgcn_exp2f(s0[r] - m);                               \
      p1[r] = __builtin_amdgcn_exp2f(s1[r] - m);                               \
    }                                                                          \
    lp += ((p0[0] + p0[1]) + (p0[2] + p0[3]))                                  \
        + ((p1[0] + p1[1]) + (p1[2] + p1[3]));                                 \
    union { unsigned u[4]; bf16x8 v; } pu;                                     \
    pu.u[0] = cvt_pk_bf16(p0[0], p0[1]);                                       \
    pu.u[1] = cvt_pk_bf16(p0[2], p0[3]);                                       \
    pu.u[2] = cvt_pk_bf16(p1[0], p1[1]);                                       \
    pu.u[3] = cvt_pk_bf16(p1[2], p1[3]);                                       \
    __builtin_amdgcn_s_setprio(1);                                             \
    acc0 = __builtin_amdgcn_mfma_f32_16x16x32_bf16(va, pu.v, acc0, 0, 0, 0);   \
    acc1 = __builtin_amdgcn_mfma_f32_16x16x32_bf16(vb, pu.v, acc1, 0, 0, 0);   \
    __builtin_amdgcn_s_setprio(0);                                             \
  }

  STAGE(0);     // tile 0 -> buf0
  STAGE(1024);  // tile 1 -> buf1

  for (int t = 0; t < 8; ++t) {
    STEP(0, 2048);
    STEP(1024, 0);
    STEP(2048, 1024);
  }
  { // tail: tile 24 (keys 768..799) in buf0; nonexistent-key V slots get P=0.
    asm volatile("s_waitcnt vmcnt(1)" ::: "memory");
    __builtin_amdgcn_s_barrier();
    asm volatile("" ::: "memory");
    bf16x8 kA = *(const bf16x8*)&Kt[0][rowA];
    bf16x8 va = *(const bf16x8*)&Vti[0][rowA];
    bf16x8 vb = *(const bf16x8*)&Vti[0][rowB];
    f32x4 s0 = __builtin_amdgcn_mfma_f32_16x16x32_bf16(kA, qf, zero4, 0, 0, 0);
    float pl = fmaxf(fmaxf(s0[0], s0[1]), fmaxf(s0[2], s0[3]));
    if (!__all(pl <= m + THR2)) {
      float pm = fmaxf(pl, __shfl_xor(pl, 16));
      pm = fmaxf(pm, __shfl_xor(pm, 32));
      float mnew = fmaxf(m, pm);
      float sc = __builtin_amdgcn_exp2f(m - mnew);
      lp *= sc; acc0 *= sc; acc1 *= sc;
      m = mnew;
    }
    float p0[4];
    #pragma unroll
    for (int r = 0; r < 4; ++r) p0[r] = __builtin_amdgcn_exp2f(s0[r] - m);
    lp += (p0[0] + p0[1]) + (p0[2] + p0[3]);
    union { unsigned u[4]; bf16x8 v; } pu;
    pu.u[0] = cvt_pk_bf16(p0[0], p0[1]);
    pu.u[1] = cvt_pk_bf16(p0[2], p0[3]);
    pu.u[2] = 0u;
    pu.u[3] = 0u;
    acc0 = __builtin_amdgcn_mfma_f32_16x16x32_bf16(va, pu.v, acc0, 0, 0, 0);
    acc1 = __builtin_amdgcn_mfma_f32_16x16x32_bf16(vb, pu.v, acc1, 0, 0, 0);
  }
#undef STEP
#undef STAGE
  float l = lp + __shfl_xor(lp, 16);
  l += __shfl_xor(l, 32);
  float linv = 1.f / l;
  if (active) {
    unsigned short* cp = ctx + (size_t)(b * 784 + qb * 16 + q) * 256 + nh * 32;
    ushort4 oA = make_ushort4(f2b(acc0[0] * linv), f2b(acc0[1] * linv),
                              f2b(acc0[2] * linv), f2b(acc0[3] * linv));
    ushort4 oB = make_ushort4(f2b(acc1[0] * linv), f2b(acc1[1] * linv),
                              f2b(acc1[2] * linv), f2b(acc1[3] * linv));
    *(ushort4*)(cp + g * 4) = oA;
    *(ushort4*)(cp + 16 + g * 4) = oB;
  }
}

// ---- mean-pool ctx (bf16 -> f32 partials): out-proj is deferred to a tiny GEMV ----
__global__ __launch_bounds__(256) void k_poolctx(const unsigned short* __restrict__ ctx,
                                                 float* __restrict__ part) {
  int b = blockIdx.x >> 3, sseg = blockIdx.x & 7;
  int d = threadIdx.x;
  const unsigned short* base = ctx + ((size_t)b * 784 + sseg * 98) * 256 + d;
  float acc = 0.f;
  for (int t = 0; t < 98; ++t)
    acc += __uint_as_float((unsigned)base[(size_t)t * 256] << 16);
  part[(size_t)blockIdx.x * 256 + d] = acc;
}

// ---- pooled[b] = mean_ctx[b] @ opw^T + opb  (f32, exact out-proj of the mean) ----
__global__ __launch_bounds__(256) void k_pgemv(const float* __restrict__ part,
                                               const float* __restrict__ opw,
                                               const float* __restrict__ opb,
                                               float* __restrict__ out) {
  __shared__ float mc[256];
  int b = blockIdx.x, d = threadIdx.x;
  float s = 0.f;
  #pragma unroll
  for (int i = 0; i < 8; ++i) s += part[(size_t)(b * 8 + i) * 256 + d];
  mc[d] = s * (1.0f / 784.0f);
  __syncthreads();
  float acc = opb[d];
  const float4* wr = (const float4*)(opw + (size_t)d * 256);
  #pragma unroll 8
  for (int j = 0; j < 64; ++j) {
    float4 w = wr[j];
    float4 m4 = *(const float4*)&mc[j * 4];
    acc += m4.x * w.x + m4.y * w.y + m4.z * w.z + m4.w * w.w;
  }
  out[b * 256 + d] = acc;
}

extern "C" void kernel_launch(void* const* d_in, const int* in_sizes, int n_in,
                              void* d_out, int out_size, void* d_ws, size_t ws_size,
                              hipStream_t stream) {
  (void)in_sizes; (void)n_in; (void)out_size; (void)ws_size;
  const float* x   = (const float*)d_in[0];
  const float* cw  = (const float*)d_in[1];
  const float* ce  = (const float*)d_in[2];
  const float* ipw = (const float*)d_in[3];
  const float* ipb = (const float*)d_in[4];
  const float* opw = (const float*)d_in[5];
  const float* opb = (const float*)d_in[6];

  float* out = (float*)d_out;
  float* pooled  = out;
  float* out_sw  = out + 8192;
  float* out_idx = out + 8192 + NA;

  float* ws = (float*)d_ws;
  float* vbuf = ws;                                   // NA f32
  unsigned* hist16 = (unsigned*)(ws + NA);            // 65536
  unsigned* hist8a = hist16 + 65536;                  // 256
  unsigned* hist8b = hist8a + 256;                    // 256
  unsigned* sel    = hist8b + 256;                    // 16
  unsigned short* seqb = (unsigned short*)(ws + NA + 66080);  // SEQN bf16 (later: ctx)
  unsigned short* qkvb = seqb + SEQN;                 // 3*SEQN bf16 (V region unused)
  unsigned short* Vt   = qkvb + 3 * (size_t)SEQN;     // 256*32*800 bf16
  unsigned short* wbuf = Vt + 256 * 32 * 800;         // 196608 bf16 (in_proj only)
  float* part = (float*)(wbuf + 262144);              // 65536 f32

  k_init<<<768, 256, 0, stream>>>(ipw, wbuf, hist16);
  k_conv<<<224, 256, 0, stream>>>(x, cw, vbuf, hist8a);
  k_h8b<<<1024, 256, 0, stream>>>(vbuf, hist8a, hist8b);
  k_h16<<<1024, 256, 0, stream>>>(vbuf, hist8a, hist8b, hist16);
  k_scan16<<<1, 1024, 0, stream>>>(hist8a, hist8b, hist16, sel);
  k_select<<<25088 / 4, 256, 0, stream>>>(vbuf, sel, ce, seqb, out_sw, out_idx);
  {
    dim3 gq(768 / 128, 25088 / 128);
    k_gemm_lds<<<gq, 256, 0, stream>>>(seqb, wbuf, ipb, qkvb, Vt, 25088, 768, 256);
  }
  k_attn<<<3328, 256, 0, stream>>>(qkvb, Vt, seqb /* ctx */);
  k_poolctx<<<256, 256, 0, stream>>>(seqb, part);
  k_pgemv<<<NB, 256, 0, stream>>>(part, opw, opb, pooled);
}

// Round 11
// 164.717 us; speedup vs baseline: 25.2944x; 1.0003x over previous
//
#include <hip/hip_runtime.h>
#include <cmath>

#define NB 32
#define C1N 64
#define DIM 256
#define NHEAD 8
#define SEQL 784
#define NA 1605632      /* NB*SEQL*C1N */
#define SEQN 6422528    /* NB*SEQL*DIM */
#define KSEL 803u
#define QK2S (0.17677669529663687f * 1.4426950408889634f)  /* (1/sqrt(32)) * log2(e) */
#define THR2 11.541560f              /* 8 * log2(e) */
#define PECOEF (-0.03597789207803197f) /* -ln(10000)/256 */

#define AS1 __attribute__((address_space(1)))
#define AS3 __attribute__((address_space(3)))

typedef __attribute__((ext_vector_type(8))) short bf16x8;
typedef __attribute__((ext_vector_type(4))) float f32x4;

__device__ __forceinline__ unsigned short f2b(float f) {
  unsigned u = __float_as_uint(f);
  unsigned r = u + 0x7fffu + ((u >> 16) & 1u);
  return (unsigned short)(r >> 16);
}

__device__ __forceinline__ unsigned cvt_pk_bf16(float lo, float hi) {
  unsigned r;
  asm("v_cvt_pk_bf16_f32 %0, %1, %2" : "=v"(r) : "v"(lo), "v"(hi));
  return r;
}

// 256-wide suffix scan in LDS (256 participating threads)
__device__ __forceinline__ void scan256_suffix(unsigned* ss, int t) {
  #pragma unroll
  for (int off = 1; off < 256; off <<= 1) {
    unsigned v = (t + off < 256) ? ss[t + off] : 0u;
    __syncthreads();
    ss[t] += v;
    __syncthreads();
  }
}

// ---------------- zero hists/sel + cast in_proj weights (fused) ----------------
__global__ __launch_bounds__(256) void k_init(const float* __restrict__ ipw,
                                              unsigned short* __restrict__ wbuf,
                                              unsigned* __restrict__ z) {
  int i = blockIdx.x * 256 + threadIdx.x;
  if (i < 66080) z[i] = 0u;
  wbuf[i] = f2b(ipw[i]);   // grid covers exactly 196608
}

// ---- conv + relu + radix stage-A (top-byte) LDS-privatized histogram ----
__global__ __launch_bounds__(256) void k_conv(const float* __restrict__ x,
                                              const float* __restrict__ cw,
                                              float* __restrict__ vbuf,
                                              unsigned* __restrict__ hist8a) {
  __shared__ __align__(16) float ximg[1296];   // 36x36 zero-padded image
  __shared__ float wlds[5184];                 // [tap 0..80][channel 0..63]
  __shared__ unsigned lh[256];
  int tid = threadIdx.x;
  int b = blockIdx.x / 7, sblk = blockIdx.x % 7;
  lh[tid] = 0u;
  for (int e = tid; e < 1296; e += 256) ximg[e] = 0.f;
  for (int e = tid; e < 5184; e += 256) {
    int c = e / 81, t = e - c * 81;
    wlds[t * 64 + c] = cw[e];
  }
  __syncthreads();
  const float* xb = x + b * 784;
  for (int e = tid; e < 784; e += 256) {
    int row = e / 28, col = e - row * 28;
    ximg[(row + 4) * 36 + col + 4] = xb[e];
  }
  __syncthreads();
  int wv = tid >> 6, lane = tid & 63;
  for (int it = 0; it < 7; ++it) {
    int grp = sblk * 28 + it * 4 + wv;     // 0..195
    int hr = grp / 7, wc0 = (grp % 7) * 4;
    float a0 = 0.f, a1 = 0.f, a2 = 0.f, a3 = 0.f;
    #pragma unroll
    for (int dy = 0; dy < 9; ++dy) {
      const float4* xr4 = (const float4*)&ximg[(hr + dy) * 36 + wc0];
      float4 xa = xr4[0], xbq = xr4[1], xc = xr4[2];
      float xr[12] = {xa.x, xa.y, xa.z, xa.w, xbq.x, xbq.y, xbq.z, xbq.w,
                      xc.x, xc.y, xc.z, xc.w};
      #pragma unroll
      for (int dx = 0; dx < 9; ++dx) {
        float w = wlds[(dy * 9 + dx) * 64 + lane];
        a0 = fmaf(xr[dx + 0], w, a0);
        a1 = fmaf(xr[dx + 1], w, a1);
        a2 = fmaf(xr[dx + 2], w, a2);
        a3 = fmaf(xr[dx + 3], w, a3);
      }
    }
    a0 = fmaxf(a0, 0.f); a1 = fmaxf(a1, 0.f);
    a2 = fmaxf(a2, 0.f); a3 = fmaxf(a3, 0.f);
    size_t base = ((size_t)(b * 784 + hr * 28 + wc0)) * 64 + lane;
    vbuf[base +   0] = a0;
    vbuf[base +  64] = a1;
    vbuf[base + 128] = a2;
    vbuf[base + 192] = a3;
    if (a0 > 0.f) atomicAdd(&lh[__float_as_uint(a0) >> 24], 1u);
    if (a1 > 0.f) atomicAdd(&lh[__float_as_uint(a1) >> 24], 1u);
    if (a2 > 0.f) atomicAdd(&lh[__float_as_uint(a2) >> 24], 1u);
    if (a3 > 0.f) atomicAdd(&lh[__float_as_uint(a3) >> 24], 1u);
  }
  __syncthreads();
  if (lh[tid] > 0u) atomicAdd(&hist8a[tid], lh[tid]);
}

// ---- radix stage B: re-derive stage-A bucket per block, hist next byte ----
__global__ __launch_bounds__(256) void k_h8b(const float* __restrict__ vbuf,
                                             const unsigned* __restrict__ hist8a,
                                             unsigned* __restrict__ hist8b) {
  __shared__ unsigned ss[256];
  __shared__ unsigned lh[256];
  __shared__ unsigned bkey;
  int t = threadIdx.x;
  ss[t] = hist8a[t];
  lh[t] = 0u;
  __syncthreads();
  scan256_suffix(ss, t);
  if (ss[0] < KSEL) return;                 // uniform fallback: threshold 0
  unsigned S = ss[t], ab = (t < 255) ? ss[t + 1] : 0u;
  if (S >= KSEL && ab < KSEL) bkey = (unsigned)t;
  __syncthreads();
  unsigned key = bkey;
  const float4* v4 = (const float4*)vbuf;
  int n4 = NA / 4;
  for (int i = blockIdx.x * 256 + t; i < n4; i += gridDim.x * 256) {
    float4 v = v4[i];
    float vv[4] = {v.x, v.y, v.z, v.w};
    #pragma unroll
    for (int j = 0; j < 4; ++j) {
      if (vv[j] > 0.0f) {
        unsigned bits = __float_as_uint(vv[j]);
        if ((bits >> 24) == key) atomicAdd(&lh[(bits >> 16) & 0xFFu], 1u);
      }
    }
  }
  __syncthreads();
  if (lh[t] > 0u) atomicAdd(&hist8b[t], lh[t]);
}

// ---- radix stage C: re-derive A+B buckets per block, hist low 16 bits ----
__global__ __launch_bounds__(256) void k_h16(const float* __restrict__ vbuf,
                                             const unsigned* __restrict__ hist8a,
                                             const unsigned* __restrict__ hist8b,
                                             unsigned* __restrict__ hist16) {
  __shared__ unsigned ss[256];
  __shared__ unsigned bk0, bk1, brem;
  int t = threadIdx.x;
  ss[t] = hist8a[t];
  __syncthreads();
  scan256_suffix(ss, t);
  if (ss[0] < KSEL) return;
  unsigned S = ss[t], ab = (t < 255) ? ss[t + 1] : 0u;
  if (S >= KSEL && ab < KSEL) { bk0 = (unsigned)t; brem = KSEL - ab; }
  __syncthreads();
  unsigned key0 = bk0, rem1 = brem;
  __syncthreads();
  ss[t] = hist8b[t];
  __syncthreads();
  scan256_suffix(ss, t);
  S = ss[t]; ab = (t < 255) ? ss[t + 1] : 0u;
  if (S >= rem1 && ab < rem1) bk1 = (unsigned)t;
  __syncthreads();
  unsigned key16 = (key0 << 8) | bk1;
  const float4* v4 = (const float4*)vbuf;
  int n4 = NA / 4;
  for (int i = blockIdx.x * 256 + t; i < n4; i += gridDim.x * 256) {
    float4 v = v4[i];
    float vv[4] = {v.x, v.y, v.z, v.w};
    #pragma unroll
    for (int j = 0; j < 4; ++j) {
      if (vv[j] > 0.0f) {
        unsigned bits = __float_as_uint(vv[j]);
        if ((bits >> 16) == key16) atomicAdd(&hist16[bits & 0xFFFFu], 1u);
      }
    }
  }
}

// ---- radix final: re-derive A+B, scan 65536 bins, write threshold sel[3] ----
__global__ __launch_bounds__(1024) void k_scan16(const unsigned* __restrict__ hist8a,
                                                 const unsigned* __restrict__ hist8b,
                                                 const unsigned* __restrict__ hist16,
                                                 unsigned* __restrict__ sel) {
  __shared__ unsigned ss[1024];
  __shared__ unsigned bk0, bk1, brem, brem2;
  int t = threadIdx.x;
  if (t < 256) ss[t] = hist8a[t];
  __syncthreads();
  for (int off = 1; off < 256; off <<= 1) {
    unsigned v = 0u;
    if (t < 256) v = (t + off < 256) ? ss[t + off] : 0u;
    __syncthreads();
    if (t < 256) ss[t] += v;
    __syncthreads();
  }
  if (ss[0] < KSEL) { if (t == 0) sel[3] = 0u; return; }
  if (t < 256) {
    unsigned S = ss[t], ab = (t < 255) ? ss[t + 1] : 0u;
    if (S >= KSEL && ab < KSEL) { bk0 = (unsigned)t; brem = KSEL - ab; }
  }
  __syncthreads();
  unsigned key0 = bk0, rem1 = brem;
  if (t < 256) ss[t] = hist8b[t];
  __syncthreads();
  for (int off = 1; off < 256; off <<= 1) {
    unsigned v = 0u;
    if (t < 256) v = (t + off < 256) ? ss[t + off] : 0u;
    __syncthreads();
    if (t < 256) ss[t] += v;
    __syncthreads();
  }
  if (t < 256) {
    unsigned S = ss[t], ab = (t < 255) ? ss[t + 1] : 0u;
    if (S >= rem1 && ab < rem1) { bk1 = (unsigned)t; brem2 = rem1 - ab; }
  }
  __syncthreads();
  unsigned key16 = (key0 << 8) | bk1;
  unsigned rem2 = brem2;
  unsigned sum = 0;
  for (int i = 0; i < 64; ++i) sum += hist16[t * 64 + i];
  ss[t] = sum;
  __syncthreads();
  for (int off = 1; off < 1024; off <<= 1) {
    unsigned v = (t + off < 1024) ? ss[t + off] : 0u;
    __syncthreads();
    ss[t] += v;
    __syncthreads();
  }
  unsigned S = ss[t];
  unsigned above = (t < 1023) ? ss[t + 1] : 0u;
  if (S >= rem2 && above < rem2) {
    unsigned cum = above;
    for (int bb = t * 64 + 63; bb >= t * 64; --bb) {
      unsigned hb = hist16[bb];
      cum += hb;
      if (cum >= rem2) {
        sel[3] = (key16 << 16) | (unsigned)bb;
        break;
      }
    }
  }
}

// ---------------- top-2 select + sparse softmax + embed + pos-enc (seq in bf16) ----
__global__ __launch_bounds__(256) void k_select(const float* __restrict__ vbuf,
                                                const unsigned* __restrict__ sel,
                                                const float* __restrict__ ce,
                                                unsigned short* __restrict__ seqb,
                                                float* __restrict__ out_sw,
                                                float* __restrict__ out_idx) {
  int wid = threadIdx.x >> 6;
  int lane = threadIdx.x & 63;
  int pos = blockIdx.x * 4 + wid;
  int hw = pos % 784;
  int hr = hw / 28;
  int wc = hw % 28;
  float thr = __uint_as_float(sel[3]);
  float a = vbuf[(size_t)pos * 64 + lane];
  float val = (a >= thr) ? a : 0.0f;
  unsigned long long nzm = __ballot(val > 0.0f);
  int count = __popcll(nzm);
  float v1 = val; int i1 = lane;
  #pragma unroll
  for (int off = 32; off > 0; off >>= 1) {
    float ov = __shfl_xor(v1, off);
    int oi = __shfl_xor(i1, off);
    if (ov > v1 || (ov == v1 && oi < i1)) { v1 = ov; i1 = oi; }
  }
  float vx = (lane == i1) ? -INFINITY : val;
  float v2 = vx; int i2 = lane;
  #pragma unroll
  for (int off = 32; off > 0; off >>= 1) {
    float ov = __shfl_xor(v2, off);
    int oi = __shfl_xor(i2, off);
    if (ov > v2 || (ov == v2 && oi < i2)) { v2 = ov; i2 = oi; }
  }
  float w1 = 0.0f, w2 = 0.0f;
  if (count >= 2) {
    float e = __expf(v2 - v1);
    float invd = 1.0f / (1.0f + e);
    w1 = invd; w2 = e * invd;
  } else if (count == 1) {
    w1 = 1.0f;
  }
  float wt = (lane == i1) ? w1 : ((lane == i2) ? w2 : 0.0f);
  out_sw[(size_t)pos * 64 + lane] = wt;
  if (lane < 2) out_idx[pos * 2 + lane] = (float)(lane == 0 ? i1 : i2);
  int d0 = lane * 4;
  float4 c1v = *(const float4*)(ce + (size_t)i1 * 256 + d0);
  float4 c2v = *(const float4*)(ce + (size_t)i2 * 256 + d0);
  float dv0 = __expf((float)d0 * PECOEF);
  float dv2 = __expf((float)(d0 + 2) * PECOEF);
  float ox = w1 * c1v.x + w2 * c2v.x + __sinf((float)hr * dv0);
  float oy = w1 * c1v.y + w2 * c2v.y + __cosf((float)wc * dv0);
  float oz = w1 * c1v.z + w2 * c2v.z + __sinf((float)hr * dv2);
  float ow = w1 * c1v.w + w2 * c2v.w + __cosf((float)wc * dv2);
  ushort4 ob = make_ushort4(f2b(ox), f2b(oy), f2b(oz), f2b(ow));
  *(ushort4*)(seqb + (size_t)pos * 256 + d0) = ob;
}

// ---- LDS-staged MFMA bf16 GEMM: C = A[M][K] @ W[N][K]^T + bias. Q cols pre-scaled
// by QK2S. V-blocks (n0>=512) store DIRECTLY to Vt (transposed + k-permuted). ----
__global__ __launch_bounds__(256) void k_gemm_lds(const unsigned short* __restrict__ A,
                                                  const unsigned short* __restrict__ W,
                                                  const float* __restrict__ bias,
                                                  unsigned short* __restrict__ C,
                                                  unsigned short* __restrict__ Vt,
                                                  int M, int N, int K) {
  __shared__ __align__(16) unsigned short As[8192];   // [128][64]
  __shared__ __align__(16) unsigned short Bs[8192];
  int tid = threadIdx.x;
  int lane = tid & 63, wid = tid >> 6;
  int q = lane & 15, g = lane >> 4;
  int m0 = blockIdx.y * 128, n0 = blockIdx.x * 128;
  int lrow = lane >> 3, s = lane & 7;
  const unsigned short* aSrc = A + (size_t)(m0 + wid * 8 + lrow) * K + (s ^ lrow) * 8;
  const unsigned short* bSrc = W + (size_t)(n0 + wid * 8 + lrow) * K + (s ^ lrow) * 8;
  int dstW = wid * 512;
  int mloc = (wid >> 1) * 64, nloc = (wid & 1) * 64;
  int q7 = q & 7;
  f32x4 acc[4][4];
  #pragma unroll
  for (int i = 0; i < 4; ++i)
    #pragma unroll
    for (int j = 0; j < 4; ++j) acc[i][j] = (f32x4){0.f, 0.f, 0.f, 0.f};
  for (int k0 = 0; k0 < K; k0 += 64) {
    #pragma unroll
    for (int i = 0; i < 4; ++i) {
      __builtin_amdgcn_global_load_lds((const AS1 void*)(aSrc + (size_t)i * 32 * K + k0),
                                       (AS3 void*)(&As[i * 2048 + dstW]), 16, 0, 0);
      __builtin_amdgcn_global_load_lds((const AS1 void*)(bSrc + (size_t)i * 32 * K + k0),
                                       (AS3 void*)(&Bs[i * 2048 + dstW]), 16, 0, 0);
    }
    __syncthreads();
    #pragma unroll
    for (int kk = 0; kk < 2; ++kk) {
      bf16x8 af[4], bf[4];
      #pragma unroll
      for (int i = 0; i < 4; ++i)
        af[i] = *(const bf16x8*)&As[(mloc + i * 16 + q) * 64 + (((kk * 4 + g) ^ q7) * 8)];
      #pragma unroll
      for (int j = 0; j < 4; ++j)
        bf[j] = *(const bf16x8*)&Bs[(nloc + j * 16 + q) * 64 + (((kk * 4 + g) ^ q7) * 8)];
      __builtin_amdgcn_s_setprio(1);
      #pragma unroll
      for (int i = 0; i < 4; ++i)
        #pragma unroll
        for (int j = 0; j < 4; ++j)
          acc[i][j] = __builtin_amdgcn_mfma_f32_16x16x32_bf16(af[i], bf[j], acc[i][j], 0, 0, 0);
      __builtin_amdgcn_s_setprio(0);
    }
    __syncthreads();
  }
  if (n0 < 512) {   // Q/K blocks -> qkv layout
    #pragma unroll
    for (int j = 0; j < 4; ++j) {
      int col = n0 + nloc + j * 16 + q;
      float bj = bias[col];
      float qs = (col < 256) ? QK2S : 1.0f;
      #pragma unroll
      for (int i = 0; i < 4; ++i) {
        #pragma unroll
        for (int r = 0; r < 4; ++r) {
          int row = m0 + mloc + i * 16 + g * 4 + r;
          C[(size_t)row * N + col] = f2b((acc[i][j][r] + bj) * qs);
        }
      }
    }
  } else {          // V blocks -> transposed + permuted Vt[(b*8+nh)*32+d][800]
    #pragma unroll
    for (int j = 0; j < 4; ++j) {
      int colV = n0 + nloc + j * 16 + q;
      float bj = bias[colV];
      int dtot = colV - 512;
      size_t vrow = ((size_t)(dtot >> 5) * 32 + (dtot & 31)) * 800;  // + b*8*32*800
      #pragma unroll
      for (int i = 0; i < 4; ++i) {
        int rowbase = m0 + mloc + i * 16;        // 16-aligned; whole group same b
        int b = rowbase / 784;
        int t16 = rowbase - b * 784;             // multiple of 16
        int pos = ((t16 >> 5) << 5) + ((t16 >> 4) & 1) * 4 + g * 8;
        uint2 o;
        o.x = cvt_pk_bf16(acc[i][j][0] + bj, acc[i][j][1] + bj);
        o.y = cvt_pk_bf16(acc[i][j][2] + bj, acc[i][j][3] + bj);
        *(uint2*)(Vt + (size_t)b * 8 * 32 * 800 + vrow + pos) = o;
      }
    }
  }
}

// ---- MFMA flash attention: 4 waves/block share (b,head); 3-buffer LDS pipeline,
// counted vmcnt(1). NEW: l computed on matrix pipe via all-ones A-fragment MFMA
// (accS = ones x P + accS -> every lane of column q holds l[q]); no lsum VALU tree,
// no final cross-lane reduce. ----
__global__ __launch_bounds__(256) void k_attn(const unsigned short* __restrict__ qkv,
                                              const unsigned short* __restrict__ Vt,
                                              unsigned short* __restrict__ ctx) {
  __shared__ __align__(16) unsigned short Kt[3][1024];   // [buf][32 keys x 32 dims]
  __shared__ __align__(16) unsigned short Vti[3][1024];  // [buf][32 dims x 32 kpos]
  int wid = threadIdx.x >> 6;
  int lane = threadIdx.x & 63;
  int blk = blockIdx.x;                       // 3328 = 8 XCDs * 416
  int wrk = (blk & 7) * 416 + (blk >> 3);
  int bh = wrk / 13;
  int qb = (wrk - bh * 13) * 4 + wid;         // 0..51
  int b = bh >> 3, nh = bh & 7;
  int q = lane & 15, g = lane >> 4;
  bool active = (qb < 49);
  const f32x4 zero4 = {0.f, 0.f, 0.f, 0.f};
  const short one_bf = (short)0x3F80;         // bf16 1.0
  const bf16x8 ones8 = {one_bf, one_bf, one_bf, one_bf,
                        one_bf, one_bf, one_bf, one_bf};

  int qrow = b * 784 + (active ? qb * 16 + q : q);
  bf16x8 qf = *(const bf16x8*)(qkv + (size_t)qrow * 768 + nh * 32 + g * 8);
  asm volatile("s_waitcnt vmcnt(0)" ::: "memory");   // qf resident; vmcnt baseline 0

  const unsigned short* kbase = qkv + (size_t)b * 784 * 768 + 256 + nh * 32;
  const unsigned short* vbase = Vt + (size_t)bh * 32 * 800;

  int rit = ((wid & 1) << 4) + (lane >> 2);
  int sG = (lane & 3) ^ ((rit + (rit >> 2)) & 3);
  bool isK = (wid < 2);
  int ldsoff = ((wid & 1) << 4) * 32;
  const unsigned short* sp = isK ? (kbase + (size_t)rit * 768 + sG * 8)
                                 : (vbase + (size_t)rit * 800 + sG * 8);
  const int sstride = isK ? (32 * 768) : 32;
  unsigned short* ldsb = (isK ? &Kt[0][0] : &Vti[0][0]) + ldsoff;

  int slotr = ((g ^ ((q + (q >> 2)) & 3)) << 3);
  int rowA = q * 32 + slotr;
  int rowB = (16 + q) * 32 + slotr;

  f32x4 acc0 = zero4, acc1 = zero4, accS = zero4;
  float m = -INFINITY;

#define STAGE(BUFO) {                                                          \
    __builtin_amdgcn_global_load_lds((const AS1 void*)sp,                      \
                                     (AS3 void*)(ldsb + (BUFO)), 16, 0, 0);    \
    sp += sstride; }

#define STEP(CUR, NXT) {                                                       \
    asm volatile("s_waitcnt vmcnt(1)" ::: "memory");                           \
    __builtin_amdgcn_s_barrier();                                              \
    asm volatile("" ::: "memory");                                             \
    STAGE(NXT);                                                                \
    bf16x8 kA = *(const bf16x8*)&Kt[0][(CUR) + rowA];                          \
    bf16x8 kB = *(const bf16x8*)&Kt[0][(CUR) + rowB];                          \
    bf16x8 va = *(const bf16x8*)&Vti[0][(CUR) + rowA];                         \
    bf16x8 vb = *(const bf16x8*)&Vti[0][(CUR) + rowB];                         \
    __builtin_amdgcn_s_setprio(1);                                             \
    f32x4 s0 = __builtin_amdgcn_mfma_f32_16x16x32_bf16(kA, qf, zero4, 0, 0, 0);\
    f32x4 s1 = __builtin_amdgcn_mfma_f32_16x16x32_bf16(kB, qf, zero4, 0, 0, 0);\
    __builtin_amdgcn_s_setprio(0);                                             \
    float t1 = fmaxf(fmaxf(s0[0], s0[1]), s0[2]);                              \
    float t2 = fmaxf(fmaxf(s0[3], s1[0]), s1[1]);                              \
    float t3 = fmaxf(fmaxf(s1[2], s1[3]), t1);                                 \
    float pl = fmaxf(t2, t3);                                                  \
    if (!__all(pl <= m + THR2)) {                                              \
      float pm = fmaxf(pl, __shfl_xor(pl, 16));                                \
      pm = fmaxf(pm, __shfl_xor(pm, 32));                                      \
      float mnew = fmaxf(m, pm);                                               \
      float sc = __builtin_amdgcn_exp2f(m - mnew);                             \
      acc0 *= sc; acc1 *= sc; accS *= sc;                                      \
      m = mnew;                                                                \
    }                                                                          \
    float p0[4], p1[4];                                                        \
    _Pragma("unroll")                                                          \
    for (int r = 0; r < 4; ++r) {                                              \
      p0[r] = __builtin_amdgcn_exp2f(s0[r] - m);                               \
      p1[r] = __builtin_amdgcn_exp2f(s1[r] - m);                               \
    }                                                                          \
    union { unsigned u[4]; bf16x8 v; } pu;                                     \
    pu.u[0] = cvt_pk_bf16(p0[0], p0[1]);                                       \
    pu.u[1] = cvt_pk_bf16(p0[2], p0[3]);                                       \
    pu.u[2] = cvt_pk_bf16(p1[0], p1[1]);                                       \
    pu.u[3] = cvt_pk_bf16(p1[2], p1[3]);                                       \
    __builtin_amdgcn_s_setprio(1);                                             \
    acc0 = __builtin_amdgcn_mfma_f32_16x16x32_bf16(va, pu.v, acc0, 0, 0, 0);   \
    acc1 = __builtin_amdgcn_mfma_f32_16x16x32_bf16(vb, pu.v, acc1, 0, 0, 0);   \
    accS = __builtin_amdgcn_mfma_f32_16x16x32_bf16(ones8, pu.v, accS, 0, 0, 0);\
    __builtin_amdgcn_s_setprio(0);                                             \
  }

  STAGE(0);     // tile 0 -> buf0
  STAGE(1024);  // tile 1 -> buf1

  for (int t = 0; t < 8; ++t) {
    STEP(0, 2048);
    STEP(1024, 0);
    STEP(2048, 1024);
  }
  { // tail: tile 24 (keys 768..799) in buf0; nonexistent-key P slots are 0.
    asm volatile("s_waitcnt vmcnt(1)" ::: "memory");
    __builtin_amdgcn_s_barrier();
    asm volatile("" ::: "memory");
    bf16x8 kA = *(const bf16x8*)&Kt[0][rowA];
    bf16x8 va = *(const bf16x8*)&Vti[0][rowA];
    bf16x8 vb = *(const bf16x8*)&Vti[0][rowB];
    f32x4 s0 = __builtin_amdgcn_mfma_f32_16x16x32_bf16(kA, qf, zero4, 0, 0, 0);
    float pl = fmaxf(fmaxf(fmaxf(s0[0], s0[1]), s0[2]), s0[3]);
    if (!__all(pl <= m + THR2)) {
      float pm = fmaxf(pl, __shfl_xor(pl, 16));
      pm = fmaxf(pm, __shfl_xor(pm, 32));
      float mnew = fmaxf(m, pm);
      float sc = __builtin_amdgcn_exp2f(m - mnew);
      acc0 *= sc; acc1 *= sc; accS *= sc;
      m = mnew;
    }
    float p0[4];
    #pragma unroll
    for (int r = 0; r < 4; ++r) p0[r] = __builtin_amdgcn_exp2f(s0[r] - m);
    union { unsigned u[4]; bf16x8 v; } pu;
    pu.u[0] = cvt_pk_bf16(p0[0], p0[1]);
    pu.u[1] = cvt_pk_bf16(p0[2], p0[3]);
    pu.u[2] = 0u;
    pu.u[3] = 0u;
    acc0 = __builtin_amdgcn_mfma_f32_16x16x32_bf16(va, pu.v, acc0, 0, 0, 0);
    acc1 = __builtin_amdgcn_mfma_f32_16x16x32_bf16(vb, pu.v, acc1, 0, 0, 0);
    accS = __builtin_amdgcn_mfma_f32_16x16x32_bf16(ones8, pu.v, accS, 0, 0, 0);
  }
#undef STEP
#undef STAGE
  float linv = 1.f / accS[0];
  if (active) {
    unsigned short* cp = ctx + (size_t)(b * 784 + qb * 16 + q) * 256 + nh * 32;
    ushort4 oA = make_ushort4(f2b(acc0[0] * linv), f2b(acc0[1] * linv),
                              f2b(acc0[2] * linv), f2b(acc0[3] * linv));
    ushort4 oB = make_ushort4(f2b(acc1[0] * linv), f2b(acc1[1] * linv),
                              f2b(acc1[2] * linv), f2b(acc1[3] * linv));
    *(ushort4*)(cp + g * 4) = oA;
    *(ushort4*)(cp + 16 + g * 4) = oB;
  }
}

// ---- fused: mean-pool ctx (bf16) + out-proj GEMV (f32). One block per batch b. ----
__global__ __launch_bounds__(1024) void k_poolgemv(const unsigned short* __restrict__ ctx,
                                                   const float* __restrict__ opw,
                                                   const float* __restrict__ opb,
                                                   float* __restrict__ out) {
  __shared__ float red[4][256];
  __shared__ float mc[256];
  int b = blockIdx.x;
  int d = threadIdx.x & 255;
  int seg = threadIdx.x >> 8;   // 0..3
  const unsigned short* base = ctx + ((size_t)b * 784 + seg * 196) * 256 + d;
  float acc = 0.f;
  for (int t = 0; t < 196; ++t)
    acc += __uint_as_float((unsigned)base[(size_t)t * 256] << 16);
  red[seg][d] = acc;
  __syncthreads();
  if (seg == 0)
    mc[d] = (red[0][d] + red[1][d] + red[2][d] + red[3][d]) * (1.0f / 784.0f);
  __syncthreads();
  float ap = 0.f;
  const float4* wr = (const float4*)(opw + (size_t)d * 256 + seg * 64);
  #pragma unroll 4
  for (int j = 0; j < 16; ++j) {
    float4 w = wr[j];
    float4 m4 = *(const float4*)&mc[seg * 64 + j * 4];
    ap += m4.x * w.x + m4.y * w.y + m4.z * w.z + m4.w * w.w;
  }
  red[seg][d] = ap;
  __syncthreads();
  if (seg == 0)
    out[b * 256 + d] = red[0][d] + red[1][d] + red[2][d] + red[3][d] + opb[d];
}

extern "C" void kernel_launch(void* const* d_in, const int* in_sizes, int n_in,
                              void* d_out, int out_size, void* d_ws, size_t ws_size,
                              hipStream_t stream) {
  (void)in_sizes; (void)n_in; (void)out_size; (void)ws_size;
  const float* x   = (const float*)d_in[0];
  const float* cw  = (const float*)d_in[1];
  const float* ce  = (const float*)d_in[2];
  const float* ipw = (const float*)d_in[3];
  const float* ipb = (const float*)d_in[4];
  const float* opw = (const float*)d_in[5];
  const float* opb = (const float*)d_in[6];

  float* out = (float*)d_out;
  float* pooled  = out;
  float* out_sw  = out + 8192;
  float* out_idx = out + 8192 + NA;

  float* ws = (float*)d_ws;
  float* vbuf = ws;                                   // NA f32
  unsigned* hist16 = (unsigned*)(ws + NA);            // 65536
  unsigned* hist8a = hist16 + 65536;                  // 256
  unsigned* hist8b = hist8a + 256;                    // 256
  unsigned* sel    = hist8b + 256;                    // 16
  unsigned short* seqb = (unsigned short*)(ws + NA + 66080);  // SEQN bf16 (later: ctx)
  unsigned short* qkvb = seqb + SEQN;                 // 3*SEQN bf16 (V region unused)
  unsigned short* Vt   = qkvb + 3 * (size_t)SEQN;     // 256*32*800 bf16
  unsigned short* wbuf = Vt + 256 * 32 * 800;         // 196608 bf16 (in_proj only)

  k_init<<<768, 256, 0, stream>>>(ipw, wbuf, hist16);
  k_conv<<<224, 256, 0, stream>>>(x, cw, vbuf, hist8a);
  k_h8b<<<1024, 256, 0, stream>>>(vbuf, hist8a, hist8b);
  k_h16<<<1024, 256, 0, stream>>>(vbuf, hist8a, hist8b, hist16);
  k_scan16<<<1, 1024, 0, stream>>>(hist8a, hist8b, hist16, sel);
  k_select<<<25088 / 4, 256, 0, stream>>>(vbuf, sel, ce, seqb, out_sw, out_idx);
  {
    dim3 gq(768 / 128, 25088 / 128);
    k_gemm_lds<<<gq, 256, 0, stream>>>(seqb, wbuf, ipb, qkvb, Vt, 25088, 768, 256);
  }
  k_attn<<<3328, 256, 0, stream>>>(qkvb, Vt, seqb /* ctx */);
  k_poolgemv<<<NB, 1024, 0, stream>>>(seqb, opw, opb, pooled);
}

// Round 12
// 157.409 us; speedup vs baseline: 26.4687x; 1.0464x over previous
//
#include <hip/hip_runtime.h>
#include <cmath>

#define NB 32
#define C1N 64
#define DIM 256
#define NHEAD 8
#define SEQL 784
#define NA 1605632      /* NB*SEQL*C1N */
#define SEQN 6422528    /* NB*SEQL*DIM */
#define KSEL 803u
#define QK2S (0.17677669529663687f * 1.4426950408889634f)  /* (1/sqrt(32)) * log2(e) */
#define PECOEF (-0.03597789207803197f) /* -ln(10000)/256 */

#define AS1 __attribute__((address_space(1)))
#define AS3 __attribute__((address_space(3)))

typedef __attribute__((ext_vector_type(8))) short bf16x8;
typedef __attribute__((ext_vector_type(4))) float f32x4;

__device__ __forceinline__ unsigned short f2b(float f) {
  unsigned u = __float_as_uint(f);
  unsigned r = u + 0x7fffu + ((u >> 16) & 1u);
  return (unsigned short)(r >> 16);
}

__device__ __forceinline__ unsigned cvt_pk_bf16(float lo, float hi) {
  unsigned r;
  asm("v_cvt_pk_bf16_f32 %0, %1, %2" : "=v"(r) : "v"(lo), "v"(hi));
  return r;
}

// 256-wide suffix scan in LDS (256 participating threads)
__device__ __forceinline__ void scan256_suffix(unsigned* ss, int t) {
  #pragma unroll
  for (int off = 1; off < 256; off <<= 1) {
    unsigned v = (t + off < 256) ? ss[t + off] : 0u;
    __syncthreads();
    ss[t] += v;
    __syncthreads();
  }
}

// ---------------- zero hists/sel + cast in_proj weights (fused) ----------------
__global__ __launch_bounds__(256) void k_init(const float* __restrict__ ipw,
                                              unsigned short* __restrict__ wbuf,
                                              unsigned* __restrict__ z) {
  int i = blockIdx.x * 256 + threadIdx.x;
  if (i < 66080) z[i] = 0u;
  wbuf[i] = f2b(ipw[i]);   // grid covers exactly 196608
}

// ---- conv + relu + radix stage-A (top-byte) LDS-privatized histogram ----
__global__ __launch_bounds__(256) void k_conv(const float* __restrict__ x,
                                              const float* __restrict__ cw,
                                              float* __restrict__ vbuf,
                                              unsigned* __restrict__ hist8a) {
  __shared__ __align__(16) float ximg[1296];   // 36x36 zero-padded image
  __shared__ float wlds[5184];                 // [tap 0..80][channel 0..63]
  __shared__ unsigned lh[256];
  int tid = threadIdx.x;
  int b = blockIdx.x / 7, sblk = blockIdx.x % 7;
  lh[tid] = 0u;
  for (int e = tid; e < 1296; e += 256) ximg[e] = 0.f;
  for (int e = tid; e < 5184; e += 256) {
    int c = e / 81, t = e - c * 81;
    wlds[t * 64 + c] = cw[e];
  }
  __syncthreads();
  const float* xb = x + b * 784;
  for (int e = tid; e < 784; e += 256) {
    int row = e / 28, col = e - row * 28;
    ximg[(row + 4) * 36 + col + 4] = xb[e];
  }
  __syncthreads();
  int wv = tid >> 6, lane = tid & 63;
  for (int it = 0; it < 7; ++it) {
    int grp = sblk * 28 + it * 4 + wv;     // 0..195
    int hr = grp / 7, wc0 = (grp % 7) * 4;
    float a0 = 0.f, a1 = 0.f, a2 = 0.f, a3 = 0.f;
    #pragma unroll
    for (int dy = 0; dy < 9; ++dy) {
      const float4* xr4 = (const float4*)&ximg[(hr + dy) * 36 + wc0];
      float4 xa = xr4[0], xbq = xr4[1], xc = xr4[2];
      float xr[12] = {xa.x, xa.y, xa.z, xa.w, xbq.x, xbq.y, xbq.z, xbq.w,
                      xc.x, xc.y, xc.z, xc.w};
      #pragma unroll
      for (int dx = 0; dx < 9; ++dx) {
        float w = wlds[(dy * 9 + dx) * 64 + lane];
        a0 = fmaf(xr[dx + 0], w, a0);
        a1 = fmaf(xr[dx + 1], w, a1);
        a2 = fmaf(xr[dx + 2], w, a2);
        a3 = fmaf(xr[dx + 3], w, a3);
      }
    }
    a0 = fmaxf(a0, 0.f); a1 = fmaxf(a1, 0.f);
    a2 = fmaxf(a2, 0.f); a3 = fmaxf(a3, 0.f);
    size_t base = ((size_t)(b * 784 + hr * 28 + wc0)) * 64 + lane;
    vbuf[base +   0] = a0;
    vbuf[base +  64] = a1;
    vbuf[base + 128] = a2;
    vbuf[base + 192] = a3;
    if (a0 > 0.f) atomicAdd(&lh[__float_as_uint(a0) >> 24], 1u);
    if (a1 > 0.f) atomicAdd(&lh[__float_as_uint(a1) >> 24], 1u);
    if (a2 > 0.f) atomicAdd(&lh[__float_as_uint(a2) >> 24], 1u);
    if (a3 > 0.f) atomicAdd(&lh[__float_as_uint(a3) >> 24], 1u);
  }
  __syncthreads();
  if (lh[tid] > 0u) atomicAdd(&hist8a[tid], lh[tid]);
}

// ---- radix stage B: re-derive stage-A bucket per block, hist next byte ----
__global__ __launch_bounds__(256) void k_h8b(const float* __restrict__ vbuf,
                                             const unsigned* __restrict__ hist8a,
                                             unsigned* __restrict__ hist8b) {
  __shared__ unsigned ss[256];
  __shared__ unsigned lh[256];
  __shared__ unsigned bkey;
  int t = threadIdx.x;
  ss[t] = hist8a[t];
  lh[t] = 0u;
  __syncthreads();
  scan256_suffix(ss, t);
  if (ss[0] < KSEL) return;                 // uniform fallback: threshold 0
  unsigned S = ss[t], ab = (t < 255) ? ss[t + 1] : 0u;
  if (S >= KSEL && ab < KSEL) bkey = (unsigned)t;
  __syncthreads();
  unsigned key = bkey;
  const float4* v4 = (const float4*)vbuf;
  int n4 = NA / 4;
  for (int i = blockIdx.x * 256 + t; i < n4; i += gridDim.x * 256) {
    float4 v = v4[i];
    float vv[4] = {v.x, v.y, v.z, v.w};
    #pragma unroll
    for (int j = 0; j < 4; ++j) {
      if (vv[j] > 0.0f) {
        unsigned bits = __float_as_uint(vv[j]);
        if ((bits >> 24) == key) atomicAdd(&lh[(bits >> 16) & 0xFFu], 1u);
      }
    }
  }
  __syncthreads();
  if (lh[t] > 0u) atomicAdd(&hist8b[t], lh[t]);
}

// ---- radix stage C: re-derive A+B buckets per block, hist low 16 bits ----
__global__ __launch_bounds__(256) void k_h16(const float* __restrict__ vbuf,
                                             const unsigned* __restrict__ hist8a,
                                             const unsigned* __restrict__ hist8b,
                                             unsigned* __restrict__ hist16) {
  __shared__ unsigned ss[256];
  __shared__ unsigned bk0, bk1, brem;
  int t = threadIdx.x;
  ss[t] = hist8a[t];
  __syncthreads();
  scan256_suffix(ss, t);
  if (ss[0] < KSEL) return;
  unsigned S = ss[t], ab = (t < 255) ? ss[t + 1] : 0u;
  if (S >= KSEL && ab < KSEL) { bk0 = (unsigned)t; brem = KSEL - ab; }
  __syncthreads();
  unsigned key0 = bk0, rem1 = brem;
  __syncthreads();
  ss[t] = hist8b[t];
  __syncthreads();
  scan256_suffix(ss, t);
  S = ss[t]; ab = (t < 255) ? ss[t + 1] : 0u;
  if (S >= rem1 && ab < rem1) bk1 = (unsigned)t;
  __syncthreads();
  unsigned key16 = (key0 << 8) | bk1;
  const float4* v4 = (const float4*)vbuf;
  int n4 = NA / 4;
  for (int i = blockIdx.x * 256 + t; i < n4; i += gridDim.x * 256) {
    float4 v = v4[i];
    float vv[4] = {v.x, v.y, v.z, v.w};
    #pragma unroll
    for (int j = 0; j < 4; ++j) {
      if (vv[j] > 0.0f) {
        unsigned bits = __float_as_uint(vv[j]);
        if ((bits >> 16) == key16) atomicAdd(&hist16[bits & 0xFFFFu], 1u);
      }
    }
  }
}

// ---- radix final: re-derive A+B, scan 65536 bins, write threshold sel[3] ----
__global__ __launch_bounds__(1024) void k_scan16(const unsigned* __restrict__ hist8a,
                                                 const unsigned* __restrict__ hist8b,
                                                 const unsigned* __restrict__ hist16,
                                                 unsigned* __restrict__ sel) {
  __shared__ unsigned ss[1024];
  __shared__ unsigned bk0, bk1, brem, brem2;
  int t = threadIdx.x;
  if (t < 256) ss[t] = hist8a[t];
  __syncthreads();
  for (int off = 1; off < 256; off <<= 1) {
    unsigned v = 0u;
    if (t < 256) v = (t + off < 256) ? ss[t + off] : 0u;
    __syncthreads();
    if (t < 256) ss[t] += v;
    __syncthreads();
  }
  if (ss[0] < KSEL) { if (t == 0) sel[3] = 0u; return; }
  if (t < 256) {
    unsigned S = ss[t], ab = (t < 255) ? ss[t + 1] : 0u;
    if (S >= KSEL && ab < KSEL) { bk0 = (unsigned)t; brem = KSEL - ab; }
  }
  __syncthreads();
  unsigned key0 = bk0, rem1 = brem;
  if (t < 256) ss[t] = hist8b[t];
  __syncthreads();
  for (int off = 1; off < 256; off <<= 1) {
    unsigned v = 0u;
    if (t < 256) v = (t + off < 256) ? ss[t + off] : 0u;
    __syncthreads();
    if (t < 256) ss[t] += v;
    __syncthreads();
  }
  if (t < 256) {
    unsigned S = ss[t], ab = (t < 255) ? ss[t + 1] : 0u;
    if (S >= rem1 && ab < rem1) { bk1 = (unsigned)t; brem2 = rem1 - ab; }
  }
  __syncthreads();
  unsigned key16 = (key0 << 8) | bk1;
  unsigned rem2 = brem2;
  unsigned sum = 0;
  for (int i = 0; i < 64; ++i) sum += hist16[t * 64 + i];
  ss[t] = sum;
  __syncthreads();
  for (int off = 1; off < 1024; off <<= 1) {
    unsigned v = (t + off < 1024) ? ss[t + off] : 0u;
    __syncthreads();
    ss[t] += v;
    __syncthreads();
  }
  unsigned S = ss[t];
  unsigned above = (t < 1023) ? ss[t + 1] : 0u;
  if (S >= rem2 && above < rem2) {
    unsigned cum = above;
    for (int bb = t * 64 + 63; bb >= t * 64; --bb) {
      unsigned hb = hist16[bb];
      cum += hb;
      if (cum >= rem2) {
        sel[3] = (key16 << 16) | (unsigned)bb;
        break;
      }
    }
  }
}

// ---------------- top-2 select + sparse softmax + embed + pos-enc (seq in bf16) ----
__global__ __launch_bounds__(256) void k_select(const float* __restrict__ vbuf,
                                                const unsigned* __restrict__ sel,
                                                const float* __restrict__ ce,
                                                unsigned short* __restrict__ seqb,
                                                float* __restrict__ out_sw,
                                                float* __restrict__ out_idx) {
  int wid = threadIdx.x >> 6;
  int lane = threadIdx.x & 63;
  int pos = blockIdx.x * 4 + wid;
  int hw = pos % 784;
  int hr = hw / 28;
  int wc = hw % 28;
  float thr = __uint_as_float(sel[3]);
  float a = vbuf[(size_t)pos * 64 + lane];
  float val = (a >= thr) ? a : 0.0f;
  unsigned long long nzm = __ballot(val > 0.0f);
  int count = __popcll(nzm);
  float v1 = val; int i1 = lane;
  #pragma unroll
  for (int off = 32; off > 0; off >>= 1) {
    float ov = __shfl_xor(v1, off);
    int oi = __shfl_xor(i1, off);
    if (ov > v1 || (ov == v1 && oi < i1)) { v1 = ov; i1 = oi; }
  }
  float vx = (lane == i1) ? -INFINITY : val;
  float v2 = vx; int i2 = lane;
  #pragma unroll
  for (int off = 32; off > 0; off >>= 1) {
    float ov = __shfl_xor(v2, off);
    int oi = __shfl_xor(i2, off);
    if (ov > v2 || (ov == v2 && oi < i2)) { v2 = ov; i2 = oi; }
  }
  float w1 = 0.0f, w2 = 0.0f;
  if (count >= 2) {
    float e = __expf(v2 - v1);
    float invd = 1.0f / (1.0f + e);
    w1 = invd; w2 = e * invd;
  } else if (count == 1) {
    w1 = 1.0f;
  }
  float wt = (lane == i1) ? w1 : ((lane == i2) ? w2 : 0.0f);
  out_sw[(size_t)pos * 64 + lane] = wt;
  if (lane < 2) out_idx[pos * 2 + lane] = (float)(lane == 0 ? i1 : i2);
  int d0 = lane * 4;
  float4 c1v = *(const float4*)(ce + (size_t)i1 * 256 + d0);
  float4 c2v = *(const float4*)(ce + (size_t)i2 * 256 + d0);
  float dv0 = __expf((float)d0 * PECOEF);
  float dv2 = __expf((float)(d0 + 2) * PECOEF);
  float ox = w1 * c1v.x + w2 * c2v.x + __sinf((float)hr * dv0);
  float oy = w1 * c1v.y + w2 * c2v.y + __cosf((float)wc * dv0);
  float oz = w1 * c1v.z + w2 * c2v.z + __sinf((float)hr * dv2);
  float ow = w1 * c1v.w + w2 * c2v.w + __cosf((float)wc * dv2);
  ushort4 ob = make_ushort4(f2b(ox), f2b(oy), f2b(oz), f2b(ow));
  *(ushort4*)(seqb + (size_t)pos * 256 + d0) = ob;
}

// ---- LDS-staged MFMA bf16 GEMM: C = A[M][K] @ W[N][K]^T + bias. Q cols pre-scaled
// by QK2S. V-blocks (n0>=512) store DIRECTLY to Vt (transposed + k-permuted). ----
__global__ __launch_bounds__(256) void k_gemm_lds(const unsigned short* __restrict__ A,
                                                  const unsigned short* __restrict__ W,
                                                  const float* __restrict__ bias,
                                                  unsigned short* __restrict__ C,
                                                  unsigned short* __restrict__ Vt,
                                                  int M, int N, int K) {
  __shared__ __align__(16) unsigned short As[8192];   // [128][64]
  __shared__ __align__(16) unsigned short Bs[8192];
  int tid = threadIdx.x;
  int lane = tid & 63, wid = tid >> 6;
  int q = lane & 15, g = lane >> 4;
  int m0 = blockIdx.y * 128, n0 = blockIdx.x * 128;
  int lrow = lane >> 3, s = lane & 7;
  const unsigned short* aSrc = A + (size_t)(m0 + wid * 8 + lrow) * K + (s ^ lrow) * 8;
  const unsigned short* bSrc = W + (size_t)(n0 + wid * 8 + lrow) * K + (s ^ lrow) * 8;
  int dstW = wid * 512;
  int mloc = (wid >> 1) * 64, nloc = (wid & 1) * 64;
  int q7 = q & 7;
  f32x4 acc[4][4];
  #pragma unroll
  for (int i = 0; i < 4; ++i)
    #pragma unroll
    for (int j = 0; j < 4; ++j) acc[i][j] = (f32x4){0.f, 0.f, 0.f, 0.f};
  for (int k0 = 0; k0 < K; k0 += 64) {
    #pragma unroll
    for (int i = 0; i < 4; ++i) {
      __builtin_amdgcn_global_load_lds((const AS1 void*)(aSrc + (size_t)i * 32 * K + k0),
                                       (AS3 void*)(&As[i * 2048 + dstW]), 16, 0, 0);
      __builtin_amdgcn_global_load_lds((const AS1 void*)(bSrc + (size_t)i * 32 * K + k0),
                                       (AS3 void*)(&Bs[i * 2048 + dstW]), 16, 0, 0);
    }
    __syncthreads();
    #pragma unroll
    for (int kk = 0; kk < 2; ++kk) {
      bf16x8 af[4], bf[4];
      #pragma unroll
      for (int i = 0; i < 4; ++i)
        af[i] = *(const bf16x8*)&As[(mloc + i * 16 + q) * 64 + (((kk * 4 + g) ^ q7) * 8)];
      #pragma unroll
      for (int j = 0; j < 4; ++j)
        bf[j] = *(const bf16x8*)&Bs[(nloc + j * 16 + q) * 64 + (((kk * 4 + g) ^ q7) * 8)];
      __builtin_amdgcn_s_setprio(1);
      #pragma unroll
      for (int i = 0; i < 4; ++i)
        #pragma unroll
        for (int j = 0; j < 4; ++j)
          acc[i][j] = __builtin_amdgcn_mfma_f32_16x16x32_bf16(af[i], bf[j], acc[i][j], 0, 0, 0);
      __builtin_amdgcn_s_setprio(0);
    }
    __syncthreads();
  }
  if (n0 < 512) {   // Q/K blocks -> qkv layout
    #pragma unroll
    for (int j = 0; j < 4; ++j) {
      int col = n0 + nloc + j * 16 + q;
      float bj = bias[col];
      float qs = (col < 256) ? QK2S : 1.0f;
      #pragma unroll
      for (int i = 0; i < 4; ++i) {
        #pragma unroll
        for (int r = 0; r < 4; ++r) {
          int row = m0 + mloc + i * 16 + g * 4 + r;
          C[(size_t)row * N + col] = f2b((acc[i][j][r] + bj) * qs);
        }
      }
    }
  } else {          // V blocks -> transposed + permuted Vt[(b*8+nh)*32+d][800]
    #pragma unroll
    for (int j = 0; j < 4; ++j) {
      int colV = n0 + nloc + j * 16 + q;
      float bj = bias[colV];
      int dtot = colV - 512;
      size_t vrow = ((size_t)(dtot >> 5) * 32 + (dtot & 31)) * 800;  // + b*8*32*800
      #pragma unroll
      for (int i = 0; i < 4; ++i) {
        int rowbase = m0 + mloc + i * 16;        // 16-aligned; whole group same b
        int b = rowbase / 784;
        int t16 = rowbase - b * 784;             // multiple of 16
        int pos = ((t16 >> 5) << 5) + ((t16 >> 4) & 1) * 4 + g * 8;
        uint2 o;
        o.x = cvt_pk_bf16(acc[i][j][0] + bj, acc[i][j][1] + bj);
        o.y = cvt_pk_bf16(acc[i][j][2] + bj, acc[i][j][3] + bj);
        *(uint2*)(Vt + (size_t)b * 8 * 32 * 800 + vrow + pos) = o;
      }
    }
  }
}

// ---- MFMA flash attention: no max tracking (scores bounded, exp2 domain), zero
// cross-lane ops; 64-key steps over 6 LDS tile-slots; one barrier + counted
// vmcnt(2) per 64 keys; l via all-ones MFMA. ----
__global__ __launch_bounds__(256) void k_attn(const unsigned short* __restrict__ qkv,
                                              const unsigned short* __restrict__ Vt,
                                              unsigned short* __restrict__ ctx) {
  __shared__ __align__(16) unsigned short Kt[6][1024];   // [slot][32 keys x 32 dims]
  __shared__ __align__(16) unsigned short Vti[6][1024];  // [slot][32 dims x 32 kpos]
  int wid = threadIdx.x >> 6;
  int lane = threadIdx.x & 63;
  int blk = blockIdx.x;                       // 3328 = 8 XCDs * 416
  int wrk = (blk & 7) * 416 + (blk >> 3);
  int bh = wrk / 13;
  int qb = (wrk - bh * 13) * 4 + wid;         // 0..51
  int b = bh >> 3, nh = bh & 7;
  int q = lane & 15, g = lane >> 4;
  bool active = (qb < 49);
  const f32x4 zero4 = {0.f, 0.f, 0.f, 0.f};
  const short one_bf = (short)0x3F80;         // bf16 1.0
  const bf16x8 ones8 = {one_bf, one_bf, one_bf, one_bf,
                        one_bf, one_bf, one_bf, one_bf};

  int qrow = b * 784 + (active ? qb * 16 + q : q);
  bf16x8 qf = *(const bf16x8*)(qkv + (size_t)qrow * 768 + nh * 32 + g * 8);
  asm volatile("s_waitcnt vmcnt(0)" ::: "memory");   // qf resident; vmcnt baseline 0

  const unsigned short* kbase = qkv + (size_t)b * 784 * 768 + 256 + nh * 32;
  const unsigned short* vbase = Vt + (size_t)bh * 32 * 800;

  // staging: wave 0 -> K rows 0-15, 1 -> K rows 16-31, 2 -> V d-rows 0-15,
  // 3 -> V d-rows 16-31; lane -> row r0+(lane>>2), 16B slot (lane&3) swizzled.
  int rit = ((wid & 1) << 4) + (lane >> 2);
  int sG = (lane & 3) ^ ((rit + (rit >> 2)) & 3);
  bool isK = (wid < 2);
  int ldsoff = ((wid & 1) << 4) * 32;
  const unsigned short* sp = isK ? (kbase + (size_t)rit * 768 + sG * 8)
                                 : (vbase + (size_t)rit * 800 + sG * 8);
  const int sstride = isK ? (32 * 768) : 32;
  unsigned short* ldsb = (isK ? &Kt[0][0] : &Vti[0][0]) + ldsoff;

  int slotr = ((g ^ ((q + (q >> 2)) & 3)) << 3);
  int rowA = q * 32 + slotr;
  int rowB = (16 + q) * 32 + slotr;

  f32x4 acc0 = zero4, acc1 = zero4, accS = zero4;

#define STAGE(SLOTO) {                                                         \
    __builtin_amdgcn_global_load_lds((const AS1 void*)sp,                      \
                                     (AS3 void*)(ldsb + (SLOTO)), 16, 0, 0);   \
    sp += sstride; }

// one 64-key step: tiles at slot offsets SA,SB; prefetch into NXA,NXB
#define STEP(SA, SB, NXA, NXB) {                                               \
    asm volatile("s_waitcnt vmcnt(2)" ::: "memory");                           \
    __builtin_amdgcn_s_barrier();                                              \
    asm volatile("" ::: "memory");                                             \
    STAGE(NXA); STAGE(NXB);                                                    \
    bf16x8 kA0 = *(const bf16x8*)&Kt[0][(SA) + rowA];                          \
    bf16x8 kB0 = *(const bf16x8*)&Kt[0][(SA) + rowB];                          \
    bf16x8 va0 = *(const bf16x8*)&Vti[0][(SA) + rowA];                         \
    bf16x8 vb0 = *(const bf16x8*)&Vti[0][(SA) + rowB];                         \
    bf16x8 kA1 = *(const bf16x8*)&Kt[0][(SB) + rowA];                          \
    bf16x8 kB1 = *(const bf16x8*)&Kt[0][(SB) + rowB];                          \
    bf16x8 va1 = *(const bf16x8*)&Vti[0][(SB) + rowA];                         \
    bf16x8 vb1 = *(const bf16x8*)&Vti[0][(SB) + rowB];                         \
    __builtin_amdgcn_s_setprio(1);                                             \
    f32x4 s0 = __builtin_amdgcn_mfma_f32_16x16x32_bf16(kA0, qf, zero4, 0, 0, 0);\
    f32x4 s1 = __builtin_amdgcn_mfma_f32_16x16x32_bf16(kB0, qf, zero4, 0, 0, 0);\
    f32x4 s2 = __builtin_amdgcn_mfma_f32_16x16x32_bf16(kA1, qf, zero4, 0, 0, 0);\
    f32x4 s3 = __builtin_amdgcn_mfma_f32_16x16x32_bf16(kB1, qf, zero4, 0, 0, 0);\
    __builtin_amdgcn_s_setprio(0);                                             \
    union { unsigned u[4]; bf16x8 v; } pu0, pu1;                               \
    pu0.u[0] = cvt_pk_bf16(__builtin_amdgcn_exp2f(s0[0]),                      \
                           __builtin_amdgcn_exp2f(s0[1]));                     \
    pu0.u[1] = cvt_pk_bf16(__builtin_amdgcn_exp2f(s0[2]),                      \
                           __builtin_amdgcn_exp2f(s0[3]));                     \
    pu0.u[2] = cvt_pk_bf16(__builtin_amdgcn_exp2f(s1[0]),                      \
                           __builtin_amdgcn_exp2f(s1[1]));                     \
    pu0.u[3] = cvt_pk_bf16(__builtin_amdgcn_exp2f(s1[2]),                      \
                           __builtin_amdgcn_exp2f(s1[3]));                     \
    pu1.u[0] = cvt_pk_bf16(__builtin_amdgcn_exp2f(s2[0]),                      \
                           __builtin_amdgcn_exp2f(s2[1]));                     \
    pu1.u[1] = cvt_pk_bf16(__builtin_amdgcn_exp2f(s2[2]),                      \
                           __builtin_amdgcn_exp2f(s2[3]));                     \
    pu1.u[2] = cvt_pk_bf16(__builtin_amdgcn_exp2f(s3[0]),                      \
                           __builtin_amdgcn_exp2f(s3[1]));                     \
    pu1.u[3] = cvt_pk_bf16(__builtin_amdgcn_exp2f(s3[2]),                      \
                           __builtin_amdgcn_exp2f(s3[3]));                     \
    __builtin_amdgcn_s_setprio(1);                                             \
    acc0 = __builtin_amdgcn_mfma_f32_16x16x32_bf16(va0, pu0.v, acc0, 0, 0, 0); \
    acc1 = __builtin_amdgcn_mfma_f32_16x16x32_bf16(vb0, pu0.v, acc1, 0, 0, 0); \
    accS = __builtin_amdgcn_mfma_f32_16x16x32_bf16(ones8, pu0.v, accS, 0, 0, 0);\
    acc0 = __builtin_amdgcn_mfma_f32_16x16x32_bf16(va1, pu1.v, acc0, 0, 0, 0); \
    acc1 = __builtin_amdgcn_mfma_f32_16x16x32_bf16(vb1, pu1.v, acc1, 0, 0, 0); \
    accS = __builtin_amdgcn_mfma_f32_16x16x32_bf16(ones8, pu1.v, accS, 0, 0, 0);\
    __builtin_amdgcn_s_setprio(0);                                             \
  }

  STAGE(0); STAGE(1024);      // step 0: tiles 0,1
  STAGE(2048); STAGE(3072);   // step 1: tiles 2,3

  // 12 steps x 64 keys = tiles 0..23 (keys 0..767); prefetch runs 2 steps ahead
  // (final prefetches are harmless dummy over-reads into mapped ws).
  for (int t = 0; t < 4; ++t) {
    STEP(0, 1024, 4096, 5120);
    STEP(2048, 3072, 0, 1024);
    STEP(4096, 5120, 2048, 3072);
  }
  { // tail: tile 24 (keys 768..799) in slot 0; nonexistent-key P slots are 0.
    asm volatile("s_waitcnt vmcnt(3)" ::: "memory");
    __builtin_amdgcn_s_barrier();
    asm volatile("" ::: "memory");
    bf16x8 kA = *(const bf16x8*)&Kt[0][rowA];
    bf16x8 va = *(const bf16x8*)&Vti[0][rowA];
    bf16x8 vb = *(const bf16x8*)&Vti[0][rowB];
    f32x4 s0 = __builtin_amdgcn_mfma_f32_16x16x32_bf16(kA, qf, zero4, 0, 0, 0);
    union { unsigned u[4]; bf16x8 v; } pu;
    pu.u[0] = cvt_pk_bf16(__builtin_amdgcn_exp2f(s0[0]),
                          __builtin_amdgcn_exp2f(s0[1]));
    pu.u[1] = cvt_pk_bf16(__builtin_amdgcn_exp2f(s0[2]),
                          __builtin_amdgcn_exp2f(s0[3]));
    pu.u[2] = 0u;
    pu.u[3] = 0u;
    acc0 = __builtin_amdgcn_mfma_f32_16x16x32_bf16(va, pu.v, acc0, 0, 0, 0);
    acc1 = __builtin_amdgcn_mfma_f32_16x16x32_bf16(vb, pu.v, acc1, 0, 0, 0);
    accS = __builtin_amdgcn_mfma_f32_16x16x32_bf16(ones8, pu.v, accS, 0, 0, 0);
  }
#undef STEP
#undef STAGE
  float linv = 1.f / accS[0];
  if (active) {
    unsigned short* cp = ctx + (size_t)(b * 784 + qb * 16 + q) * 256 + nh * 32;
    ushort4 oA = make_ushort4(f2b(acc0[0] * linv), f2b(acc0[1] * linv),
                              f2b(acc0[2] * linv), f2b(acc0[3] * linv));
    ushort4 oB = make_ushort4(f2b(acc1[0] * linv), f2b(acc1[1] * linv),
                              f2b(acc1[2] * linv), f2b(acc1[3] * linv));
    *(ushort4*)(cp + g * 4) = oA;
    *(ushort4*)(cp + 16 + g * 4) = oB;
  }
}

// ---- mean-pool ctx (bf16 -> f32 partials): out-proj is deferred to a tiny GEMV ----
__global__ __launch_bounds__(256) void k_poolctx(const unsigned short* __restrict__ ctx,
                                                 float* __restrict__ part) {
  int b = blockIdx.x >> 3, sseg = blockIdx.x & 7;
  int d = threadIdx.x;
  const unsigned short* base = ctx + ((size_t)b * 784 + sseg * 98) * 256 + d;
  float acc = 0.f;
  for (int t = 0; t < 98; ++t)
    acc += __uint_as_float((unsigned)base[(size_t)t * 256] << 16);
  part[(size_t)blockIdx.x * 256 + d] = acc;
}

// ---- pooled[b] = mean_ctx[b] @ opw^T + opb  (f32, exact out-proj of the mean) ----
__global__ __launch_bounds__(256) void k_pgemv(const float* __restrict__ part,
                                               const float* __restrict__ opw,
                                               const float* __restrict__ opb,
                                               float* __restrict__ out) {
  __shared__ float mc[256];
  int b = blockIdx.x, d = threadIdx.x;
  float s = 0.f;
  #pragma unroll
  for (int i = 0; i < 8; ++i) s += part[(size_t)(b * 8 + i) * 256 + d];
  mc[d] = s * (1.0f / 784.0f);
  __syncthreads();
  float acc = opb[d];
  const float4* wr = (const float4*)(opw + (size_t)d * 256);
  #pragma unroll 8
  for (int j = 0; j < 64; ++j) {
    float4 w = wr[j];
    float4 m4 = *(const float4*)&mc[j * 4];
    acc += m4.x * w.x + m4.y * w.y + m4.z * w.z + m4.w * w.w;
  }
  out[b * 256 + d] = acc;
}

extern "C" void kernel_launch(void* const* d_in, const int* in_sizes, int n_in,
                              void* d_out, int out_size, void* d_ws, size_t ws_size,
                              hipStream_t stream) {
  (void)in_sizes; (void)n_in; (void)out_size; (void)ws_size;
  const float* x   = (const float*)d_in[0];
  const float* cw  = (const float*)d_in[1];
  const float* ce  = (const float*)d_in[2];
  const float* ipw = (const float*)d_in[3];
  const float* ipb = (const float*)d_in[4];
  const float* opw = (const float*)d_in[5];
  const float* opb = (const float*)d_in[6];

  float* out = (float*)d_out;
  float* pooled  = out;
  float* out_sw  = out + 8192;
  float* out_idx = out + 8192 + NA;

  float* ws = (float*)d_ws;
  float* vbuf = ws;                                   // NA f32
  unsigned* hist16 = (unsigned*)(ws + NA);            // 65536
  unsigned* hist8a = hist16 + 65536;                  // 256
  unsigned* hist8b = hist8a + 256;                    // 256
  unsigned* sel    = hist8b + 256;                    // 16
  unsigned short* seqb = (unsigned short*)(ws + NA + 66080);  // SEQN bf16 (later: ctx)
  unsigned short* qkvb = seqb + SEQN;                 // 3*SEQN bf16 (V region unused)
  unsigned short* Vt   = qkvb + 3 * (size_t)SEQN;     // 256*32*800 bf16
  unsigned short* wbuf = Vt + 256 * 32 * 800;         // 196608 bf16 (in_proj only)
  float* part = (float*)(wbuf + 262144);              // 65536 f32

  k_init<<<768, 256, 0, stream>>>(ipw, wbuf, hist16);
  k_conv<<<224, 256, 0, stream>>>(x, cw, vbuf, hist8a);
  k_h8b<<<1024, 256, 0, stream>>>(vbuf, hist8a, hist8b);
  k_h16<<<1024, 256, 0, stream>>>(vbuf, hist8a, hist8b, hist16);
  k_scan16<<<1, 1024, 0, stream>>>(hist8a, hist8b, hist16, sel);
  k_select<<<25088 / 4, 256, 0, stream>>>(vbuf, sel, ce, seqb, out_sw, out_idx);
  {
    dim3 gq(768 / 128, 25088 / 128);
    k_gemm_lds<<<gq, 256, 0, stream>>>(seqb, wbuf, ipb, qkvb, Vt, 25088, 768, 256);
  }
  k_attn<<<3328, 256, 0, stream>>>(qkvb, Vt, seqb /* ctx */);
  k_poolctx<<<256, 256, 0, stream>>>(seqb, part);
  k_pgemv<<<NB, 256, 0, stream>>>(part, opw, opb, pooled);
}